// Round 8
// baseline (1075.967 us; speedup 1.0000x reference)
//
#include <hip/hip_runtime.h>
#include <math.h>

#define B_   8
#define L_   1024
#define D_   768
#define R_   16
#define NSP  4
#define NREL 33

typedef __attribute__((ext_vector_type(8))) short bf16x8;
typedef __attribute__((ext_vector_type(4))) float f32x4;
typedef __attribute__((address_space(1))) const void gv_t;
typedef __attribute__((address_space(3))) void sv_t;

__device__ __forceinline__ unsigned short f2bf(float f) {
    unsigned int u = __float_as_uint(f);
    u += 0x7fff + ((u >> 16) & 1);          // RNE
    return (unsigned short)(u >> 16);
}
__device__ __forceinline__ float bf2f(unsigned short s) {
    return __uint_as_float(((unsigned int)s) << 16);
}
__device__ __forceinline__ unsigned short f2h(float f) {
    _Float16 h = (_Float16)f;
    return *(unsigned short*)&h;
}
__device__ __forceinline__ float h2f(unsigned short u) {
    _Float16 h = *(_Float16*)&u;
    return (float)h;
}

struct PSet {
    const unsigned short* A0;
    const unsigned short* B0;
    const unsigned short* A1;   // dual-K phase 2
    const unsigned short* B1;
    const float*          bias;
    const unsigned short* addend;
    void*                 Cout;
    float*                qout;    // mode 2 output (fp32 qrel)
    const float*          bterm;   // mode 1 per-key bias
    long                  bB0;     // per-batch stride of B0 (0 = unbatched)
    long                  cStride;
    long                  mValid;  // prep kernel row guard
    float                 scale;
    int                   mode;    // 0=bf16 C, 1=scores->fp16 scratch, 2=qrel
    int                   relu;
    int                   nValid;  // early-exit when col0 >= nValid
};
struct PSet4 { PSet s[4]; };

// ===========================================================================
// 8-phase 256x256 MFMA GEMM (T2+T3+T4+T5). BK=64, 8 waves (2Mx4N), 512 thr.
// LDS 128 KiB dbuf, st_16x32 XOR-swizzle reads + inverse-swizzled global src,
// linear global_load_lds dest, counted vmcnt(4). Runtime per-z mode/epilogue.
// Optional row compaction: rows/cntp non-null -> per-batch gathered A rows,
// scattered C rows; blockIdx.y = b*4 + tile; tile past cntp[b] exits.
__global__ __launch_bounds__(512, 2) void k_mfma8(
    PSet4 ps, long aS0, long bS0, int bR0, int K0,
    long aS1, long bS1, int K1,
    const int* __restrict__ rows, const int* __restrict__ cntp,
    const int* __restrict__ spw, const int* __restrict__ srcm,
    const int* __restrict__ attm, int it)
{
    PSet p = ps.s[blockIdx.z];
    const int col0 = blockIdx.x * 256;
    if (col0 >= p.nValid) return;

    int b, tile; long row0;
    const int* rowsb = nullptr;
    if (rows) {
        b = blockIdx.y >> 2; tile = blockIdx.y & 3;
        if (tile * 256 >= cntp[b]) return;
        rowsb = rows + b * 1024 + tile * 256;
        row0 = 0;
    } else {
        row0 = (long)blockIdx.y * 256;
        b = (int)(row0 >> 10); tile = 0;
    }

    __shared__ unsigned short lds[2][2][256 * 64];   // 128 KiB

    const int tid  = threadIdx.x;
    const int lane = tid & 63;
    const int wave = tid >> 6;
    const int wr = wave >> 2;           // 0..1 (M half)
    const int wc = wave & 3;            // 0..3 (N quarter)
    const int lq = lane >> 4, lr = lane & 15;

    const unsigned short* Bb0 = p.B0 + (rows ? (long)b * p.bB0
                                             : (row0 / bR0) * p.bB0);

    // preload A-gather indices (4 per lane, constant over K loop)
    int ridxA[2][2];
#pragma unroll
    for (int h = 0; h < 2; ++h)
#pragma unroll
        for (int j = 0; j < 2; ++j) {
            const int r = h * 128 + j * 64 + wave * 8 + (lane >> 3);
            ridxA[j][h] = rowsb ? rowsb[r] : (int)(row0 + r);
        }

    const int NT0 = K0 / 64;
    const int NT  = NT0 + K1 / 64;

    f32x4 acc[8][4];
#pragma unroll
    for (int m = 0; m < 8; ++m)
#pragma unroll
        for (int n = 0; n < 4; ++n) acc[m][n] = (f32x4)0.f;

    auto stageHalf = [&](int tt, int side, int h) {
        if (tt >= NT) return;
        const unsigned short* src; long stride; int k0;
        if (tt < NT0) { src = side ? Bb0  : p.A0; stride = side ? bS0 : aS0; k0 = tt * 64; }
        else          { src = side ? p.B1 : p.A1; stride = side ? bS1 : aS1; k0 = (tt - NT0) * 64; }
        unsigned short* dst = &lds[tt & 1][side][h * 8192];
#pragma unroll
        for (int j = 0; j < 2; ++j) {
            const int r = j * 64 + wave * 8 + (lane >> 3);
            const int csrc = ((lane & 7) * 8) ^ (((r >> 2) & 1) << 4);
            const long grow = side ? (long)(col0 + h * 128 + r) : (long)ridxA[j][h];
            const unsigned short* g = src + grow * stride + k0 + csrc;
            __builtin_amdgcn_global_load_lds((gv_t*)g,
                (sv_t*)(dst + j * 4096 + wave * 512), 16, 0, 0);
        }
    };
    auto rd = [&](int bt, int side, int r, int ks) -> bf16x8 {
        const int idx = r * 64 + (((ks << 5) | (lq << 3)) ^ (((r >> 2) & 1) << 4));
        return *(const bf16x8*)&lds[bt][side][idx];
    };

    stageHalf(0, 0, 0); stageHalf(0, 0, 1);
    stageHalf(0, 1, 0); stageHalf(0, 1, 1);
    stageHalf(1, 1, 0); stageHalf(1, 1, 1);
    if (1 < NT) asm volatile("s_waitcnt vmcnt(4)" ::: "memory");
    else        asm volatile("s_waitcnt vmcnt(0)" ::: "memory");
    __builtin_amdgcn_s_barrier();

    bf16x8 af[4][2], bfr[4][2];

    for (int t = 0; t < NT; ++t) {
        const int bt = t & 1;
        // phase 1: read A m0-3 + B n0-1; stage (t+1).A0
#pragma unroll
        for (int mf = 0; mf < 4; ++mf)
#pragma unroll
            for (int ks = 0; ks < 2; ++ks)
                af[mf][ks] = rd(bt, 0, wr * 128 + mf * 16 + lr, ks);
#pragma unroll
        for (int nf = 0; nf < 2; ++nf)
#pragma unroll
            for (int ks = 0; ks < 2; ++ks)
                bfr[nf][ks] = rd(bt, 1, wc * 64 + nf * 16 + lr, ks);
        stageHalf(t + 1, 0, 0);
        __builtin_amdgcn_s_barrier();
        asm volatile("s_waitcnt lgkmcnt(0)" ::: "memory");
        __builtin_amdgcn_sched_barrier(0);
        __builtin_amdgcn_s_setprio(1);
#pragma unroll
        for (int nf = 0; nf < 2; ++nf)
#pragma unroll
            for (int mf = 0; mf < 4; ++mf)
#pragma unroll
                for (int ks = 0; ks < 2; ++ks)
                    acc[mf][nf] = __builtin_amdgcn_mfma_f32_16x16x32_bf16(
                        af[mf][ks], bfr[nf][ks], acc[mf][nf], 0, 0, 0);
        __builtin_amdgcn_s_setprio(0);
        __builtin_amdgcn_s_barrier();
        // phase 2: read B n2-3; stage (t+1).A1
#pragma unroll
        for (int nf = 2; nf < 4; ++nf)
#pragma unroll
            for (int ks = 0; ks < 2; ++ks)
                bfr[nf][ks] = rd(bt, 1, wc * 64 + nf * 16 + lr, ks);
        stageHalf(t + 1, 0, 1);
        __builtin_amdgcn_s_barrier();
        asm volatile("s_waitcnt lgkmcnt(0)" ::: "memory");
        __builtin_amdgcn_sched_barrier(0);
        __builtin_amdgcn_s_setprio(1);
#pragma unroll
        for (int nf = 2; nf < 4; ++nf)
#pragma unroll
            for (int mf = 0; mf < 4; ++mf)
#pragma unroll
                for (int ks = 0; ks < 2; ++ks)
                    acc[mf][nf] = __builtin_amdgcn_mfma_f32_16x16x32_bf16(
                        af[mf][ks], bfr[nf][ks], acc[mf][nf], 0, 0, 0);
        __builtin_amdgcn_s_setprio(0);
        __builtin_amdgcn_s_barrier();
        // phase 3: read A m4-7; stage (t+2).B0
#pragma unroll
        for (int mf = 0; mf < 4; ++mf)
#pragma unroll
            for (int ks = 0; ks < 2; ++ks)
                af[mf][ks] = rd(bt, 0, wr * 128 + 64 + mf * 16 + lr, ks);
        stageHalf(t + 2, 1, 0);
        __builtin_amdgcn_s_barrier();
        asm volatile("s_waitcnt lgkmcnt(0)" ::: "memory");
        __builtin_amdgcn_sched_barrier(0);
        __builtin_amdgcn_s_setprio(1);
#pragma unroll
        for (int nf = 0; nf < 2; ++nf)
#pragma unroll
            for (int mf = 0; mf < 4; ++mf)
#pragma unroll
                for (int ks = 0; ks < 2; ++ks)
                    acc[4 + mf][nf] = __builtin_amdgcn_mfma_f32_16x16x32_bf16(
                        af[mf][ks], bfr[nf][ks], acc[4 + mf][nf], 0, 0, 0);
        __builtin_amdgcn_s_setprio(0);
        __builtin_amdgcn_s_barrier();
        // phase 4: stage (t+2).B1; counted vmcnt; MFMA m4-7 x n2-3
        stageHalf(t + 2, 1, 1);
        if (t + 2 < NT) asm volatile("s_waitcnt vmcnt(4)" ::: "memory");
        else            asm volatile("s_waitcnt vmcnt(0)" ::: "memory");
        __builtin_amdgcn_s_barrier();
        __builtin_amdgcn_sched_barrier(0);
        __builtin_amdgcn_s_setprio(1);
#pragma unroll
        for (int nf = 2; nf < 4; ++nf)
#pragma unroll
            for (int mf = 0; mf < 4; ++mf)
#pragma unroll
                for (int ks = 0; ks < 2; ++ks)
                    acc[4 + mf][nf] = __builtin_amdgcn_mfma_f32_16x16x32_bf16(
                        af[mf][ks], bfr[nf][ks], acc[4 + mf][nf], 0, 0, 0);
        __builtin_amdgcn_s_setprio(0);
        __builtin_amdgcn_s_barrier();
    }

    auto mgof = [&](int r) -> long {
        return rowsb ? (long)rowsb[r] : row0 + r;
    };

    // ---------------- epilogue (runtime mode) ----------------
    if (p.mode == 0) {
        unsigned short* C = (unsigned short*)p.Cout;
#pragma unroll
        for (int nf = 0; nf < 4; ++nf) {
            const int col = col0 + wc * 64 + nf * 16 + lr;
            const float bc = p.bias ? p.bias[col] : 0.f;
#pragma unroll
            for (int mf = 0; mf < 8; ++mf) {
#pragma unroll
                for (int rr = 0; rr < 4; ++rr) {
                    const long row = mgof(wr * 128 + mf * 16 + lq * 4 + rr);
                    float v = acc[mf][nf][rr] + bc;
                    if (p.addend) v += bf2f(p.addend[row * p.cStride + col]);
                    v *= p.scale;
                    if (p.relu) v = fmaxf(v, 0.f);
                    C[row * p.cStride + col] = f2bf(v);
                }
            }
        }
    } else if (p.mode == 1) {
        unsigned short* C = (unsigned short*)p.Cout;   // fp16 scratch [m][L]
        int amv[4]; float btv[4];
#pragma unroll
        for (int nf = 0; nf < 4; ++nf) {
            const int col = col0 + wc * 64 + nf * 16 + lr;
            amv[nf] = attm[b * L_ + col];
            btv[nf] = p.bterm[b * L_ + col];
        }
#pragma unroll
        for (int mf = 0; mf < 8; ++mf) {
#pragma unroll
            for (int rr = 0; rr < 4; ++rr) {
                const long mg = mgof(wr * 128 + mf * 16 + lq * 4 + rr);
                const bool rowAct = (it < spw[mg]) && (srcm[mg] != 0);
#pragma unroll
                for (int nf = 0; nf < 4; ++nf) {
                    const int col = col0 + wc * 64 + nf * 16 + lr;
                    const float v = (rowAct && amv[nf]) ? (acc[mf][nf][rr] + btv[nf]) : -60000.f;
                    C[mg * L_ + col] = f2h(v);
                }
            }
        }
    } else {   // mode 2: qrel fp32 (col < NREL)
        float* qout = p.qout;
#pragma unroll
        for (int nf = 0; nf < 3; ++nf) {
            const int col = wc * 64 + nf * 16 + lr;
            if (col < NREL) {
                const float bc = p.bias[col];
#pragma unroll
                for (int mf = 0; mf < 8; ++mf)
#pragma unroll
                    for (int rr = 0; rr < 4; ++rr) {
                        const long mg = mgof(wr * 128 + mf * 16 + lq * 4 + rr);
                        qout[mg * NREL + col] = (acc[mf][nf][rr] + bc) * p.scale;
                    }
            }
        }
    }
}

// ===========================================================================
// 2-phase 128x128 kernel (prep-only: GtT / Wqrel, small M)
__global__ __launch_bounds__(256) void k_mfma_prep(
    PSet4 ps, long aS0, long bS0, int K0)
{
    PSet p = ps.s[blockIdx.z];
    const long row0 = (long)blockIdx.y * 128;
    if (row0 >= p.mValid) return;
    const int col0 = blockIdx.x * 128;

    __shared__ unsigned short As[2][128 * 32];
    __shared__ unsigned short Bs[2][128 * 32];
    const int tid  = threadIdx.x;
    const int lane = tid & 63;
    const int wave = tid >> 6;
    const int wr = wave >> 1, wc = wave & 1;
    const int lq = lane >> 4, lr = lane & 15;
    const int sr = lane >> 2;
    const int sc = (lane & 3) * 8;

    f32x4 acc[4][4];
#pragma unroll
    for (int m = 0; m < 4; ++m)
#pragma unroll
        for (int n = 0; n < 4; ++n) acc[m][n] = (f32x4)0.f;

    const int NT = K0 / 32;
    auto stage = [&](int t, int buf) {
        const int k0 = t * 32;
#pragma unroll
        for (int j = 0; j < 2; ++j) {
            const int c = wave + j * 4;
            const unsigned short* ga = p.A0 + (row0 + c * 16 + sr) * aS0 + k0 + sc;
            const unsigned short* gb = p.B0 + (long)(col0 + c * 16 + sr) * bS0 + k0 + sc;
            __builtin_amdgcn_global_load_lds((gv_t*)ga, (sv_t*)&As[buf][c * 512], 16, 0, 0);
            __builtin_amdgcn_global_load_lds((gv_t*)gb, (sv_t*)&Bs[buf][c * 512], 16, 0, 0);
        }
    };
    stage(0, 0);
    asm volatile("s_waitcnt vmcnt(0)" ::: "memory");
    __builtin_amdgcn_s_barrier();
    int cur = 0;
    for (int t = 0; t < NT; ++t) {
        if (t + 1 < NT) stage(t + 1, cur ^ 1);
        bf16x8 a4[4], b4[4];
#pragma unroll
        for (int m = 0; m < 4; ++m)
            a4[m] = *(const bf16x8*)&As[cur][(wr * 64 + m * 16 + lr) * 32 + lq * 8];
#pragma unroll
        for (int n = 0; n < 4; ++n)
            b4[n] = *(const bf16x8*)&Bs[cur][(wc * 64 + n * 16 + lr) * 32 + lq * 8];
#pragma unroll
        for (int m = 0; m < 4; ++m)
#pragma unroll
            for (int n = 0; n < 4; ++n)
                acc[m][n] = __builtin_amdgcn_mfma_f32_16x16x32_bf16(a4[m], b4[n], acc[m][n], 0, 0, 0);
        asm volatile("s_waitcnt vmcnt(0)" ::: "memory");
        __builtin_amdgcn_s_barrier();
        cur ^= 1;
    }
    unsigned short* C = (unsigned short*)p.Cout;
#pragma unroll
    for (int n = 0; n < 4; ++n) {
        const int col = col0 + wc * 64 + n * 16 + lr;
#pragma unroll
        for (int m = 0; m < 4; ++m)
#pragma unroll
            for (int r = 0; r < 4; ++r) {
                const long row = row0 + wr * 64 + m * 16 + lq * 4 + r;
                C[row * p.cStride + col] = f2bf(acc[m][n][r]);
            }
    }
}

// ---------------------------------------------------------------------------
struct Zero8 { float4* p[8]; long n4[8]; };
__global__ __launch_bounds__(256) void k_zero8(Zero8 z)
{
    long g = (long)blockIdx.x * 256 + threadIdx.x;
#pragma unroll
    for (int s = 0; s < 8; ++s) {
        if (g < z.n4[s]) {
            float4 v; v.x = v.y = v.z = v.w = 0.f;
            z.p[s][g] = v;
            return;
        }
        g -= z.n4[s];
    }
}

struct Cvt8 { const float* src[8]; unsigned short* dst[8]; long n4[8]; };
__global__ __launch_bounds__(256) void k_cvt8(Cvt8 c)
{
    long g = (long)blockIdx.x * 256 + threadIdx.x;
#pragma unroll
    for (int s = 0; s < 8; ++s) {
        if (g < c.n4[s]) {
            const float4 v = ((const float4*)c.src[s])[g];
            ushort4 o; o.x = f2bf(v.x); o.y = f2bf(v.y); o.z = f2bf(v.z); o.w = f2bf(v.w);
            ((ushort4*)c.dst[s])[g] = o;
            return;
        }
        g -= c.n4[s];
    }
}

__global__ __launch_bounds__(256) void k_transpose(
    const float* __restrict__ in, unsigned short* __restrict__ out, int rows, int cols)
{
    __shared__ float t[32][33];
    const long zo = (long)blockIdx.z * rows * cols;
    const int c0 = blockIdx.x * 32, r0 = blockIdx.y * 32;
    const int tx = threadIdx.x & 31, ty = threadIdx.x >> 5;
#pragma unroll
    for (int i = 0; i < 32; i += 8)
        t[ty + i][tx] = in[zo + (long)(r0 + ty + i) * cols + c0 + tx];
    __syncthreads();
#pragma unroll
    for (int i = 0; i < 32; i += 8)
        out[zo + (long)(c0 + ty + i) * rows + r0 + tx] = f2bf(t[tx][ty + i]);
}

__global__ __launch_bounds__(256) void k_transpose_bf(
    const unsigned short* __restrict__ in, unsigned short* __restrict__ out,
    int rows, int cols)
{
    __shared__ unsigned short t[32][33];
    const long zo = (long)blockIdx.z * rows * cols;
    const int c0 = blockIdx.x * 32, r0 = blockIdx.y * 32;
    const int tx = threadIdx.x & 31, ty = threadIdx.x >> 5;
#pragma unroll
    for (int i = 0; i < 32; i += 8)
        t[ty + i][tx] = in[zo + (long)(r0 + ty + i) * cols + c0 + tx];
    __syncthreads();
#pragma unroll
    for (int i = 0; i < 32; i += 8)
        out[zo + (long)(c0 + ty + i) * rows + r0 + tx] = t[tx][ty + i];
}

// ---------------------------------------------------------------------------
// biasQ[896]: [0..767] = bq.Wk[i,:]; [768+r] = bq.rel[r,:]; wave per output
__global__ __launch_bounds__(256) void k_biasq(
    const float* __restrict__ bq0, const float* __restrict__ bq1,
    const float* __restrict__ wk0, const float* __restrict__ wk1,
    const float* __restrict__ rel0, const float* __restrict__ rel1,
    float* __restrict__ out0, float* __restrict__ out1)
{
    const int z = blockIdx.y;
    const float* bq  = z ? bq1  : bq0;
    const float* wk  = z ? wk1  : wk0;
    const float* rel = z ? rel1 : rel0;
    float* out       = z ? out1 : out0;
    const int i = blockIdx.x * 4 + (threadIdx.x >> 6);
    const int lane = threadIdx.x & 63;
    const float* w = nullptr;
    if (i < D_) w = wk + (long)i * D_;
    else if (i - D_ < NREL) w = rel + (long)(i - D_) * D_;
    float a = 0.f;
    if (w)
        for (int e = lane * 4; e < D_; e += 256) {
            const float4 w4 = *(const float4*)&w[e];
            const float4 b4 = *(const float4*)&bq[e];
            a += w4.x * b4.x + w4.y * b4.y + w4.z * b4.z + w4.w * b4.w;
        }
#pragma unroll
    for (int o = 32; o > 0; o >>= 1) a += __shfl_xor(a, o, 64);
    if (lane == 0) out[i] = a;
}

// bterm[m] = invs * sum_d biasQ[d] * hid[m,d]
__global__ __launch_bounds__(256) void k_bterm(
    const unsigned short* __restrict__ hid_bf,
    const float* __restrict__ biasQ0, const float* __restrict__ biasQ1,
    float* __restrict__ out0, float* __restrict__ out1, float invs)
{
    const float* biasQ = blockIdx.y ? biasQ1 : biasQ0;
    float* out = blockIdx.y ? out1 : out0;
    const long row = (long)blockIdx.x * 4 + (threadIdx.x >> 6);
    const int lane = threadIdx.x & 63;
    const unsigned short* h = hid_bf + row * D_;
    float a = 0.f;
    for (int d = lane * 4; d < D_; d += 256) {
        const ushort4 u = *(const ushort4*)&h[d];
        const float4 bq4 = *(const float4*)&biasQ[d];
        a += bf2f(u.x) * bq4.x + bf2f(u.y) * bq4.y + bf2f(u.z) * bq4.z + bf2f(u.w) * bq4.w;
    }
#pragma unroll
    for (int o = 32; o > 0; o >>= 1) a += __shfl_xor(a, o, 64);
    if (lane == 0) out[row] = a * invs;
}

// ---------------------------------------------------------------------------
// active-row lists per (it, batch); values order-independent downstream
__global__ __launch_bounds__(256) void k_lists(
    const int* __restrict__ spw, int* __restrict__ lists, int* __restrict__ cnt)
{
    const int m = blockIdx.x * 256 + threadIdx.x;
    const int s = spw[m];
    const int b = m >> 10;
#pragma unroll
    for (int it = 0; it < NSP; ++it)
        if (s > it) {
            const int pos = atomicAdd(&cnt[it * 8 + b], 1);
            lists[(long)(it * 8 + b) * 1024 + pos] = m;
        }
}

__global__ __launch_bounds__(256) void k_padlists(
    int* __restrict__ lists, const int* __restrict__ cnt)
{
    const int idx = blockIdx.x;
    const int c = cnt[idx];
    if (c == 0) return;
    const int v = lists[(long)idx * 1024];
    for (int j = c + threadIdx.x; j < 1024; j += 256)
        lists[(long)idx * 1024 + j] = v;
}

// uniform 1/1024 rows for masked (m, it)
__global__ __launch_bounds__(256) void k_fillu(
    const int* __restrict__ spw, float* __restrict__ oSt, float* __restrict__ oEd)
{
    const int m = blockIdx.x, it = blockIdx.y;
    if (spw[m] > it) return;
    const long base = ((long)m * NSP + it) * L_;
    float4 u; u.x = u.y = u.z = u.w = 0.0009765625f;
    ((float4*)&oSt[base])[threadIdx.x] = u;
    ((float4*)&oEd[base])[threadIdx.x] = u;
}

// ---------------------------------------------------------------------------
// compacted softmax: fp16 scratch -> fp32 d_out + bf16 attn; y selects st/ed
__global__ __launch_bounds__(256) void k_softmax(
    const unsigned short* __restrict__ sSt, const unsigned short* __restrict__ sEd,
    float* __restrict__ oSt, float* __restrict__ oEd,
    unsigned short* __restrict__ aSt, unsigned short* __restrict__ aEd,
    const float* __restrict__ qrSt, const float* __restrict__ qrEd,
    const int* __restrict__ rows, const int* __restrict__ cnt8, int it)
{
    const int slot = blockIdx.x;
    const int b = slot >> 10, i = slot & 1023;
    if (i >= cnt8[b]) return;
    const long m = rows[b * 1024 + i];
    const unsigned short* s = (blockIdx.y ? sEd : sSt) + m * L_;
    float* o = (blockIdx.y ? oEd : oSt) + (m * NSP + it) * L_;
    unsigned short* a = (blockIdx.y ? aEd : aSt) + m * L_;
    const float* qrow = (blockIdx.y ? qrEd : qrSt) + m * NREL;
    const int q = (int)(m & (L_ - 1));
    const int t = threadIdx.x;
    const ushort4 u = *(const ushort4*)&s[4 * t];
    float vv[4];
    const unsigned short* up = (const unsigned short*)&u;
#pragma unroll
    for (int j = 0; j < 4; ++j) {
        float x = h2f(up[j]);
        if (x < -3.0e4f) x = -1e18f;      // masked: exact absorption (matches ref)
        else {
            int dr = 4 * t + j - q;
            dr = dr < -R_ ? -R_ : (dr > R_ ? R_ : dr);
            x += qrow[dr + R_];
        }
        vv[j] = x;
    }
    float mx = fmaxf(fmaxf(vv[0], vv[1]), fmaxf(vv[2], vv[3]));
#pragma unroll
    for (int ofs = 32; ofs > 0; ofs >>= 1) mx = fmaxf(mx, __shfl_xor(mx, ofs, 64));
    __shared__ float redm[4];
    __shared__ float reds[4];
    const int wave = t >> 6;
    if ((t & 63) == 0) redm[wave] = mx;
    __syncthreads();
    mx = fmaxf(fmaxf(redm[0], redm[1]), fmaxf(redm[2], redm[3]));
    float sum = 0.f;
#pragma unroll
    for (int j = 0; j < 4; ++j) { vv[j] = expf(vv[j] - mx); sum += vv[j]; }
#pragma unroll
    for (int ofs = 32; ofs > 0; ofs >>= 1) sum += __shfl_xor(sum, ofs, 64);
    if ((t & 63) == 0) reds[wave] = sum;
    __syncthreads();
    sum = reds[0] + reds[1] + reds[2] + reds[3];
    const float inv = 1.0f / sum;
    float4 v; v.x = vv[0] * inv; v.y = vv[1] * inv; v.z = vv[2] * inv; v.w = vv[3] * inv;
    *(float4*)&o[4 * t] = v;
    ushort4 ob; ob.x = f2bf(v.x); ob.y = f2bf(v.y); ob.z = f2bf(v.z); ob.w = f2bf(v.w);
    *(ushort4*)&a[4 * t] = ob;
}

// ---------------------------------------------------------------------------
__global__ __launch_bounds__(256) void k_count(const int* __restrict__ attm, float* __restrict__ counts)
{
    const int b = blockIdx.x, t = threadIdx.x;
    int c = 0;
    for (int k = t; k < L_; k += 256) c += (attm[b * L_ + k] != 0);
#pragma unroll
    for (int o = 32; o > 0; o >>= 1) c += __shfl_xor(c, o, 64);
    __shared__ int red[4];
    if ((t & 63) == 0) red[t >> 6] = c;
    __syncthreads();
    if (t == 0) counts[b] = (float)(red[0] + red[1] + red[2] + red[3]);
}

__global__ __launch_bounds__(256) void k_batchsum(
    const float* __restrict__ hid, const int* __restrict__ attm, float* __restrict__ pooled)
{
    const int b = blockIdx.x;
    const int d = blockIdx.y * 256 + threadIdx.x;
    const int k0 = blockIdx.z * 128;
    const float* hb = hid + (long)b * L_ * D_;
    float acc = 0.f;
    for (int k = k0; k < k0 + 128; ++k)
        acc += attm[b * L_ + k] ? hb[(long)k * D_ + d] : 0.f;
    atomicAdd(&pooled[b * D_ + d], acc);
}

__global__ __launch_bounds__(256) void k_pw2(
    const float* __restrict__ pooled, const float* __restrict__ W_sp, float* __restrict__ pw2)
{
    const int b = blockIdx.x;
    const int n = blockIdx.y * 256 + threadIdx.x;
    const int d0 = blockIdx.z * 96;
    float acc = 0.f;
    for (int d = d0; d < d0 + 96; ++d)
        acc += pooled[b * D_ + d] * W_sp[(long)(D_ + d) * D_ + n];
    atomicAdd(&pw2[b * D_ + n], acc);
}

__global__ __launch_bounds__(256) void k_addend0m(
    const float* __restrict__ pw2, const float* __restrict__ counts,
    const int* __restrict__ srcm, const int* __restrict__ spw,
    unsigned short* __restrict__ out, float* __restrict__ outM)
{
    const long idx = (long)blockIdx.x * 256 + threadIdx.x;
    const int d = (int)(idx % D_);
    const long m = idx / D_;
    const int b = (int)(m >> 10);
    const float inv = 1.0f / fmaxf(counts[b], 1.0f);
    out[idx] = f2bf(srcm[m] ? pw2[b * D_ + d] * inv : 0.0f);
    if (idx < (long)B_ * L_ * NSP)
        outM[idx] = ((int)(idx & 3) < spw[idx >> 2]) ? 1.0f : 0.0f;
}

// ---------------------------------------------------------------------------
extern "C" void kernel_launch(void* const* d_in, const int* in_sizes, int n_in,
                              void* d_out, int out_size, void* d_ws, size_t ws_size,
                              hipStream_t stream)
{
    (void)in_sizes; (void)n_in; (void)out_size; (void)ws_size;
    const float* hid     = (const float*)d_in[0];
    const float* src_hid = (const float*)d_in[1];
    const int*   spw     = (const int*)d_in[2];
    const int*   attm    = (const int*)d_in[3];
    const int*   srcm    = (const int*)d_in[4];
    const float* Wq_st = (const float*)d_in[6];
    const float* bq_st = (const float*)d_in[7];
    const float* Wk_st = (const float*)d_in[8];
    const float* rel_st= (const float*)d_in[10];
    const float* Wq_ed = (const float*)d_in[11];
    const float* bq_ed = (const float*)d_in[12];
    const float* Wk_ed = (const float*)d_in[13];
    const float* rel_ed= (const float*)d_in[15];
    const float* W_sp  = (const float*)d_in[16];
    const float* b_sp  = (const float*)d_in[17];

    float* out      = (float*)d_out;
    float* outSts   = out;
    float* outEds   = out + (long)B_ * L_ * NSP * L_;
    float* outMasks = outEds + (long)B_ * L_ * NSP * L_;

    const long S = (long)B_ * L_ * D_;
    const long DD = (long)D_ * D_;
    const long ML = (long)B_ * L_;
    char* wsB = (char*)d_ws;
    auto take = [&](size_t bytes) -> char* {
        char* p = wsB; wsB += (bytes + 255) & ~(size_t)255; return p;
    };
    unsigned short* hid_bf  = (unsigned short*)take(S * 2);
    unsigned short* src_bf  = (unsigned short*)take(S * 2);
    unsigned short* h1a     = (unsigned short*)take(S * 2);
    unsigned short* h1b     = (unsigned short*)take(S * 2);
    unsigned short* h2a     = (unsigned short*)take(S * 2);
    unsigned short* h2b     = (unsigned short*)take(S * 2);
    unsigned short* tmpP    = (unsigned short*)take(S * 2);
    unsigned short* hidW2T  = (unsigned short*)take(S * 2);   // [B][D][L]
    unsigned short* add0    = (unsigned short*)take(S * 2);
    unsigned short* hidGst  = (unsigned short*)take(S * 2);
    unsigned short* hidGed  = (unsigned short*)take(S * 2);
    unsigned short* GtTst   = (unsigned short*)take(DD * 2);
    unsigned short* GtTed   = (unsigned short*)take(DD * 2);
    unsigned short* W1T     = (unsigned short*)take(DD * 2);  // contiguous with W2T
    unsigned short* W2T     = (unsigned short*)take(DD * 2);
    unsigned short* WqBfSt  = (unsigned short*)take(DD * 2);
    unsigned short* WqBfEd  = (unsigned short*)take(DD * 2);
    unsigned short* WkBfSt  = (unsigned short*)take(DD * 2);
    unsigned short* WkBfEd  = (unsigned short*)take(DD * 2);
    unsigned short* relbst  = (unsigned short*)take((long)128 * D_ * 2);
    unsigned short* relbed  = (unsigned short*)take((long)128 * D_ * 2);
    unsigned short* WqrelSt = (unsigned short*)take((long)256 * D_ * 2);
    unsigned short* WqrelEd = (unsigned short*)take((long)256 * D_ * 2);
    unsigned short* attn_st = (unsigned short*)take(ML * L_ * 2);
    unsigned short* attn_ed = (unsigned short*)take(ML * L_ * 2);
    unsigned short* scrSt   = (unsigned short*)take(ML * L_ * 2);   // fp16 scores
    unsigned short* scrEd   = (unsigned short*)take(ML * L_ * 2);
    float* qrelbSt = (float*)take(ML * NREL * 4);
    float* qrelbEd = (float*)take(ML * NREL * 4);
    float* biasQst = (float*)take(896 * 4);
    float* biasQed = (float*)take(896 * 4);
    float* btermSt = (float*)take(ML * 4);
    float* btermEd = (float*)take(ML * 4);
    float* pooled  = (float*)take((long)B_ * D_ * 4);
    float* pw2     = (float*)take((long)B_ * D_ * 4);
    float* counts  = (float*)take(256);
    int*   lists   = (int*)take((long)32 * 1024 * 4);
    int*   cnt     = (int*)take(128);

    const float invs = 1.0f / sqrtf((float)D_);
    const long BB   = (long)L_ * D_;
    const int  NOB  = 1 << 30;

    PSet4 ps;
    auto clr = [&](int i) {
        ps.s[i] = PSet{nullptr,nullptr,nullptr,nullptr,nullptr,nullptr,nullptr,
                       nullptr,nullptr,0,0,1L<<40,1.f,0,0,1<<30};
    };

    // ---- prep ----
    {
        Zero8 z;
        z.p[0] = (float4*)(relbst + (long)NREL * D_);  z.n4[0] = (long)(128 - NREL) * D_ * 2 / 16;
        z.p[1] = (float4*)(relbed + (long)NREL * D_);  z.n4[1] = (long)(128 - NREL) * D_ * 2 / 16;
        z.p[2] = (float4*)(WqrelSt + (long)128 * D_);  z.n4[2] = (long)128 * D_ * 2 / 16;
        z.p[3] = (float4*)(WqrelEd + (long)128 * D_);  z.n4[3] = (long)128 * D_ * 2 / 16;
        z.p[4] = (float4*)pooled;                      z.n4[4] = (long)B_ * D_ / 4;
        z.p[5] = (float4*)pw2;                         z.n4[5] = (long)B_ * D_ / 4;
        z.p[6] = (float4*)cnt;                         z.n4[6] = 8;   // 32 ints
        z.p[7] = nullptr;                              z.n4[7] = 0;
        long tot = 0; for (int i = 0; i < 8; ++i) tot += z.n4[i];
        k_zero8<<<(int)((tot + 255) / 256), 256, 0, stream>>>(z);
    }
    {
        Cvt8 c;
        c.src[0] = hid;     c.dst[0] = hid_bf;  c.n4[0] = S / 4;
        c.src[1] = src_hid; c.dst[1] = src_bf;  c.n4[1] = S / 4;
        c.src[2] = Wq_st;   c.dst[2] = WqBfSt;  c.n4[2] = DD / 4;
        c.src[3] = Wq_ed;   c.dst[3] = WqBfEd;  c.n4[3] = DD / 4;
        c.src[4] = Wk_st;   c.dst[4] = WkBfSt;  c.n4[4] = DD / 4;
        c.src[5] = Wk_ed;   c.dst[5] = WkBfEd;  c.n4[5] = DD / 4;
        c.src[6] = rel_st;  c.dst[6] = relbst;  c.n4[6] = (long)NREL * D_ / 4;
        c.src[7] = rel_ed;  c.dst[7] = relbed;  c.n4[7] = (long)NREL * D_ / 4;
        long tot = 0; for (int i = 0; i < 8; ++i) tot += c.n4[i];
        k_cvt8<<<(int)((tot + 255) / 256), 256, 0, stream>>>(c);
    }
    k_transpose<<<dim3(D_ / 32, D_ / 32, 2), 256, 0, stream>>>(W_sp, W1T, D_, D_);
    k_biasq<<<dim3(224, 2), 256, 0, stream>>>(bq_st, bq_ed, Wk_st, Wk_ed,
                                              rel_st, rel_ed, biasQst, biasQed);
    k_count<<<B_, 256, 0, stream>>>(attm, counts);
    k_batchsum<<<dim3(B_, D_ / 256, 8), 256, 0, stream>>>(hid, attm, pooled);
    k_pw2<<<dim3(B_, D_ / 256, 8), 256, 0, stream>>>(pooled, W_sp, pw2);
    k_addend0m<<<(int)(S / 256), 256, 0, stream>>>(pw2, counts, srcm, spw, add0, outMasks);
    k_bterm<<<dim3(B_ * L_ / 4, 2), 256, 0, stream>>>(hid_bf, biasQst, biasQed,
                                                      btermSt, btermEd, invs);
    k_lists<<<(int)(ML / 256), 256, 0, stream>>>(spw, lists, cnt);
    k_padlists<<<32, 256, 0, stream>>>(lists, cnt);
    k_fillu<<<dim3(B_ * L_, NSP), 256, 0, stream>>>(spw, outSts, outEds);

    // GtT (Wq.Wk^T) + Wqrel (rel.Wq^T), 2-phase 128^2 kernel, z=4
    for (int i = 0; i < 4; ++i) clr(i);
    ps.s[0].A0 = WqBfSt; ps.s[0].B0 = WkBfSt; ps.s[0].Cout = GtTst;   ps.s[0].cStride = D_; ps.s[0].mValid = D_;
    ps.s[1].A0 = WqBfEd; ps.s[1].B0 = WkBfEd; ps.s[1].Cout = GtTed;   ps.s[1].cStride = D_; ps.s[1].mValid = D_;
    ps.s[2].A0 = relbst; ps.s[2].B0 = WqBfSt; ps.s[2].Cout = WqrelSt; ps.s[2].cStride = D_; ps.s[2].mValid = 128;
    ps.s[3].A0 = relbed; ps.s[3].B0 = WqBfEd; ps.s[3].Cout = WqrelEd; ps.s[3].cStride = D_; ps.s[3].mValid = 128;
    k_mfma_prep<<<dim3(D_ / 128, D_ / 128, 4), 256, 0, stream>>>(ps, D_, D_, D_);

    // concat0 (src@W1+add0, relu) + hid@W2 + hidG st/ed : one z=4 8-phase dispatch
    for (int i = 0; i < 4; ++i) clr(i);
    ps.s[0].A0 = src_bf; ps.s[0].B0 = W1T;   ps.s[0].bias = b_sp; ps.s[0].addend = add0;
    ps.s[0].Cout = h1a;  ps.s[0].cStride = D_; ps.s[0].relu = 1; ps.s[0].nValid = D_;
    ps.s[1].A0 = hid_bf; ps.s[1].B0 = W2T;   ps.s[1].Cout = tmpP;   ps.s[1].cStride = D_; ps.s[1].nValid = D_;
    ps.s[2].A0 = hid_bf; ps.s[2].B0 = GtTst; ps.s[2].Cout = hidGst; ps.s[2].cStride = D_; ps.s[2].scale = invs; ps.s[2].nValid = D_;
    ps.s[3].A0 = hid_bf; ps.s[3].B0 = GtTed; ps.s[3].Cout = hidGed; ps.s[3].cStride = D_; ps.s[3].scale = invs; ps.s[3].nValid = D_;
    k_mfma8<<<dim3(D_ / 256, (B_ * L_) / 256, 4), 512, 0, stream>>>(
        ps, D_, D_, NOB, D_, D_, D_, 0, nullptr, nullptr, nullptr, nullptr, nullptr, 0);
    k_transpose_bf<<<dim3(D_ / 32, L_ / 32, B_), 256, 0, stream>>>(tmpP, hidW2T, L_, D_);

    unsigned short* h1cur = h1a; unsigned short* h2cur = h1a;
    unsigned short* h1nxt = h1b; unsigned short* h2nxt = h2a;

    for (int it = 0; it < NSP; ++it) {
        const int* rowsIt = lists + (long)it * 8 * 1024;
        const int* cntIt  = cnt + it * 8;
        if (it > 0) {
            // compacted fused pooling+concat: attn@hidW2T (K=1024) + hcur@W1 (K=768)
            for (int i = 0; i < 4; ++i) clr(i);
            ps.s[0].A0 = attn_st; ps.s[0].B0 = hidW2T; ps.s[0].A1 = h1cur; ps.s[0].B1 = W1T;
            ps.s[0].bias = b_sp; ps.s[0].Cout = h1nxt; ps.s[0].cStride = D_;
            ps.s[0].relu = 1; ps.s[0].bB0 = (long)D_ * L_; ps.s[0].nValid = D_;
            ps.s[1] = ps.s[0];
            ps.s[1].A0 = attn_ed; ps.s[1].A1 = h2cur; ps.s[1].Cout = h2nxt;
            k_mfma8<<<dim3(D_ / 256, 32, 2), 512, 0, stream>>>(
                ps, L_, L_, L_, L_, D_, D_, D_, rowsIt, cntIt, nullptr, nullptr, nullptr, it);
            h1cur = h1nxt; h2cur = h2nxt;
            h1nxt = (h1cur == h1a) ? h1b : h1a;
            h2nxt = (h2cur == h2a) ? h2b : h2a;
        }
        // compacted scores (z0,z1 -> fp16 scratch) + qrel (z2,z3)
        for (int i = 0; i < 4; ++i) clr(i);
        ps.s[0].A0 = h1cur; ps.s[0].B0 = hidGst; ps.s[0].Cout = scrSt;
        ps.s[0].bterm = btermSt; ps.s[0].bB0 = BB; ps.s[0].mode = 1;
        ps.s[0].cStride = L_; ps.s[0].nValid = L_;
        ps.s[1].A0 = h2cur; ps.s[1].B0 = hidGed; ps.s[1].Cout = scrEd;
        ps.s[1].bterm = btermEd; ps.s[1].bB0 = BB; ps.s[1].mode = 1;
        ps.s[1].cStride = L_; ps.s[1].nValid = L_;
        ps.s[2].A0 = h1cur; ps.s[2].B0 = WqrelSt; ps.s[2].qout = qrelbSt;
        ps.s[2].bias = biasQst + D_; ps.s[2].scale = invs; ps.s[2].mode = 2; ps.s[2].nValid = 256;
        ps.s[3].A0 = h2cur; ps.s[3].B0 = WqrelEd; ps.s[3].qout = qrelbEd;
        ps.s[3].bias = biasQed + D_; ps.s[3].scale = invs; ps.s[3].mode = 2; ps.s[3].nValid = 256;
        k_mfma8<<<dim3(L_ / 256, 32, 4), 512, 0, stream>>>(
            ps, D_, D_, L_, D_, D_, D_, 0, rowsIt, cntIt, spw, srcm, attm, it);
        // compacted softmax (rel-gather fused) st+ed
        k_softmax<<<dim3(B_ * L_, 2), 256, 0, stream>>>(
            scrSt, scrEd, outSts, outEds, attn_st, attn_ed,
            qrelbSt, qrelbEd, rowsIt, cntIt, it);
    }
}

// Round 9
// 879.666 us; speedup vs baseline: 1.2232x; 1.2232x over previous
//
#include <hip/hip_runtime.h>
#include <math.h>

#define B_   8
#define L_   1024
#define D_   768
#define R_   16
#define NSP  4
#define NREL 33

typedef __attribute__((ext_vector_type(8))) short bf16x8;
typedef __attribute__((ext_vector_type(4))) float f32x4;
typedef __attribute__((address_space(1))) const void gv_t;
typedef __attribute__((address_space(3))) void sv_t;

__device__ __forceinline__ unsigned short f2bf(float f) {
    unsigned int u = __float_as_uint(f);
    u += 0x7fff + ((u >> 16) & 1);          // RNE
    return (unsigned short)(u >> 16);
}
__device__ __forceinline__ float bf2f(unsigned short s) {
    return __uint_as_float(((unsigned int)s) << 16);
}
__device__ __forceinline__ unsigned short f2h(float f) {
    _Float16 h = (_Float16)f;
    return *(unsigned short*)&h;
}
__device__ __forceinline__ float h2f(unsigned short u) {
    _Float16 h = *(_Float16*)&u;
    return (float)h;
}

struct PSet {
    const unsigned short* A0;
    const unsigned short* B0;
    const unsigned short* A1;   // dual-K phase 2
    const unsigned short* B1;
    const float*          bias;
    const unsigned short* addend;
    void*                 Cout;
    float*                qout;    // mode 2 output (fp32 qrel)
    const float*          bterm;   // mode 1 per-key bias
    long                  bB0;     // per-batch stride of B0 (0 = unbatched)
    long                  cStride;
    long                  mValid;  // prep kernel row guard
    float                 scale;
    int                   mode;    // 0=bf16 C, 1=scores->fp16 scratch, 2=qrel
    int                   relu;
    int                   nValid;  // early-exit when col0 >= nValid
};
struct PSet4 { PSet s[4]; };

// ===========================================================================
// 8-phase 256x256 MFMA GEMM (T2+T3+T4+T5). BK=64, 8 waves (2Mx4N), 512 thr.
// LDS 128 KiB dbuf, st_16x32 XOR-swizzle reads + inverse-swizzled global src,
// linear global_load_lds dest, counted vmcnt(4). Runtime per-z mode/epilogue.
// Optional row compaction: rows/cntp non-null -> per-batch gathered A rows,
// scattered C rows; blockIdx.y = b*4 + tile; tile past cntp[b] exits.
__global__ __launch_bounds__(512, 2) void k_mfma8(
    PSet4 ps, long aS0, long bS0, int bR0, int K0,
    long aS1, long bS1, int K1,
    const int* __restrict__ rows, const int* __restrict__ cntp,
    const int* __restrict__ spw, const int* __restrict__ srcm,
    const int* __restrict__ attm, int it)
{
    PSet p = ps.s[blockIdx.z];
    const int col0 = blockIdx.x * 256;
    if (col0 >= p.nValid) return;

    int b, tile; long row0;
    const int* rowsb = nullptr;
    if (rows) {
        b = blockIdx.y >> 2; tile = blockIdx.y & 3;
        if (tile * 256 >= cntp[b]) return;
        rowsb = rows + b * 1024 + tile * 256;
        row0 = 0;
    } else {
        row0 = (long)blockIdx.y * 256;
        b = (int)(row0 >> 10); tile = 0;
    }

    __shared__ unsigned short lds[2][2][256 * 64];   // 128 KiB

    const int tid  = threadIdx.x;
    const int lane = tid & 63;
    const int wave = tid >> 6;
    const int wr = wave >> 2;           // 0..1 (M half)
    const int wc = wave & 3;            // 0..3 (N quarter)
    const int lq = lane >> 4, lr = lane & 15;

    const unsigned short* Bb0 = p.B0 + (rows ? (long)b * p.bB0
                                             : (row0 / bR0) * p.bB0);

    // preload A-gather indices (4 per lane, constant over K loop)
    int ridxA[2][2];
#pragma unroll
    for (int h = 0; h < 2; ++h)
#pragma unroll
        for (int j = 0; j < 2; ++j) {
            const int r = h * 128 + j * 64 + wave * 8 + (lane >> 3);
            ridxA[j][h] = rowsb ? rowsb[r] : (int)(row0 + r);
        }

    const int NT0 = K0 / 64;
    const int NT  = NT0 + K1 / 64;

    f32x4 acc[8][4];
#pragma unroll
    for (int m = 0; m < 8; ++m)
#pragma unroll
        for (int n = 0; n < 4; ++n) acc[m][n] = (f32x4)0.f;

    auto stageHalf = [&](int tt, int side, int h) {
        if (tt >= NT) return;
        const unsigned short* src; long stride; int k0;
        if (tt < NT0) { src = side ? Bb0  : p.A0; stride = side ? bS0 : aS0; k0 = tt * 64; }
        else          { src = side ? p.B1 : p.A1; stride = side ? bS1 : aS1; k0 = (tt - NT0) * 64; }
        unsigned short* dst = &lds[tt & 1][side][h * 8192];
#pragma unroll
        for (int j = 0; j < 2; ++j) {
            const int r = j * 64 + wave * 8 + (lane >> 3);
            const int csrc = ((lane & 7) * 8) ^ (((r >> 2) & 1) << 4);
            const long grow = side ? (long)(col0 + h * 128 + r) : (long)ridxA[j][h];
            const unsigned short* g = src + grow * stride + k0 + csrc;
            __builtin_amdgcn_global_load_lds((gv_t*)g,
                (sv_t*)(dst + j * 4096 + wave * 512), 16, 0, 0);
        }
    };
    auto rd = [&](int bt, int side, int r, int ks) -> bf16x8 {
        const int idx = r * 64 + (((ks << 5) | (lq << 3)) ^ (((r >> 2) & 1) << 4));
        return *(const bf16x8*)&lds[bt][side][idx];
    };

    stageHalf(0, 0, 0); stageHalf(0, 0, 1);
    stageHalf(0, 1, 0); stageHalf(0, 1, 1);
    stageHalf(1, 1, 0); stageHalf(1, 1, 1);
    if (1 < NT) asm volatile("s_waitcnt vmcnt(4)" ::: "memory");
    else        asm volatile("s_waitcnt vmcnt(0)" ::: "memory");
    __builtin_amdgcn_s_barrier();

    bf16x8 af[4][2], bfr[4][2];

    for (int t = 0; t < NT; ++t) {
        const int bt = t & 1;
        // phase 1: read A m0-3 + B n0-1; stage (t+1).A0
#pragma unroll
        for (int mf = 0; mf < 4; ++mf)
#pragma unroll
            for (int ks = 0; ks < 2; ++ks)
                af[mf][ks] = rd(bt, 0, wr * 128 + mf * 16 + lr, ks);
#pragma unroll
        for (int nf = 0; nf < 2; ++nf)
#pragma unroll
            for (int ks = 0; ks < 2; ++ks)
                bfr[nf][ks] = rd(bt, 1, wc * 64 + nf * 16 + lr, ks);
        stageHalf(t + 1, 0, 0);
        __builtin_amdgcn_s_barrier();
        asm volatile("s_waitcnt lgkmcnt(0)" ::: "memory");
        __builtin_amdgcn_sched_barrier(0);
        __builtin_amdgcn_s_setprio(1);
#pragma unroll
        for (int nf = 0; nf < 2; ++nf)
#pragma unroll
            for (int mf = 0; mf < 4; ++mf)
#pragma unroll
                for (int ks = 0; ks < 2; ++ks)
                    acc[mf][nf] = __builtin_amdgcn_mfma_f32_16x16x32_bf16(
                        af[mf][ks], bfr[nf][ks], acc[mf][nf], 0, 0, 0);
        __builtin_amdgcn_s_setprio(0);
        __builtin_amdgcn_s_barrier();
        // phase 2: read B n2-3; stage (t+1).A1
#pragma unroll
        for (int nf = 2; nf < 4; ++nf)
#pragma unroll
            for (int ks = 0; ks < 2; ++ks)
                bfr[nf][ks] = rd(bt, 1, wc * 64 + nf * 16 + lr, ks);
        stageHalf(t + 1, 0, 1);
        __builtin_amdgcn_s_barrier();
        asm volatile("s_waitcnt lgkmcnt(0)" ::: "memory");
        __builtin_amdgcn_sched_barrier(0);
        __builtin_amdgcn_s_setprio(1);
#pragma unroll
        for (int nf = 2; nf < 4; ++nf)
#pragma unroll
            for (int mf = 0; mf < 4; ++mf)
#pragma unroll
                for (int ks = 0; ks < 2; ++ks)
                    acc[mf][nf] = __builtin_amdgcn_mfma_f32_16x16x32_bf16(
                        af[mf][ks], bfr[nf][ks], acc[mf][nf], 0, 0, 0);
        __builtin_amdgcn_s_setprio(0);
        __builtin_amdgcn_s_barrier();
        // phase 3: read A m4-7; stage (t+2).B0
#pragma unroll
        for (int mf = 0; mf < 4; ++mf)
#pragma unroll
            for (int ks = 0; ks < 2; ++ks)
                af[mf][ks] = rd(bt, 0, wr * 128 + 64 + mf * 16 + lr, ks);
        stageHalf(t + 2, 1, 0);
        __builtin_amdgcn_s_barrier();
        asm volatile("s_waitcnt lgkmcnt(0)" ::: "memory");
        __builtin_amdgcn_sched_barrier(0);
        __builtin_amdgcn_s_setprio(1);
#pragma unroll
        for (int nf = 0; nf < 2; ++nf)
#pragma unroll
            for (int mf = 0; mf < 4; ++mf)
#pragma unroll
                for (int ks = 0; ks < 2; ++ks)
                    acc[4 + mf][nf] = __builtin_amdgcn_mfma_f32_16x16x32_bf16(
                        af[mf][ks], bfr[nf][ks], acc[4 + mf][nf], 0, 0, 0);
        __builtin_amdgcn_s_setprio(0);
        __builtin_amdgcn_s_barrier();
        // phase 4: stage (t+2).B1; counted vmcnt; MFMA m4-7 x n2-3
        stageHalf(t + 2, 1, 1);
        if (t + 2 < NT) asm volatile("s_waitcnt vmcnt(4)" ::: "memory");
        else            asm volatile("s_waitcnt vmcnt(0)" ::: "memory");
        __builtin_amdgcn_s_barrier();
        __builtin_amdgcn_sched_barrier(0);
        __builtin_amdgcn_s_setprio(1);
#pragma unroll
        for (int nf = 2; nf < 4; ++nf)
#pragma unroll
            for (int mf = 0; mf < 4; ++mf)
#pragma unroll
                for (int ks = 0; ks < 2; ++ks)
                    acc[4 + mf][nf] = __builtin_amdgcn_mfma_f32_16x16x32_bf16(
                        af[mf][ks], bfr[nf][ks], acc[4 + mf][nf], 0, 0, 0);
        __builtin_amdgcn_s_setprio(0);
        __builtin_amdgcn_s_barrier();
    }

    auto mgof = [&](int r) -> long {
        return rowsb ? (long)rowsb[r] : row0 + r;
    };

    // ---------------- epilogue (runtime mode) ----------------
    if (p.mode == 0) {
        unsigned short* C = (unsigned short*)p.Cout;
#pragma unroll
        for (int nf = 0; nf < 4; ++nf) {
            const int col = col0 + wc * 64 + nf * 16 + lr;
            const float bc = p.bias ? p.bias[col] : 0.f;
#pragma unroll
            for (int mf = 0; mf < 8; ++mf) {
#pragma unroll
                for (int rr = 0; rr < 4; ++rr) {
                    const long row = mgof(wr * 128 + mf * 16 + lq * 4 + rr);
                    float v = acc[mf][nf][rr] + bc;
                    if (p.addend) v += bf2f(p.addend[row * p.cStride + col]);
                    v *= p.scale;
                    if (p.relu) v = fmaxf(v, 0.f);
                    C[row * p.cStride + col] = f2bf(v);
                }
            }
        }
    } else if (p.mode == 1) {
        unsigned short* C = (unsigned short*)p.Cout;   // fp16 scratch [m][L]
        int amv[4]; float btv[4];
#pragma unroll
        for (int nf = 0; nf < 4; ++nf) {
            const int col = col0 + wc * 64 + nf * 16 + lr;
            amv[nf] = attm[b * L_ + col];
            btv[nf] = p.bterm[b * L_ + col];
        }
#pragma unroll
        for (int mf = 0; mf < 8; ++mf) {
#pragma unroll
            for (int rr = 0; rr < 4; ++rr) {
                const long mg = mgof(wr * 128 + mf * 16 + lq * 4 + rr);
                const bool rowAct = (it < spw[mg]) && (srcm[mg] != 0);
#pragma unroll
                for (int nf = 0; nf < 4; ++nf) {
                    const int col = col0 + wc * 64 + nf * 16 + lr;
                    const float v = (rowAct && amv[nf]) ? (acc[mf][nf][rr] + btv[nf]) : -60000.f;
                    C[mg * L_ + col] = f2h(v);
                }
            }
        }
    } else {   // mode 2: qrel fp32 (col < NREL)
        float* qout = p.qout;
#pragma unroll
        for (int nf = 0; nf < 3; ++nf) {
            const int col = wc * 64 + nf * 16 + lr;
            if (col < NREL) {
                const float bc = p.bias[col];
#pragma unroll
                for (int mf = 0; mf < 8; ++mf)
#pragma unroll
                    for (int rr = 0; rr < 4; ++rr) {
                        const long mg = mgof(wr * 128 + mf * 16 + lq * 4 + rr);
                        qout[mg * NREL + col] = (acc[mf][nf][rr] + bc) * p.scale;
                    }
            }
        }
    }
}

// ===========================================================================
// 2-phase 128x128 kernel (prep-only: GtT / Wqrel, small M)
__global__ __launch_bounds__(256) void k_mfma_prep(
    PSet4 ps, long aS0, long bS0, int K0)
{
    PSet p = ps.s[blockIdx.z];
    const long row0 = (long)blockIdx.y * 128;
    if (row0 >= p.mValid) return;
    const int col0 = blockIdx.x * 128;

    __shared__ unsigned short As[2][128 * 32];
    __shared__ unsigned short Bs[2][128 * 32];
    const int tid  = threadIdx.x;
    const int lane = tid & 63;
    const int wave = tid >> 6;
    const int wr = wave >> 1, wc = wave & 1;
    const int lq = lane >> 4, lr = lane & 15;
    const int sr = lane >> 2;
    const int sc = (lane & 3) * 8;

    f32x4 acc[4][4];
#pragma unroll
    for (int m = 0; m < 4; ++m)
#pragma unroll
        for (int n = 0; n < 4; ++n) acc[m][n] = (f32x4)0.f;

    const int NT = K0 / 32;
    auto stage = [&](int t, int buf) {
        const int k0 = t * 32;
#pragma unroll
        for (int j = 0; j < 2; ++j) {
            const int c = wave + j * 4;
            const unsigned short* ga = p.A0 + (row0 + c * 16 + sr) * aS0 + k0 + sc;
            const unsigned short* gb = p.B0 + (long)(col0 + c * 16 + sr) * bS0 + k0 + sc;
            __builtin_amdgcn_global_load_lds((gv_t*)ga, (sv_t*)&As[buf][c * 512], 16, 0, 0);
            __builtin_amdgcn_global_load_lds((gv_t*)gb, (sv_t*)&Bs[buf][c * 512], 16, 0, 0);
        }
    };
    stage(0, 0);
    asm volatile("s_waitcnt vmcnt(0)" ::: "memory");
    __builtin_amdgcn_s_barrier();
    int cur = 0;
    for (int t = 0; t < NT; ++t) {
        if (t + 1 < NT) stage(t + 1, cur ^ 1);
        bf16x8 a4[4], b4[4];
#pragma unroll
        for (int m = 0; m < 4; ++m)
            a4[m] = *(const bf16x8*)&As[cur][(wr * 64 + m * 16 + lr) * 32 + lq * 8];
#pragma unroll
        for (int n = 0; n < 4; ++n)
            b4[n] = *(const bf16x8*)&Bs[cur][(wc * 64 + n * 16 + lr) * 32 + lq * 8];
#pragma unroll
        for (int m = 0; m < 4; ++m)
#pragma unroll
            for (int n = 0; n < 4; ++n)
                acc[m][n] = __builtin_amdgcn_mfma_f32_16x16x32_bf16(a4[m], b4[n], acc[m][n], 0, 0, 0);
        asm volatile("s_waitcnt vmcnt(0)" ::: "memory");
        __builtin_amdgcn_s_barrier();
        cur ^= 1;
    }
    unsigned short* C = (unsigned short*)p.Cout;
#pragma unroll
    for (int n = 0; n < 4; ++n) {
        const int col = col0 + wc * 64 + n * 16 + lr;
#pragma unroll
        for (int m = 0; m < 4; ++m)
#pragma unroll
            for (int r = 0; r < 4; ++r) {
                const long row = row0 + wr * 64 + m * 16 + lq * 4 + r;
                C[row * p.cStride + col] = f2bf(acc[m][n][r]);
            }
    }
}

// ---------------------------------------------------------------------------
struct Zero8 { float4* p[8]; long n4[8]; };
__global__ __launch_bounds__(256) void k_zero8(Zero8 z)
{
    long g = (long)blockIdx.x * 256 + threadIdx.x;
#pragma unroll
    for (int s = 0; s < 8; ++s) {
        if (g < z.n4[s]) {
            float4 v; v.x = v.y = v.z = v.w = 0.f;
            z.p[s][g] = v;
            return;
        }
        g -= z.n4[s];
    }
}

struct Cvt8 { const float* src[8]; unsigned short* dst[8]; long n4[8]; };
__global__ __launch_bounds__(256) void k_cvt8(Cvt8 c)
{
    long g = (long)blockIdx.x * 256 + threadIdx.x;
#pragma unroll
    for (int s = 0; s < 8; ++s) {
        if (g < c.n4[s]) {
            const float4 v = ((const float4*)c.src[s])[g];
            ushort4 o; o.x = f2bf(v.x); o.y = f2bf(v.y); o.z = f2bf(v.z); o.w = f2bf(v.w);
            ((ushort4*)c.dst[s])[g] = o;
            return;
        }
        g -= c.n4[s];
    }
}

__global__ __launch_bounds__(256) void k_transpose(
    const float* __restrict__ in, unsigned short* __restrict__ out, int rows, int cols)
{
    __shared__ float t[32][33];
    const long zo = (long)blockIdx.z * rows * cols;
    const int c0 = blockIdx.x * 32, r0 = blockIdx.y * 32;
    const int tx = threadIdx.x & 31, ty = threadIdx.x >> 5;
#pragma unroll
    for (int i = 0; i < 32; i += 8)
        t[ty + i][tx] = in[zo + (long)(r0 + ty + i) * cols + c0 + tx];
    __syncthreads();
#pragma unroll
    for (int i = 0; i < 32; i += 8)
        out[zo + (long)(c0 + ty + i) * rows + r0 + tx] = f2bf(t[tx][ty + i]);
}

__global__ __launch_bounds__(256) void k_transpose_bf(
    const unsigned short* __restrict__ in, unsigned short* __restrict__ out,
    int rows, int cols)
{
    __shared__ unsigned short t[32][33];
    const long zo = (long)blockIdx.z * rows * cols;
    const int c0 = blockIdx.x * 32, r0 = blockIdx.y * 32;
    const int tx = threadIdx.x & 31, ty = threadIdx.x >> 5;
#pragma unroll
    for (int i = 0; i < 32; i += 8)
        t[ty + i][tx] = in[zo + (long)(r0 + ty + i) * cols + c0 + tx];
    __syncthreads();
#pragma unroll
    for (int i = 0; i < 32; i += 8)
        out[zo + (long)(c0 + ty + i) * rows + r0 + tx] = t[tx][ty + i];
}

// ---------------------------------------------------------------------------
// biasQ[896]: [0..767] = bq.Wk[i,:]; [768+r] = bq.rel[r,:]; wave per output
__global__ __launch_bounds__(256) void k_biasq(
    const float* __restrict__ bq0, const float* __restrict__ bq1,
    const float* __restrict__ wk0, const float* __restrict__ wk1,
    const float* __restrict__ rel0, const float* __restrict__ rel1,
    float* __restrict__ out0, float* __restrict__ out1)
{
    const int z = blockIdx.y;
    const float* bq  = z ? bq1  : bq0;
    const float* wk  = z ? wk1  : wk0;
    const float* rel = z ? rel1 : rel0;
    float* out       = z ? out1 : out0;
    const int i = blockIdx.x * 4 + (threadIdx.x >> 6);
    const int lane = threadIdx.x & 63;
    const float* w = nullptr;
    if (i < D_) w = wk + (long)i * D_;
    else if (i - D_ < NREL) w = rel + (long)(i - D_) * D_;
    float a = 0.f;
    if (w)
        for (int e = lane * 4; e < D_; e += 256) {
            const float4 w4 = *(const float4*)&w[e];
            const float4 b4 = *(const float4*)&bq[e];
            a += w4.x * b4.x + w4.y * b4.y + w4.z * b4.z + w4.w * b4.w;
        }
#pragma unroll
    for (int o = 32; o > 0; o >>= 1) a += __shfl_xor(a, o, 64);
    if (lane == 0) out[i] = a;
}

// bterm[m] = invs * sum_d biasQ[d] * hid[m,d]
__global__ __launch_bounds__(256) void k_bterm(
    const unsigned short* __restrict__ hid_bf,
    const float* __restrict__ biasQ0, const float* __restrict__ biasQ1,
    float* __restrict__ out0, float* __restrict__ out1, float invs)
{
    const float* biasQ = blockIdx.y ? biasQ1 : biasQ0;
    float* out = blockIdx.y ? out1 : out0;
    const long row = (long)blockIdx.x * 4 + (threadIdx.x >> 6);
    const int lane = threadIdx.x & 63;
    const unsigned short* h = hid_bf + row * D_;
    float a = 0.f;
    for (int d = lane * 4; d < D_; d += 256) {
        const ushort4 u = *(const ushort4*)&h[d];
        const float4 bq4 = *(const float4*)&biasQ[d];
        a += bf2f(u.x) * bq4.x + bf2f(u.y) * bq4.y + bf2f(u.z) * bq4.z + bf2f(u.w) * bq4.w;
    }
#pragma unroll
    for (int o = 32; o > 0; o >>= 1) a += __shfl_xor(a, o, 64);
    if (lane == 0) out[row] = a * invs;
}

// ---------------------------------------------------------------------------
// active-row lists per (it, batch) via block prefix scan — NO global atomics.
// One block per (b, it); ascending-m deterministic; pads tail with first row.
__global__ __launch_bounds__(256) void k_lists(
    const int* __restrict__ spw, int* __restrict__ lists, int* __restrict__ cnt)
{
    const int b = blockIdx.x, it = blockIdx.y;
    const int t = threadIdx.x;
    __shared__ int sc[256];
    const int base = b * 1024 + t * 4;
    int pred[4]; int c = 0;
#pragma unroll
    for (int j = 0; j < 4; ++j) { pred[j] = (spw[base + j] > it) ? 1 : 0; c += pred[j]; }
    sc[t] = c;
    __syncthreads();
    for (int ofs = 1; ofs < 256; ofs <<= 1) {
        const int v = (t >= ofs) ? sc[t - ofs] : 0;
        __syncthreads();
        sc[t] += v;
        __syncthreads();
    }
    const int total = sc[255];
    int pos = sc[t] - c;                    // exclusive prefix
    int* dst = lists + (long)(it * 8 + b) * 1024;
#pragma unroll
    for (int j = 0; j < 4; ++j)
        if (pred[j]) dst[pos++] = base + j;
    if (t == 0) cnt[it * 8 + b] = total;
    __syncthreads();
    if (total > 0 && total < 1024) {
        const int v0 = dst[0];
        for (int j = total + t; j < 1024; j += 256) dst[j] = v0;
    }
}

// ---------------------------------------------------------------------------
// softmax over all rows: masked rows -> uniform 1/L (no scratch read);
// active rows: fp16 scratch + qrel gather -> fp32 d_out + bf16 attn
__global__ __launch_bounds__(256) void k_softmax(
    const unsigned short* __restrict__ sSt, const unsigned short* __restrict__ sEd,
    float* __restrict__ oSt, float* __restrict__ oEd,
    unsigned short* __restrict__ aSt, unsigned short* __restrict__ aEd,
    const float* __restrict__ qrSt, const float* __restrict__ qrEd,
    const int* __restrict__ spw, int it)
{
    const long m = blockIdx.x;
    float* o = (blockIdx.y ? oEd : oSt) + (m * NSP + it) * L_;
    const int t = threadIdx.x;
    if (spw[m] <= it) {                 // masked: exact uniform row
        float4 u; u.x = u.y = u.z = u.w = 0.0009765625f;
        *(float4*)&o[4 * t] = u;
        return;
    }
    const unsigned short* s = (blockIdx.y ? sEd : sSt) + m * L_;
    unsigned short* a = (blockIdx.y ? aEd : aSt) + m * L_;
    const float* qrow = (blockIdx.y ? qrEd : qrSt) + m * NREL;
    const int q = (int)(m & (L_ - 1));
    const ushort4 u = *(const ushort4*)&s[4 * t];
    float vv[4];
    const unsigned short* up = (const unsigned short*)&u;
#pragma unroll
    for (int j = 0; j < 4; ++j) {
        float x = h2f(up[j]);
        if (x < -3.0e4f) x = -1e18f;      // masked col: exact absorption
        else {
            int dr = 4 * t + j - q;
            dr = dr < -R_ ? -R_ : (dr > R_ ? R_ : dr);
            x += qrow[dr + R_];
        }
        vv[j] = x;
    }
    float mx = fmaxf(fmaxf(vv[0], vv[1]), fmaxf(vv[2], vv[3]));
#pragma unroll
    for (int ofs = 32; ofs > 0; ofs >>= 1) mx = fmaxf(mx, __shfl_xor(mx, ofs, 64));
    __shared__ float redm[4];
    __shared__ float reds[4];
    const int wave = t >> 6;
    if ((t & 63) == 0) redm[wave] = mx;
    __syncthreads();
    mx = fmaxf(fmaxf(redm[0], redm[1]), fmaxf(redm[2], redm[3]));
    float sum = 0.f;
#pragma unroll
    for (int j = 0; j < 4; ++j) { vv[j] = expf(vv[j] - mx); sum += vv[j]; }
#pragma unroll
    for (int ofs = 32; ofs > 0; ofs >>= 1) sum += __shfl_xor(sum, ofs, 64);
    if ((t & 63) == 0) reds[wave] = sum;
    __syncthreads();
    sum = reds[0] + reds[1] + reds[2] + reds[3];
    const float inv = 1.0f / sum;
    float4 v; v.x = vv[0] * inv; v.y = vv[1] * inv; v.z = vv[2] * inv; v.w = vv[3] * inv;
    *(float4*)&o[4 * t] = v;
    ushort4 ob; ob.x = f2bf(v.x); ob.y = f2bf(v.y); ob.z = f2bf(v.z); ob.w = f2bf(v.w);
    *(ushort4*)&a[4 * t] = ob;
}

// ---------------------------------------------------------------------------
__global__ __launch_bounds__(256) void k_count(const int* __restrict__ attm, float* __restrict__ counts)
{
    const int b = blockIdx.x, t = threadIdx.x;
    int c = 0;
    for (int k = t; k < L_; k += 256) c += (attm[b * L_ + k] != 0);
#pragma unroll
    for (int o = 32; o > 0; o >>= 1) c += __shfl_xor(c, o, 64);
    __shared__ int red[4];
    if ((t & 63) == 0) red[t >> 6] = c;
    __syncthreads();
    if (t == 0) counts[b] = (float)(red[0] + red[1] + red[2] + red[3]);
}

__global__ __launch_bounds__(256) void k_batchsum(
    const float* __restrict__ hid, const int* __restrict__ attm, float* __restrict__ pooled)
{
    const int b = blockIdx.x;
    const int d = blockIdx.y * 256 + threadIdx.x;
    const int k0 = blockIdx.z * 128;
    const float* hb = hid + (long)b * L_ * D_;
    float acc = 0.f;
    for (int k = k0; k < k0 + 128; ++k)
        acc += attm[b * L_ + k] ? hb[(long)k * D_ + d] : 0.f;
    atomicAdd(&pooled[b * D_ + d], acc);
}

__global__ __launch_bounds__(256) void k_pw2(
    const float* __restrict__ pooled, const float* __restrict__ W_sp, float* __restrict__ pw2)
{
    const int b = blockIdx.x;
    const int n = blockIdx.y * 256 + threadIdx.x;
    const int d0 = blockIdx.z * 96;
    float acc = 0.f;
    for (int d = d0; d < d0 + 96; ++d)
        acc += pooled[b * D_ + d] * W_sp[(long)(D_ + d) * D_ + n];
    atomicAdd(&pw2[b * D_ + n], acc);
}

__global__ __launch_bounds__(256) void k_addend0m(
    const float* __restrict__ pw2, const float* __restrict__ counts,
    const int* __restrict__ srcm, const int* __restrict__ spw,
    unsigned short* __restrict__ out, float* __restrict__ outM)
{
    const long idx = (long)blockIdx.x * 256 + threadIdx.x;
    const int d = (int)(idx % D_);
    const long m = idx / D_;
    const int b = (int)(m >> 10);
    const float inv = 1.0f / fmaxf(counts[b], 1.0f);
    out[idx] = f2bf(srcm[m] ? pw2[b * D_ + d] * inv : 0.0f);
    if (idx < (long)B_ * L_ * NSP)
        outM[idx] = ((int)(idx & 3) < spw[idx >> 2]) ? 1.0f : 0.0f;
}

// ---------------------------------------------------------------------------
extern "C" void kernel_launch(void* const* d_in, const int* in_sizes, int n_in,
                              void* d_out, int out_size, void* d_ws, size_t ws_size,
                              hipStream_t stream)
{
    (void)in_sizes; (void)n_in; (void)out_size; (void)ws_size;
    const float* hid     = (const float*)d_in[0];
    const float* src_hid = (const float*)d_in[1];
    const int*   spw     = (const int*)d_in[2];
    const int*   attm    = (const int*)d_in[3];
    const int*   srcm    = (const int*)d_in[4];
    const float* Wq_st = (const float*)d_in[6];
    const float* bq_st = (const float*)d_in[7];
    const float* Wk_st = (const float*)d_in[8];
    const float* rel_st= (const float*)d_in[10];
    const float* Wq_ed = (const float*)d_in[11];
    const float* bq_ed = (const float*)d_in[12];
    const float* Wk_ed = (const float*)d_in[13];
    const float* rel_ed= (const float*)d_in[15];
    const float* W_sp  = (const float*)d_in[16];
    const float* b_sp  = (const float*)d_in[17];

    float* out      = (float*)d_out;
    float* outSts   = out;
    float* outEds   = out + (long)B_ * L_ * NSP * L_;
    float* outMasks = outEds + (long)B_ * L_ * NSP * L_;

    const long S = (long)B_ * L_ * D_;
    const long DD = (long)D_ * D_;
    const long ML = (long)B_ * L_;
    char* wsB = (char*)d_ws;
    auto take = [&](size_t bytes) -> char* {
        char* p = wsB; wsB += (bytes + 255) & ~(size_t)255; return p;
    };
    unsigned short* hid_bf  = (unsigned short*)take(S * 2);
    unsigned short* src_bf  = (unsigned short*)take(S * 2);
    unsigned short* h1a     = (unsigned short*)take(S * 2);
    unsigned short* h1b     = (unsigned short*)take(S * 2);
    unsigned short* h2a     = (unsigned short*)take(S * 2);
    unsigned short* h2b     = (unsigned short*)take(S * 2);
    unsigned short* tmpP    = (unsigned short*)take(S * 2);
    unsigned short* hidW2T  = (unsigned short*)take(S * 2);   // [B][D][L]
    unsigned short* add0    = (unsigned short*)take(S * 2);
    unsigned short* hidGst  = (unsigned short*)take(S * 2);
    unsigned short* hidGed  = (unsigned short*)take(S * 2);
    unsigned short* GtTst   = (unsigned short*)take(DD * 2);
    unsigned short* GtTed   = (unsigned short*)take(DD * 2);
    unsigned short* W1T     = (unsigned short*)take(DD * 2);  // contiguous with W2T
    unsigned short* W2T     = (unsigned short*)take(DD * 2);
    unsigned short* WqBfSt  = (unsigned short*)take(DD * 2);
    unsigned short* WqBfEd  = (unsigned short*)take(DD * 2);
    unsigned short* WkBfSt  = (unsigned short*)take(DD * 2);
    unsigned short* WkBfEd  = (unsigned short*)take(DD * 2);
    unsigned short* relbst  = (unsigned short*)take((long)128 * D_ * 2);
    unsigned short* relbed  = (unsigned short*)take((long)128 * D_ * 2);
    unsigned short* WqrelSt = (unsigned short*)take((long)256 * D_ * 2);
    unsigned short* WqrelEd = (unsigned short*)take((long)256 * D_ * 2);
    unsigned short* attn_st = (unsigned short*)take(ML * L_ * 2);
    unsigned short* attn_ed = (unsigned short*)take(ML * L_ * 2);
    unsigned short* scrSt   = (unsigned short*)take(ML * L_ * 2);   // fp16 scores
    unsigned short* scrEd   = (unsigned short*)take(ML * L_ * 2);
    float* qrelbSt = (float*)take(ML * NREL * 4);
    float* qrelbEd = (float*)take(ML * NREL * 4);
    float* biasQst = (float*)take(896 * 4);
    float* biasQed = (float*)take(896 * 4);
    float* btermSt = (float*)take(ML * 4);
    float* btermEd = (float*)take(ML * 4);
    float* pooled  = (float*)take((long)B_ * D_ * 4);
    float* pw2     = (float*)take((long)B_ * D_ * 4);
    float* counts  = (float*)take(256);
    int*   lists   = (int*)take((long)32 * 1024 * 4);
    int*   cnt     = (int*)take(128);

    const float invs = 1.0f / sqrtf((float)D_);
    const long BB   = (long)L_ * D_;
    const int  NOB  = 1 << 30;

    PSet4 ps;
    auto clr = [&](int i) {
        ps.s[i] = PSet{nullptr,nullptr,nullptr,nullptr,nullptr,nullptr,nullptr,
                       nullptr,nullptr,0,0,1L<<40,1.f,0,0,1<<30};
    };

    // ---- prep ----
    {
        Zero8 z;
        z.p[0] = (float4*)(relbst + (long)NREL * D_);  z.n4[0] = (long)(128 - NREL) * D_ * 2 / 16;
        z.p[1] = (float4*)(relbed + (long)NREL * D_);  z.n4[1] = (long)(128 - NREL) * D_ * 2 / 16;
        z.p[2] = (float4*)(WqrelSt + (long)128 * D_);  z.n4[2] = (long)128 * D_ * 2 / 16;
        z.p[3] = (float4*)(WqrelEd + (long)128 * D_);  z.n4[3] = (long)128 * D_ * 2 / 16;
        z.p[4] = (float4*)pooled;                      z.n4[4] = (long)B_ * D_ / 4;
        z.p[5] = (float4*)pw2;                         z.n4[5] = (long)B_ * D_ / 4;
        z.p[6] = nullptr;                              z.n4[6] = 0;
        z.p[7] = nullptr;                              z.n4[7] = 0;
        long tot = 0; for (int i = 0; i < 8; ++i) tot += z.n4[i];
        k_zero8<<<(int)((tot + 255) / 256), 256, 0, stream>>>(z);
    }
    {
        Cvt8 c;
        c.src[0] = hid;     c.dst[0] = hid_bf;  c.n4[0] = S / 4;
        c.src[1] = src_hid; c.dst[1] = src_bf;  c.n4[1] = S / 4;
        c.src[2] = Wq_st;   c.dst[2] = WqBfSt;  c.n4[2] = DD / 4;
        c.src[3] = Wq_ed;   c.dst[3] = WqBfEd;  c.n4[3] = DD / 4;
        c.src[4] = Wk_st;   c.dst[4] = WkBfSt;  c.n4[4] = DD / 4;
        c.src[5] = Wk_ed;   c.dst[5] = WkBfEd;  c.n4[5] = DD / 4;
        c.src[6] = rel_st;  c.dst[6] = relbst;  c.n4[6] = (long)NREL * D_ / 4;
        c.src[7] = rel_ed;  c.dst[7] = relbed;  c.n4[7] = (long)NREL * D_ / 4;
        long tot = 0; for (int i = 0; i < 8; ++i) tot += c.n4[i];
        k_cvt8<<<(int)((tot + 255) / 256), 256, 0, stream>>>(c);
    }
    k_transpose<<<dim3(D_ / 32, D_ / 32, 2), 256, 0, stream>>>(W_sp, W1T, D_, D_);
    k_biasq<<<dim3(224, 2), 256, 0, stream>>>(bq_st, bq_ed, Wk_st, Wk_ed,
                                              rel_st, rel_ed, biasQst, biasQed);
    k_count<<<B_, 256, 0, stream>>>(attm, counts);
    k_batchsum<<<dim3(B_, D_ / 256, 8), 256, 0, stream>>>(hid, attm, pooled);
    k_pw2<<<dim3(B_, D_ / 256, 8), 256, 0, stream>>>(pooled, W_sp, pw2);
    k_addend0m<<<(int)(S / 256), 256, 0, stream>>>(pw2, counts, srcm, spw, add0, outMasks);
    k_bterm<<<dim3(B_ * L_ / 4, 2), 256, 0, stream>>>(hid_bf, biasQst, biasQed,
                                                      btermSt, btermEd, invs);
    k_lists<<<dim3(8, 4), 256, 0, stream>>>(spw, lists, cnt);

    // GtT (Wq.Wk^T) + Wqrel (rel.Wq^T), 2-phase 128^2 kernel, z=4
    for (int i = 0; i < 4; ++i) clr(i);
    ps.s[0].A0 = WqBfSt; ps.s[0].B0 = WkBfSt; ps.s[0].Cout = GtTst;   ps.s[0].cStride = D_; ps.s[0].mValid = D_;
    ps.s[1].A0 = WqBfEd; ps.s[1].B0 = WkBfEd; ps.s[1].Cout = GtTed;   ps.s[1].cStride = D_; ps.s[1].mValid = D_;
    ps.s[2].A0 = relbst; ps.s[2].B0 = WqBfSt; ps.s[2].Cout = WqrelSt; ps.s[2].cStride = D_; ps.s[2].mValid = 128;
    ps.s[3].A0 = relbed; ps.s[3].B0 = WqBfEd; ps.s[3].Cout = WqrelEd; ps.s[3].cStride = D_; ps.s[3].mValid = 128;
    k_mfma_prep<<<dim3(D_ / 128, D_ / 128, 4), 256, 0, stream>>>(ps, D_, D_, D_);

    // concat0 (src@W1+add0, relu) + hid@W2 + hidG st/ed : one z=4 8-phase dispatch
    for (int i = 0; i < 4; ++i) clr(i);
    ps.s[0].A0 = src_bf; ps.s[0].B0 = W1T;   ps.s[0].bias = b_sp; ps.s[0].addend = add0;
    ps.s[0].Cout = h1a;  ps.s[0].cStride = D_; ps.s[0].relu = 1; ps.s[0].nValid = D_;
    ps.s[1].A0 = hid_bf; ps.s[1].B0 = W2T;   ps.s[1].Cout = tmpP;   ps.s[1].cStride = D_; ps.s[1].nValid = D_;
    ps.s[2].A0 = hid_bf; ps.s[2].B0 = GtTst; ps.s[2].Cout = hidGst; ps.s[2].cStride = D_; ps.s[2].scale = invs; ps.s[2].nValid = D_;
    ps.s[3].A0 = hid_bf; ps.s[3].B0 = GtTed; ps.s[3].Cout = hidGed; ps.s[3].cStride = D_; ps.s[3].scale = invs; ps.s[3].nValid = D_;
    k_mfma8<<<dim3(D_ / 256, (B_ * L_) / 256, 4), 512, 0, stream>>>(
        ps, D_, D_, NOB, D_, D_, D_, 0, nullptr, nullptr, nullptr, nullptr, nullptr, 0);
    k_transpose_bf<<<dim3(D_ / 32, L_ / 32, B_), 256, 0, stream>>>(tmpP, hidW2T, L_, D_);

    unsigned short* h1cur = h1a; unsigned short* h2cur = h1a;
    unsigned short* h1nxt = h1b; unsigned short* h2nxt = h2a;

    for (int it = 0; it < NSP; ++it) {
        const int* rowsIt = lists + (long)it * 8 * 1024;
        const int* cntIt  = cnt + it * 8;
        if (it > 0) {
            // compacted fused pooling+concat: attn@hidW2T (K=1024) + hcur@W1 (K=768)
            for (int i = 0; i < 4; ++i) clr(i);
            ps.s[0].A0 = attn_st; ps.s[0].B0 = hidW2T; ps.s[0].A1 = h1cur; ps.s[0].B1 = W1T;
            ps.s[0].bias = b_sp; ps.s[0].Cout = h1nxt; ps.s[0].cStride = D_;
            ps.s[0].relu = 1; ps.s[0].bB0 = (long)D_ * L_; ps.s[0].nValid = D_;
            ps.s[1] = ps.s[0];
            ps.s[1].A0 = attn_ed; ps.s[1].A1 = h2cur; ps.s[1].Cout = h2nxt;
            k_mfma8<<<dim3(D_ / 256, 32, 2), 512, 0, stream>>>(
                ps, L_, L_, L_, L_, D_, D_, D_, rowsIt, cntIt, nullptr, nullptr, nullptr, it);
            h1cur = h1nxt; h2cur = h2nxt;
            h1nxt = (h1cur == h1a) ? h1b : h1a;
            h2nxt = (h2cur == h2a) ? h2b : h2a;
        }
        // compacted scores (z0,z1 -> fp16 scratch) + qrel (z2,z3)
        for (int i = 0; i < 4; ++i) clr(i);
        ps.s[0].A0 = h1cur; ps.s[0].B0 = hidGst; ps.s[0].Cout = scrSt;
        ps.s[0].bterm = btermSt; ps.s[0].bB0 = BB; ps.s[0].mode = 1;
        ps.s[0].cStride = L_; ps.s[0].nValid = L_;
        ps.s[1].A0 = h2cur; ps.s[1].B0 = hidGed; ps.s[1].Cout = scrEd;
        ps.s[1].bterm = btermEd; ps.s[1].bB0 = BB; ps.s[1].mode = 1;
        ps.s[1].cStride = L_; ps.s[1].nValid = L_;
        ps.s[2].A0 = h1cur; ps.s[2].B0 = WqrelSt; ps.s[2].qout = qrelbSt;
        ps.s[2].bias = biasQst + D_; ps.s[2].scale = invs; ps.s[2].mode = 2; ps.s[2].nValid = 256;
        ps.s[3].A0 = h2cur; ps.s[3].B0 = WqrelEd; ps.s[3].qout = qrelbEd;
        ps.s[3].bias = biasQed + D_; ps.s[3].scale = invs; ps.s[3].mode = 2; ps.s[3].nValid = 256;
        k_mfma8<<<dim3(L_ / 256, 32, 4), 512, 0, stream>>>(
            ps, D_, D_, L_, D_, D_, D_, 0, rowsIt, cntIt, spw, srcm, attm, it);
        // softmax (rel-gather fused; masked rows -> uniform) st+ed
        k_softmax<<<dim3(B_ * L_, 2), 256, 0, stream>>>(
            scrSt, scrEd, outSts, outEds, attn_st, attn_ed,
            qrelbSt, qrelbEd, spw, it);
    }
}

// Round 10
// 743.809 us; speedup vs baseline: 1.4466x; 1.1826x over previous
//
#include <hip/hip_runtime.h>
#include <math.h>

#define B_   8
#define L_   1024
#define D_   768
#define R_   16
#define NSP  4
#define NREL 33

typedef __attribute__((ext_vector_type(8))) short bf16x8;
typedef __attribute__((ext_vector_type(4))) float f32x4;
typedef __attribute__((address_space(1))) const void gv_t;
typedef __attribute__((address_space(3))) void sv_t;

__device__ __forceinline__ unsigned short f2bf(float f) {
    unsigned int u = __float_as_uint(f);
    u += 0x7fff + ((u >> 16) & 1);          // RNE
    return (unsigned short)(u >> 16);
}
__device__ __forceinline__ float bf2f(unsigned short s) {
    return __uint_as_float(((unsigned int)s) << 16);
}
__device__ __forceinline__ unsigned short f2h(float f) {
    _Float16 h = (_Float16)f;
    return *(unsigned short*)&h;
}
__device__ __forceinline__ float h2f(unsigned short u) {
    _Float16 h = *(_Float16*)&u;
    return (float)h;
}

struct PSet {
    const unsigned short* A0;
    const unsigned short* B0;
    const unsigned short* A1;   // dual-K phase 2
    const unsigned short* B1;
    const float*          bias;
    const unsigned short* addend;
    void*                 Cout;
    float*                qout;    // mode 2 output (fp32 qrel)
    const float*          bterm;   // mode 1 per-key bias
    long                  bB0;     // per-batch stride of B0 (0 = unbatched)
    long                  cStride;
    long                  mValid;  // prep kernel row guard
    float                 scale;
    int                   mode;    // 0=bf16 C, 1=scores->fp16 scratch, 2=qrel
    int                   relu;
    int                   nValid;  // early-exit when col0 >= nValid
};
struct PSet4 { PSet s[4]; };

// ===========================================================================
// 8-phase 256x256 MFMA GEMM (T2+T3+T4+T5). BK=64, 8 waves (2Mx4N), 512 thr.
// LDS 128 KiB dbuf, st_16x32 XOR-swizzle reads + inverse-swizzled global src,
// linear global_load_lds dest, counted vmcnt(4). Runtime per-z mode/epilogue.
__global__ __launch_bounds__(512, 2) void k_mfma8(
    PSet4 ps, long aS0, long bS0, int bR0, int K0,
    long aS1, long bS1, int K1,
    const int* __restrict__ spw, const int* __restrict__ srcm,
    const int* __restrict__ attm, int it)
{
    PSet p = ps.s[blockIdx.z];
    const int col0 = blockIdx.x * 256;
    if (col0 >= p.nValid) return;
    const long row0 = (long)blockIdx.y * 256;
    const int b = (int)(row0 >> 10);

    __shared__ unsigned short lds[2][2][256 * 64];   // 128 KiB

    const int tid  = threadIdx.x;
    const int lane = tid & 63;
    const int wave = tid >> 6;
    const int wr = wave >> 2;           // 0..1 (M half)
    const int wc = wave & 3;            // 0..3 (N quarter)
    const int lq = lane >> 4, lr = lane & 15;

    const unsigned short* Bb0 = p.B0 + (row0 / bR0) * p.bB0;

    const int NT0 = K0 / 64;
    const int NT  = NT0 + K1 / 64;

    f32x4 acc[8][4];
#pragma unroll
    for (int m = 0; m < 8; ++m)
#pragma unroll
        for (int n = 0; n < 4; ++n) acc[m][n] = (f32x4)0.f;

    auto stageHalf = [&](int tt, int side, int h) {
        if (tt >= NT) return;
        const unsigned short* src; long stride; int k0;
        if (tt < NT0) { src = side ? Bb0  : p.A0; stride = side ? bS0 : aS0; k0 = tt * 64; }
        else          { src = side ? p.B1 : p.A1; stride = side ? bS1 : aS1; k0 = (tt - NT0) * 64; }
        const long base = side ? (long)col0 : row0;
        unsigned short* dst = &lds[tt & 1][side][h * 8192];
#pragma unroll
        for (int j = 0; j < 2; ++j) {
            const int r = j * 64 + wave * 8 + (lane >> 3);
            const int csrc = ((lane & 7) * 8) ^ (((r >> 2) & 1) << 4);
            const unsigned short* g = src + (base + h * 128 + r) * stride + k0 + csrc;
            __builtin_amdgcn_global_load_lds((gv_t*)g,
                (sv_t*)(dst + j * 4096 + wave * 512), 16, 0, 0);
        }
    };
    auto rd = [&](int bt, int side, int r, int ks) -> bf16x8 {
        const int idx = r * 64 + (((ks << 5) | (lq << 3)) ^ (((r >> 2) & 1) << 4));
        return *(const bf16x8*)&lds[bt][side][idx];
    };

    stageHalf(0, 0, 0); stageHalf(0, 0, 1);
    stageHalf(0, 1, 0); stageHalf(0, 1, 1);
    stageHalf(1, 1, 0); stageHalf(1, 1, 1);
    if (1 < NT) asm volatile("s_waitcnt vmcnt(4)" ::: "memory");
    else        asm volatile("s_waitcnt vmcnt(0)" ::: "memory");
    __builtin_amdgcn_s_barrier();

    bf16x8 af[4][2], bfr[4][2];

    for (int t = 0; t < NT; ++t) {
        const int bt = t & 1;
        // phase 1: read A m0-3 + B n0-1; stage (t+1).A0
#pragma unroll
        for (int mf = 0; mf < 4; ++mf)
#pragma unroll
            for (int ks = 0; ks < 2; ++ks)
                af[mf][ks] = rd(bt, 0, wr * 128 + mf * 16 + lr, ks);
#pragma unroll
        for (int nf = 0; nf < 2; ++nf)
#pragma unroll
            for (int ks = 0; ks < 2; ++ks)
                bfr[nf][ks] = rd(bt, 1, wc * 64 + nf * 16 + lr, ks);
        stageHalf(t + 1, 0, 0);
        __builtin_amdgcn_s_barrier();
        asm volatile("s_waitcnt lgkmcnt(0)" ::: "memory");
        __builtin_amdgcn_sched_barrier(0);
        __builtin_amdgcn_s_setprio(1);
#pragma unroll
        for (int nf = 0; nf < 2; ++nf)
#pragma unroll
            for (int mf = 0; mf < 4; ++mf)
#pragma unroll
                for (int ks = 0; ks < 2; ++ks)
                    acc[mf][nf] = __builtin_amdgcn_mfma_f32_16x16x32_bf16(
                        af[mf][ks], bfr[nf][ks], acc[mf][nf], 0, 0, 0);
        __builtin_amdgcn_s_setprio(0);
        __builtin_amdgcn_s_barrier();
        // phase 2: read B n2-3; stage (t+1).A1
#pragma unroll
        for (int nf = 2; nf < 4; ++nf)
#pragma unroll
            for (int ks = 0; ks < 2; ++ks)
                bfr[nf][ks] = rd(bt, 1, wc * 64 + nf * 16 + lr, ks);
        stageHalf(t + 1, 0, 1);
        __builtin_amdgcn_s_barrier();
        asm volatile("s_waitcnt lgkmcnt(0)" ::: "memory");
        __builtin_amdgcn_sched_barrier(0);
        __builtin_amdgcn_s_setprio(1);
#pragma unroll
        for (int nf = 2; nf < 4; ++nf)
#pragma unroll
            for (int mf = 0; mf < 4; ++mf)
#pragma unroll
                for (int ks = 0; ks < 2; ++ks)
                    acc[mf][nf] = __builtin_amdgcn_mfma_f32_16x16x32_bf16(
                        af[mf][ks], bfr[nf][ks], acc[mf][nf], 0, 0, 0);
        __builtin_amdgcn_s_setprio(0);
        __builtin_amdgcn_s_barrier();
        // phase 3: read A m4-7; stage (t+2).B0
#pragma unroll
        for (int mf = 0; mf < 4; ++mf)
#pragma unroll
            for (int ks = 0; ks < 2; ++ks)
                af[mf][ks] = rd(bt, 0, wr * 128 + 64 + mf * 16 + lr, ks);
        stageHalf(t + 2, 1, 0);
        __builtin_amdgcn_s_barrier();
        asm volatile("s_waitcnt lgkmcnt(0)" ::: "memory");
        __builtin_amdgcn_sched_barrier(0);
        __builtin_amdgcn_s_setprio(1);
#pragma unroll
        for (int nf = 0; nf < 2; ++nf)
#pragma unroll
            for (int mf = 0; mf < 4; ++mf)
#pragma unroll
                for (int ks = 0; ks < 2; ++ks)
                    acc[4 + mf][nf] = __builtin_amdgcn_mfma_f32_16x16x32_bf16(
                        af[mf][ks], bfr[nf][ks], acc[4 + mf][nf], 0, 0, 0);
        __builtin_amdgcn_s_setprio(0);
        __builtin_amdgcn_s_barrier();
        // phase 4: stage (t+2).B1; counted vmcnt; MFMA m4-7 x n2-3
        stageHalf(t + 2, 1, 1);
        if (t + 2 < NT) asm volatile("s_waitcnt vmcnt(4)" ::: "memory");
        else            asm volatile("s_waitcnt vmcnt(0)" ::: "memory");
        __builtin_amdgcn_s_barrier();
        __builtin_amdgcn_sched_barrier(0);
        __builtin_amdgcn_s_setprio(1);
#pragma unroll
        for (int nf = 2; nf < 4; ++nf)
#pragma unroll
            for (int mf = 0; mf < 4; ++mf)
#pragma unroll
                for (int ks = 0; ks < 2; ++ks)
                    acc[4 + mf][nf] = __builtin_amdgcn_mfma_f32_16x16x32_bf16(
                        af[mf][ks], bfr[nf][ks], acc[4 + mf][nf], 0, 0, 0);
        __builtin_amdgcn_s_setprio(0);
        __builtin_amdgcn_s_barrier();
    }

    // ---------------- epilogue (runtime mode) ----------------
    if (p.mode == 0) {
        unsigned short* C = (unsigned short*)p.Cout;
#pragma unroll
        for (int nf = 0; nf < 4; ++nf) {
            const int col = col0 + wc * 64 + nf * 16 + lr;
            const float bc = p.bias ? p.bias[col] : 0.f;
#pragma unroll
            for (int mf = 0; mf < 8; ++mf) {
#pragma unroll
                for (int rr = 0; rr < 4; ++rr) {
                    const long row = row0 + wr * 128 + mf * 16 + lq * 4 + rr;
                    float v = acc[mf][nf][rr] + bc;
                    if (p.addend) v += bf2f(p.addend[row * p.cStride + col]);
                    v *= p.scale;
                    if (p.relu) v = fmaxf(v, 0.f);
                    C[row * p.cStride + col] = f2bf(v);
                }
            }
        }
    } else if (p.mode == 1) {
        unsigned short* C = (unsigned short*)p.Cout;   // fp16 scratch [m][L]
        int amv[4]; float btv[4];
#pragma unroll
        for (int nf = 0; nf < 4; ++nf) {
            const int col = col0 + wc * 64 + nf * 16 + lr;
            amv[nf] = attm[b * L_ + col];
            btv[nf] = p.bterm[b * L_ + col];
        }
#pragma unroll
        for (int mf = 0; mf < 8; ++mf) {
#pragma unroll
            for (int rr = 0; rr < 4; ++rr) {
                const long mg = row0 + wr * 128 + mf * 16 + lq * 4 + rr;
                const bool rowAct = (it < spw[mg]) && (srcm[mg] != 0);
#pragma unroll
                for (int nf = 0; nf < 4; ++nf) {
                    const int col = col0 + wc * 64 + nf * 16 + lr;
                    const float v = (rowAct && amv[nf]) ? (acc[mf][nf][rr] + btv[nf]) : -60000.f;
                    C[mg * L_ + col] = f2h(v);
                }
            }
        }
    } else {   // mode 2: qrel fp32 (col < NREL)
        float* qout = p.qout;
#pragma unroll
        for (int nf = 0; nf < 3; ++nf) {
            const int col = wc * 64 + nf * 16 + lr;
            if (col < NREL) {
                const float bc = p.bias[col];
#pragma unroll
                for (int mf = 0; mf < 8; ++mf)
#pragma unroll
                    for (int rr = 0; rr < 4; ++rr) {
                        const long mg = row0 + wr * 128 + mf * 16 + lq * 4 + rr;
                        qout[mg * NREL + col] = (acc[mf][nf][rr] + bc) * p.scale;
                    }
            }
        }
    }
}

// ===========================================================================
// 2-phase 128x128 kernel (prep-only: GtT / Wqrel, small M)
__global__ __launch_bounds__(256) void k_mfma_prep(
    PSet4 ps, long aS0, long bS0, int K0)
{
    PSet p = ps.s[blockIdx.z];
    const long row0 = (long)blockIdx.y * 128;
    if (row0 >= p.mValid) return;
    const int col0 = blockIdx.x * 128;

    __shared__ unsigned short As[2][128 * 32];
    __shared__ unsigned short Bs[2][128 * 32];
    const int tid  = threadIdx.x;
    const int lane = tid & 63;
    const int wave = tid >> 6;
    const int wr = wave >> 1, wc = wave & 1;
    const int lq = lane >> 4, lr = lane & 15;
    const int sr = lane >> 2;
    const int sc = (lane & 3) * 8;

    f32x4 acc[4][4];
#pragma unroll
    for (int m = 0; m < 4; ++m)
#pragma unroll
        for (int n = 0; n < 4; ++n) acc[m][n] = (f32x4)0.f;

    const int NT = K0 / 32;
    auto stage = [&](int t, int buf) {
        const int k0 = t * 32;
#pragma unroll
        for (int j = 0; j < 2; ++j) {
            const int c = wave + j * 4;
            const unsigned short* ga = p.A0 + (row0 + c * 16 + sr) * aS0 + k0 + sc;
            const unsigned short* gb = p.B0 + (long)(col0 + c * 16 + sr) * bS0 + k0 + sc;
            __builtin_amdgcn_global_load_lds((gv_t*)ga, (sv_t*)&As[buf][c * 512], 16, 0, 0);
            __builtin_amdgcn_global_load_lds((gv_t*)gb, (sv_t*)&Bs[buf][c * 512], 16, 0, 0);
        }
    };
    stage(0, 0);
    asm volatile("s_waitcnt vmcnt(0)" ::: "memory");
    __builtin_amdgcn_s_barrier();
    int cur = 0;
    for (int t = 0; t < NT; ++t) {
        if (t + 1 < NT) stage(t + 1, cur ^ 1);
        bf16x8 a4[4], b4[4];
#pragma unroll
        for (int m = 0; m < 4; ++m)
            a4[m] = *(const bf16x8*)&As[cur][(wr * 64 + m * 16 + lr) * 32 + lq * 8];
#pragma unroll
        for (int n = 0; n < 4; ++n)
            b4[n] = *(const bf16x8*)&Bs[cur][(wc * 64 + n * 16 + lr) * 32 + lq * 8];
#pragma unroll
        for (int m = 0; m < 4; ++m)
#pragma unroll
            for (int n = 0; n < 4; ++n)
                acc[m][n] = __builtin_amdgcn_mfma_f32_16x16x32_bf16(a4[m], b4[n], acc[m][n], 0, 0, 0);
        asm volatile("s_waitcnt vmcnt(0)" ::: "memory");
        __builtin_amdgcn_s_barrier();
        cur ^= 1;
    }
    unsigned short* C = (unsigned short*)p.Cout;
#pragma unroll
    for (int n = 0; n < 4; ++n) {
        const int col = col0 + wc * 64 + n * 16 + lr;
#pragma unroll
        for (int m = 0; m < 4; ++m)
#pragma unroll
            for (int r = 0; r < 4; ++r) {
                const long row = row0 + wr * 64 + m * 16 + lq * 4 + r;
                C[row * p.cStride + col] = f2bf(acc[m][n][r]);
            }
    }
}

// ---------------------------------------------------------------------------
struct Zero8 { float4* p[8]; long n4[8]; };
__global__ __launch_bounds__(256) void k_zero8(Zero8 z)
{
    long g = (long)blockIdx.x * 256 + threadIdx.x;
#pragma unroll
    for (int s = 0; s < 8; ++s) {
        if (g < z.n4[s]) {
            float4 v; v.x = v.y = v.z = v.w = 0.f;
            z.p[s][g] = v;
            return;
        }
        g -= z.n4[s];
    }
}

struct Cvt8 { const float* src[8]; unsigned short* dst[8]; long n4[8]; };
__global__ __launch_bounds__(256) void k_cvt8(Cvt8 c)
{
    long g = (long)blockIdx.x * 256 + threadIdx.x;
#pragma unroll
    for (int s = 0; s < 8; ++s) {
        if (g < c.n4[s]) {
            const float4 v = ((const float4*)c.src[s])[g];
            ushort4 o; o.x = f2bf(v.x); o.y = f2bf(v.y); o.z = f2bf(v.z); o.w = f2bf(v.w);
            ((ushort4*)c.dst[s])[g] = o;
            return;
        }
        g -= c.n4[s];
    }
}

__global__ __launch_bounds__(256) void k_transpose(
    const float* __restrict__ in, unsigned short* __restrict__ out, int rows, int cols)
{
    __shared__ float t[32][33];
    const long zo = (long)blockIdx.z * rows * cols;
    const int c0 = blockIdx.x * 32, r0 = blockIdx.y * 32;
    const int tx = threadIdx.x & 31, ty = threadIdx.x >> 5;
#pragma unroll
    for (int i = 0; i < 32; i += 8)
        t[ty + i][tx] = in[zo + (long)(r0 + ty + i) * cols + c0 + tx];
    __syncthreads();
#pragma unroll
    for (int i = 0; i < 32; i += 8)
        out[zo + (long)(c0 + ty + i) * rows + r0 + tx] = f2bf(t[tx][ty + i]);
}

__global__ __launch_bounds__(256) void k_transpose_bf(
    const unsigned short* __restrict__ in, unsigned short* __restrict__ out,
    int rows, int cols)
{
    __shared__ unsigned short t[32][33];
    const long zo = (long)blockIdx.z * rows * cols;
    const int c0 = blockIdx.x * 32, r0 = blockIdx.y * 32;
    const int tx = threadIdx.x & 31, ty = threadIdx.x >> 5;
#pragma unroll
    for (int i = 0; i < 32; i += 8)
        t[ty + i][tx] = in[zo + (long)(r0 + ty + i) * cols + c0 + tx];
    __syncthreads();
#pragma unroll
    for (int i = 0; i < 32; i += 8)
        out[zo + (long)(c0 + ty + i) * rows + r0 + tx] = t[tx][ty + i];
}

// ---------------------------------------------------------------------------
// biasQ[896]: [0..767] = bq.Wk[i,:]; [768+r] = bq.rel[r,:]; wave per output
__global__ __launch_bounds__(256) void k_biasq(
    const float* __restrict__ bq0, const float* __restrict__ bq1,
    const float* __restrict__ wk0, const float* __restrict__ wk1,
    const float* __restrict__ rel0, const float* __restrict__ rel1,
    float* __restrict__ out0, float* __restrict__ out1)
{
    const int z = blockIdx.y;
    const float* bq  = z ? bq1  : bq0;
    const float* wk  = z ? wk1  : wk0;
    const float* rel = z ? rel1 : rel0;
    float* out       = z ? out1 : out0;
    const int i = blockIdx.x * 4 + (threadIdx.x >> 6);
    const int lane = threadIdx.x & 63;
    const float* w = nullptr;
    if (i < D_) w = wk + (long)i * D_;
    else if (i - D_ < NREL) w = rel + (long)(i - D_) * D_;
    float a = 0.f;
    if (w)
        for (int e = lane * 4; e < D_; e += 256) {
            const float4 w4 = *(const float4*)&w[e];
            const float4 b4 = *(const float4*)&bq[e];
            a += w4.x * b4.x + w4.y * b4.y + w4.z * b4.z + w4.w * b4.w;
        }
#pragma unroll
    for (int o = 32; o > 0; o >>= 1) a += __shfl_xor(a, o, 64);
    if (lane == 0) out[i] = a;
}

// bterm[m] = invs * sum_d biasQ[d] * hid[m,d]
__global__ __launch_bounds__(256) void k_bterm(
    const unsigned short* __restrict__ hid_bf,
    const float* __restrict__ biasQ0, const float* __restrict__ biasQ1,
    float* __restrict__ out0, float* __restrict__ out1, float invs)
{
    const float* biasQ = blockIdx.y ? biasQ1 : biasQ0;
    float* out = blockIdx.y ? out1 : out0;
    const long row = (long)blockIdx.x * 4 + (threadIdx.x >> 6);
    const int lane = threadIdx.x & 63;
    const unsigned short* h = hid_bf + row * D_;
    float a = 0.f;
    for (int d = lane * 4; d < D_; d += 256) {
        const ushort4 u = *(const ushort4*)&h[d];
        const float4 bq4 = *(const float4*)&biasQ[d];
        a += bf2f(u.x) * bq4.x + bf2f(u.y) * bq4.y + bf2f(u.z) * bq4.z + bf2f(u.w) * bq4.w;
    }
#pragma unroll
    for (int o = 32; o > 0; o >>= 1) a += __shfl_xor(a, o, 64);
    if (lane == 0) out[row] = a * invs;
}

// ---------------------------------------------------------------------------
// softmax over all rows: masked rows -> uniform 1/L (no scratch read);
// active rows: fp16 scratch + qrel gather -> fp32 d_out + bf16 attn
__global__ __launch_bounds__(256) void k_softmax(
    const unsigned short* __restrict__ sSt, const unsigned short* __restrict__ sEd,
    float* __restrict__ oSt, float* __restrict__ oEd,
    unsigned short* __restrict__ aSt, unsigned short* __restrict__ aEd,
    const float* __restrict__ qrSt, const float* __restrict__ qrEd,
    const int* __restrict__ spw, int it)
{
    const long m = blockIdx.x;
    float* o = (blockIdx.y ? oEd : oSt) + (m * NSP + it) * L_;
    const int t = threadIdx.x;
    if (spw[m] <= it) {                 // masked: exact uniform row
        float4 u; u.x = u.y = u.z = u.w = 0.0009765625f;
        *(float4*)&o[4 * t] = u;
        return;
    }
    const unsigned short* s = (blockIdx.y ? sEd : sSt) + m * L_;
    unsigned short* a = (blockIdx.y ? aEd : aSt) + m * L_;
    const float* qrow = (blockIdx.y ? qrEd : qrSt) + m * NREL;
    const int q = (int)(m & (L_ - 1));
    const ushort4 u = *(const ushort4*)&s[4 * t];
    float vv[4];
    const unsigned short* up = (const unsigned short*)&u;
#pragma unroll
    for (int j = 0; j < 4; ++j) {
        float x = h2f(up[j]);
        if (x < -3.0e4f) x = -1e18f;      // masked col: exact absorption
        else {
            int dr = 4 * t + j - q;
            dr = dr < -R_ ? -R_ : (dr > R_ ? R_ : dr);
            x += qrow[dr + R_];
        }
        vv[j] = x;
    }
    float mx = fmaxf(fmaxf(vv[0], vv[1]), fmaxf(vv[2], vv[3]));
#pragma unroll
    for (int ofs = 32; ofs > 0; ofs >>= 1) mx = fmaxf(mx, __shfl_xor(mx, ofs, 64));
    __shared__ float redm[4];
    __shared__ float reds[4];
    const int wave = t >> 6;
    if ((t & 63) == 0) redm[wave] = mx;
    __syncthreads();
    mx = fmaxf(fmaxf(redm[0], redm[1]), fmaxf(redm[2], redm[3]));
    float sum = 0.f;
#pragma unroll
    for (int j = 0; j < 4; ++j) { vv[j] = expf(vv[j] - mx); sum += vv[j]; }
#pragma unroll
    for (int ofs = 32; ofs > 0; ofs >>= 1) sum += __shfl_xor(sum, ofs, 64);
    if ((t & 63) == 0) reds[wave] = sum;
    __syncthreads();
    sum = reds[0] + reds[1] + reds[2] + reds[3];
    const float inv = 1.0f / sum;
    float4 v; v.x = vv[0] * inv; v.y = vv[1] * inv; v.z = vv[2] * inv; v.w = vv[3] * inv;
    *(float4*)&o[4 * t] = v;
    ushort4 ob; ob.x = f2bf(v.x); ob.y = f2bf(v.y); ob.z = f2bf(v.z); ob.w = f2bf(v.w);
    *(ushort4*)&a[4 * t] = ob;
}

// ---------------------------------------------------------------------------
__global__ __launch_bounds__(256) void k_count(const int* __restrict__ attm, float* __restrict__ counts)
{
    const int b = blockIdx.x, t = threadIdx.x;
    int c = 0;
    for (int k = t; k < L_; k += 256) c += (attm[b * L_ + k] != 0);
#pragma unroll
    for (int o = 32; o > 0; o >>= 1) c += __shfl_xor(c, o, 64);
    __shared__ int red[4];
    if ((t & 63) == 0) red[t >> 6] = c;
    __syncthreads();
    if (t == 0) counts[b] = (float)(red[0] + red[1] + red[2] + red[3]);
}

__global__ __launch_bounds__(256) void k_batchsum(
    const float* __restrict__ hid, const int* __restrict__ attm, float* __restrict__ pooled)
{
    const int b = blockIdx.x;
    const int d = blockIdx.y * 256 + threadIdx.x;
    const int k0 = blockIdx.z * 128;
    const float* hb = hid + (long)b * L_ * D_;
    float acc = 0.f;
    for (int k = k0; k < k0 + 128; ++k)
        acc += attm[b * L_ + k] ? hb[(long)k * D_ + d] : 0.f;
    atomicAdd(&pooled[b * D_ + d], acc);
}

__global__ __launch_bounds__(256) void k_pw2(
    const float* __restrict__ pooled, const float* __restrict__ W_sp, float* __restrict__ pw2)
{
    const int b = blockIdx.x;
    const int n = blockIdx.y * 256 + threadIdx.x;
    const int d0 = blockIdx.z * 96;
    float acc = 0.f;
    for (int d = d0; d < d0 + 96; ++d)
        acc += pooled[b * D_ + d] * W_sp[(long)(D_ + d) * D_ + n];
    atomicAdd(&pw2[b * D_ + n], acc);
}

__global__ __launch_bounds__(256) void k_addend0m(
    const float* __restrict__ pw2, const float* __restrict__ counts,
    const int* __restrict__ srcm, const int* __restrict__ spw,
    unsigned short* __restrict__ out, float* __restrict__ outM)
{
    const long idx = (long)blockIdx.x * 256 + threadIdx.x;
    const int d = (int)(idx % D_);
    const long m = idx / D_;
    const int b = (int)(m >> 10);
    const float inv = 1.0f / fmaxf(counts[b], 1.0f);
    out[idx] = f2bf(srcm[m] ? pw2[b * D_ + d] * inv : 0.0f);
    if (idx < (long)B_ * L_ * NSP)
        outM[idx] = ((int)(idx & 3) < spw[idx >> 2]) ? 1.0f : 0.0f;
}

// ---------------------------------------------------------------------------
extern "C" void kernel_launch(void* const* d_in, const int* in_sizes, int n_in,
                              void* d_out, int out_size, void* d_ws, size_t ws_size,
                              hipStream_t stream)
{
    (void)in_sizes; (void)n_in; (void)out_size; (void)ws_size;
    const float* hid     = (const float*)d_in[0];
    const float* src_hid = (const float*)d_in[1];
    const int*   spw     = (const int*)d_in[2];
    const int*   attm    = (const int*)d_in[3];
    const int*   srcm    = (const int*)d_in[4];
    const float* Wq_st = (const float*)d_in[6];
    const float* bq_st = (const float*)d_in[7];
    const float* Wk_st = (const float*)d_in[8];
    const float* rel_st= (const float*)d_in[10];
    const float* Wq_ed = (const float*)d_in[11];
    const float* bq_ed = (const float*)d_in[12];
    const float* Wk_ed = (const float*)d_in[13];
    const float* rel_ed= (const float*)d_in[15];
    const float* W_sp  = (const float*)d_in[16];
    const float* b_sp  = (const float*)d_in[17];

    float* out      = (float*)d_out;
    float* outSts   = out;
    float* outEds   = out + (long)B_ * L_ * NSP * L_;
    float* outMasks = outEds + (long)B_ * L_ * NSP * L_;

    const long S = (long)B_ * L_ * D_;
    const long DD = (long)D_ * D_;
    const long ML = (long)B_ * L_;
    char* wsB = (char*)d_ws;
    auto take = [&](size_t bytes) -> char* {
        char* p = wsB; wsB += (bytes + 255) & ~(size_t)255; return p;
    };
    unsigned short* hid_bf  = (unsigned short*)take(S * 2);
    unsigned short* src_bf  = (unsigned short*)take(S * 2);
    unsigned short* h1a     = (unsigned short*)take(S * 2);
    unsigned short* h1b     = (unsigned short*)take(S * 2);
    unsigned short* h2a     = (unsigned short*)take(S * 2);
    unsigned short* h2b     = (unsigned short*)take(S * 2);
    unsigned short* tmpP    = (unsigned short*)take(S * 2);
    unsigned short* hidW2T  = (unsigned short*)take(S * 2);   // [B][D][L]
    unsigned short* add0    = (unsigned short*)take(S * 2);
    unsigned short* hidGst  = (unsigned short*)take(S * 2);
    unsigned short* hidGed  = (unsigned short*)take(S * 2);
    unsigned short* GtTst   = (unsigned short*)take(DD * 2);
    unsigned short* GtTed   = (unsigned short*)take(DD * 2);
    unsigned short* W1T     = (unsigned short*)take(DD * 2);  // contiguous with W2T
    unsigned short* W2T     = (unsigned short*)take(DD * 2);
    unsigned short* WqBfSt  = (unsigned short*)take(DD * 2);
    unsigned short* WqBfEd  = (unsigned short*)take(DD * 2);
    unsigned short* WkBfSt  = (unsigned short*)take(DD * 2);
    unsigned short* WkBfEd  = (unsigned short*)take(DD * 2);
    unsigned short* relbst  = (unsigned short*)take((long)128 * D_ * 2);
    unsigned short* relbed  = (unsigned short*)take((long)128 * D_ * 2);
    unsigned short* WqrelSt = (unsigned short*)take((long)256 * D_ * 2);
    unsigned short* WqrelEd = (unsigned short*)take((long)256 * D_ * 2);
    unsigned short* attn_st = (unsigned short*)take(ML * L_ * 2);
    unsigned short* attn_ed = (unsigned short*)take(ML * L_ * 2);
    unsigned short* scrSt   = (unsigned short*)take(ML * L_ * 2);   // fp16 scores
    unsigned short* scrEd   = (unsigned short*)take(ML * L_ * 2);
    float* qrelbSt = (float*)take(ML * NREL * 4);
    float* qrelbEd = (float*)take(ML * NREL * 4);
    float* biasQst = (float*)take(896 * 4);
    float* biasQed = (float*)take(896 * 4);
    float* btermSt = (float*)take(ML * 4);
    float* btermEd = (float*)take(ML * 4);
    float* pooled  = (float*)take((long)B_ * D_ * 4);
    float* pw2     = (float*)take((long)B_ * D_ * 4);
    float* counts  = (float*)take(256);

    const float invs = 1.0f / sqrtf((float)D_);
    const long BB   = (long)L_ * D_;
    const int  NOB  = 1 << 30;

    PSet4 ps;
    auto clr = [&](int i) {
        ps.s[i] = PSet{nullptr,nullptr,nullptr,nullptr,nullptr,nullptr,nullptr,
                       nullptr,nullptr,0,0,1L<<40,1.f,0,0,1<<30};
    };

    // ---- prep ----
    {
        Zero8 z;
        z.p[0] = (float4*)(relbst + (long)NREL * D_);  z.n4[0] = (long)(128 - NREL) * D_ * 2 / 16;
        z.p[1] = (float4*)(relbed + (long)NREL * D_);  z.n4[1] = (long)(128 - NREL) * D_ * 2 / 16;
        z.p[2] = (float4*)(WqrelSt + (long)128 * D_);  z.n4[2] = (long)128 * D_ * 2 / 16;
        z.p[3] = (float4*)(WqrelEd + (long)128 * D_);  z.n4[3] = (long)128 * D_ * 2 / 16;
        z.p[4] = (float4*)pooled;                      z.n4[4] = (long)B_ * D_ / 4;
        z.p[5] = (float4*)pw2;                         z.n4[5] = (long)B_ * D_ / 4;
        z.p[6] = nullptr;                              z.n4[6] = 0;
        z.p[7] = nullptr;                              z.n4[7] = 0;
        long tot = 0; for (int i = 0; i < 8; ++i) tot += z.n4[i];
        k_zero8<<<(int)((tot + 255) / 256), 256, 0, stream>>>(z);
    }
    {
        Cvt8 c;
        c.src[0] = hid;     c.dst[0] = hid_bf;  c.n4[0] = S / 4;
        c.src[1] = src_hid; c.dst[1] = src_bf;  c.n4[1] = S / 4;
        c.src[2] = Wq_st;   c.dst[2] = WqBfSt;  c.n4[2] = DD / 4;
        c.src[3] = Wq_ed;   c.dst[3] = WqBfEd;  c.n4[3] = DD / 4;
        c.src[4] = Wk_st;   c.dst[4] = WkBfSt;  c.n4[4] = DD / 4;
        c.src[5] = Wk_ed;   c.dst[5] = WkBfEd;  c.n4[5] = DD / 4;
        c.src[6] = rel_st;  c.dst[6] = relbst;  c.n4[6] = (long)NREL * D_ / 4;
        c.src[7] = rel_ed;  c.dst[7] = relbed;  c.n4[7] = (long)NREL * D_ / 4;
        long tot = 0; for (int i = 0; i < 8; ++i) tot += c.n4[i];
        k_cvt8<<<(int)((tot + 255) / 256), 256, 0, stream>>>(c);
    }
    k_transpose<<<dim3(D_ / 32, D_ / 32, 2), 256, 0, stream>>>(W_sp, W1T, D_, D_);
    k_biasq<<<dim3(224, 2), 256, 0, stream>>>(bq_st, bq_ed, Wk_st, Wk_ed,
                                              rel_st, rel_ed, biasQst, biasQed);
    k_count<<<B_, 256, 0, stream>>>(attm, counts);
    k_batchsum<<<dim3(B_, D_ / 256, 8), 256, 0, stream>>>(hid, attm, pooled);
    k_pw2<<<dim3(B_, D_ / 256, 8), 256, 0, stream>>>(pooled, W_sp, pw2);
    k_addend0m<<<(int)(S / 256), 256, 0, stream>>>(pw2, counts, srcm, spw, add0, outMasks);
    k_bterm<<<dim3(B_ * L_ / 4, 2), 256, 0, stream>>>(hid_bf, biasQst, biasQed,
                                                      btermSt, btermEd, invs);

    // GtT (Wq.Wk^T) + Wqrel (rel.Wq^T), 2-phase 128^2 kernel, z=4
    for (int i = 0; i < 4; ++i) clr(i);
    ps.s[0].A0 = WqBfSt; ps.s[0].B0 = WkBfSt; ps.s[0].Cout = GtTst;   ps.s[0].cStride = D_; ps.s[0].mValid = D_;
    ps.s[1].A0 = WqBfEd; ps.s[1].B0 = WkBfEd; ps.s[1].Cout = GtTed;   ps.s[1].cStride = D_; ps.s[1].mValid = D_;
    ps.s[2].A0 = relbst; ps.s[2].B0 = WqBfSt; ps.s[2].Cout = WqrelSt; ps.s[2].cStride = D_; ps.s[2].mValid = 128;
    ps.s[3].A0 = relbed; ps.s[3].B0 = WqBfEd; ps.s[3].Cout = WqrelEd; ps.s[3].cStride = D_; ps.s[3].mValid = 128;
    k_mfma_prep<<<dim3(D_ / 128, D_ / 128, 4), 256, 0, stream>>>(ps, D_, D_, D_);

    // concat0 (src@W1+add0, relu) + hid@W2 + hidG st/ed : one z=4 8-phase dispatch
    for (int i = 0; i < 4; ++i) clr(i);
    ps.s[0].A0 = src_bf; ps.s[0].B0 = W1T;   ps.s[0].bias = b_sp; ps.s[0].addend = add0;
    ps.s[0].Cout = h1a;  ps.s[0].cStride = D_; ps.s[0].relu = 1; ps.s[0].nValid = D_;
    ps.s[1].A0 = hid_bf; ps.s[1].B0 = W2T;   ps.s[1].Cout = tmpP;   ps.s[1].cStride = D_; ps.s[1].nValid = D_;
    ps.s[2].A0 = hid_bf; ps.s[2].B0 = GtTst; ps.s[2].Cout = hidGst; ps.s[2].cStride = D_; ps.s[2].scale = invs; ps.s[2].nValid = D_;
    ps.s[3].A0 = hid_bf; ps.s[3].B0 = GtTed; ps.s[3].Cout = hidGed; ps.s[3].cStride = D_; ps.s[3].scale = invs; ps.s[3].nValid = D_;
    k_mfma8<<<dim3(D_ / 256, (B_ * L_) / 256, 4), 512, 0, stream>>>(
        ps, D_, D_, NOB, D_, D_, D_, 0, nullptr, nullptr, nullptr, 0);
    k_transpose_bf<<<dim3(D_ / 32, L_ / 32, B_), 256, 0, stream>>>(tmpP, hidW2T, L_, D_);

    unsigned short* h1cur = h1a; unsigned short* h2cur = h1a;
    unsigned short* h1nxt = h1b; unsigned short* h2nxt = h2a;

    for (int it = 0; it < NSP; ++it) {
        if (it > 0) {
            // fused pooling+concat: attn@hidW2T (K=1024) + hcur@W1 (K=768)
            for (int i = 0; i < 4; ++i) clr(i);
            ps.s[0].A0 = attn_st; ps.s[0].B0 = hidW2T; ps.s[0].A1 = h1cur; ps.s[0].B1 = W1T;
            ps.s[0].bias = b_sp; ps.s[0].Cout = h1nxt; ps.s[0].cStride = D_;
            ps.s[0].relu = 1; ps.s[0].bB0 = (long)D_ * L_; ps.s[0].nValid = D_;
            ps.s[1] = ps.s[0];
            ps.s[1].A0 = attn_ed; ps.s[1].A1 = h2cur; ps.s[1].Cout = h2nxt;
            k_mfma8<<<dim3(D_ / 256, (B_ * L_) / 256, 2), 512, 0, stream>>>(
                ps, L_, L_, L_, L_, D_, D_, D_, nullptr, nullptr, nullptr, it);
            h1cur = h1nxt; h2cur = h2nxt;
            h1nxt = (h1cur == h1a) ? h1b : h1a;
            h2nxt = (h2cur == h2a) ? h2b : h2a;
        }
        // scores (z0,z1 -> fp16 scratch) + qrel (z2,z3)
        for (int i = 0; i < 4; ++i) clr(i);
        ps.s[0].A0 = h1cur; ps.s[0].B0 = hidGst; ps.s[0].Cout = scrSt;
        ps.s[0].bterm = btermSt; ps.s[0].bB0 = BB; ps.s[0].mode = 1;
        ps.s[0].cStride = L_; ps.s[0].nValid = L_;
        ps.s[1].A0 = h2cur; ps.s[1].B0 = hidGed; ps.s[1].Cout = scrEd;
        ps.s[1].bterm = btermEd; ps.s[1].bB0 = BB; ps.s[1].mode = 1;
        ps.s[1].cStride = L_; ps.s[1].nValid = L_;
        ps.s[2].A0 = h1cur; ps.s[2].B0 = WqrelSt; ps.s[2].qout = qrelbSt;
        ps.s[2].bias = biasQst + D_; ps.s[2].scale = invs; ps.s[2].mode = 2; ps.s[2].nValid = 256;
        ps.s[3].A0 = h2cur; ps.s[3].B0 = WqrelEd; ps.s[3].qout = qrelbEd;
        ps.s[3].bias = biasQed + D_; ps.s[3].scale = invs; ps.s[3].mode = 2; ps.s[3].nValid = 256;
        k_mfma8<<<dim3(L_ / 256, (B_ * L_) / 256, 4), 512, 0, stream>>>(
            ps, D_, D_, L_, D_, D_, D_, 0, spw, srcm, attm, it);
        // softmax (rel-gather fused; masked rows -> uniform) st+ed
        k_softmax<<<dim3(B_ * L_, 2), 256, 0, stream>>>(
            scrSt, scrEd, outSts, outEds, attn_st, attn_ed,
            qrelbSt, qrelbEd, spw, it);
    }
}

// Round 11
// 709.152 us; speedup vs baseline: 1.5173x; 1.0489x over previous
//
#include <hip/hip_runtime.h>
#include <math.h>

#define B_   8
#define L_   1024
#define D_   768
#define R_   16
#define NSP  4
#define NREL 33
#define TRASH (B_ * L_)   // scatter row for masked keys

typedef __attribute__((ext_vector_type(8))) short bf16x8;
typedef __attribute__((ext_vector_type(4))) float f32x4;
typedef __attribute__((address_space(1))) const void gv_t;
typedef __attribute__((address_space(3))) void sv_t;

__device__ __forceinline__ unsigned short f2bf(float f) {
    unsigned int u = __float_as_uint(f);
    u += 0x7fff + ((u >> 16) & 1);          // RNE
    return (unsigned short)(u >> 16);
}
__device__ __forceinline__ float bf2f(unsigned short s) {
    return __uint_as_float(((unsigned int)s) << 16);
}
__device__ __forceinline__ unsigned short f2h(float f) {
    _Float16 h = (_Float16)f;
    return *(unsigned short*)&h;
}
__device__ __forceinline__ float h2f(unsigned short u) {
    _Float16 h = *(_Float16*)&u;
    return (float)h;
}

struct PSet {
    const unsigned short* A0;
    const unsigned short* B0;
    const unsigned short* A1;   // dual-K phase 2
    const unsigned short* B1;
    const float*          bias;
    const unsigned short* addend;
    void*                 Cout;
    float*                qout;    // mode 2 output (fp32 qrel)
    const float*          bterm;   // mode 1 per-key bias (compacted)
    const int*            rmap;    // mode 0 store-row remap (nullptr = identity)
    long                  bB0;     // per-batch stride of B0 (0 = unbatched)
    long                  cStride;
    long                  mValid;  // prep kernel row guard
    float                 scale;
    int                   mode;    // 0=bf16 C, 1=scores->fp16 scratch, 2=qrel
    int                   relu;
    int                   nValid;  // early-exit when col0 >= nValid
    int                   useCnt;  // also exit when col0 >= cntp[b]
    int                   varK0;   // K0 = round64(cntp[b])
};
struct PSet4 { PSet s[4]; };

// ===========================================================================
// 8-phase 256x256 MFMA GEMM (T2+T3+T4+T5). BK=64, 8 waves (2Mx4N), 512 thr.
// LDS 128 KiB dbuf, st_16x32 XOR-swizzle reads + inverse-swizzled global src,
// linear global_load_lds dest, counted vmcnt(4). Runtime per-z mode/epilogue.
// Per-batch variable K0 (key compaction) and per-batch col bound via cntp.
__global__ __launch_bounds__(512, 2) void k_mfma8(
    PSet4 ps, long aS0, long bS0, int bR0, int K0,
    long aS1, long bS1, int K1, const int* __restrict__ cntp)
{
    PSet p = ps.s[blockIdx.z];
    const int col0 = blockIdx.x * 256;
    if (col0 >= p.nValid) return;
    const long row0 = (long)blockIdx.y * 256;
    const int b = (int)(row0 >> 10);
    const int cb = (p.useCnt | p.varK0) ? cntp[b] : 0;
    if (p.useCnt && col0 >= cb) return;

    __shared__ unsigned short lds[2][2][256 * 64];   // 128 KiB

    const int tid  = threadIdx.x;
    const int lane = tid & 63;
    const int wave = tid >> 6;
    const int wr = wave >> 2;           // 0..1 (M half)
    const int wc = wave & 3;            // 0..3 (N quarter)
    const int lq = lane >> 4, lr = lane & 15;

    const unsigned short* Bb0 = p.B0 + (row0 / bR0) * p.bB0;

    const int K0l = p.varK0 ? ((cb + 63) & ~63) : K0;
    const int NT0 = K0l / 64;
    const int NT  = NT0 + K1 / 64;

    f32x4 acc[8][4];
#pragma unroll
    for (int m = 0; m < 8; ++m)
#pragma unroll
        for (int n = 0; n < 4; ++n) acc[m][n] = (f32x4)0.f;

    auto stageHalf = [&](int tt, int side, int h) {
        if (tt >= NT) return;
        const unsigned short* src; long stride; int k0;
        if (tt < NT0) { src = side ? Bb0  : p.A0; stride = side ? bS0 : aS0; k0 = tt * 64; }
        else          { src = side ? p.B1 : p.A1; stride = side ? bS1 : aS1; k0 = (tt - NT0) * 64; }
        const long base = side ? (long)col0 : row0;
        unsigned short* dst = &lds[tt & 1][side][h * 8192];
#pragma unroll
        for (int j = 0; j < 2; ++j) {
            const int r = j * 64 + wave * 8 + (lane >> 3);
            const int csrc = ((lane & 7) * 8) ^ (((r >> 2) & 1) << 4);
            const unsigned short* g = src + (base + h * 128 + r) * stride + k0 + csrc;
            __builtin_amdgcn_global_load_lds((gv_t*)g,
                (sv_t*)(dst + j * 4096 + wave * 512), 16, 0, 0);
        }
    };
    auto rd = [&](int bt, int side, int r, int ks) -> bf16x8 {
        const int idx = r * 64 + (((ks << 5) | (lq << 3)) ^ (((r >> 2) & 1) << 4));
        return *(const bf16x8*)&lds[bt][side][idx];
    };

    stageHalf(0, 0, 0); stageHalf(0, 0, 1);
    stageHalf(0, 1, 0); stageHalf(0, 1, 1);
    stageHalf(1, 1, 0); stageHalf(1, 1, 1);
    if (1 < NT) asm volatile("s_waitcnt vmcnt(4)" ::: "memory");
    else        asm volatile("s_waitcnt vmcnt(0)" ::: "memory");
    __builtin_amdgcn_s_barrier();

    bf16x8 af[4][2], bfr[4][2];

    for (int t = 0; t < NT; ++t) {
        const int bt = t & 1;
        // phase 1: read A m0-3 + B n0-1; stage (t+1).A0
#pragma unroll
        for (int mf = 0; mf < 4; ++mf)
#pragma unroll
            for (int ks = 0; ks < 2; ++ks)
                af[mf][ks] = rd(bt, 0, wr * 128 + mf * 16 + lr, ks);
#pragma unroll
        for (int nf = 0; nf < 2; ++nf)
#pragma unroll
            for (int ks = 0; ks < 2; ++ks)
                bfr[nf][ks] = rd(bt, 1, wc * 64 + nf * 16 + lr, ks);
        stageHalf(t + 1, 0, 0);
        __builtin_amdgcn_s_barrier();
        asm volatile("s_waitcnt lgkmcnt(0)" ::: "memory");
        __builtin_amdgcn_sched_barrier(0);
        __builtin_amdgcn_s_setprio(1);
#pragma unroll
        for (int nf = 0; nf < 2; ++nf)
#pragma unroll
            for (int mf = 0; mf < 4; ++mf)
#pragma unroll
                for (int ks = 0; ks < 2; ++ks)
                    acc[mf][nf] = __builtin_amdgcn_mfma_f32_16x16x32_bf16(
                        af[mf][ks], bfr[nf][ks], acc[mf][nf], 0, 0, 0);
        __builtin_amdgcn_s_setprio(0);
        __builtin_amdgcn_s_barrier();
        // phase 2: read B n2-3; stage (t+1).A1
#pragma unroll
        for (int nf = 2; nf < 4; ++nf)
#pragma unroll
            for (int ks = 0; ks < 2; ++ks)
                bfr[nf][ks] = rd(bt, 1, wc * 64 + nf * 16 + lr, ks);
        stageHalf(t + 1, 0, 1);
        __builtin_amdgcn_s_barrier();
        asm volatile("s_waitcnt lgkmcnt(0)" ::: "memory");
        __builtin_amdgcn_sched_barrier(0);
        __builtin_amdgcn_s_setprio(1);
#pragma unroll
        for (int nf = 2; nf < 4; ++nf)
#pragma unroll
            for (int mf = 0; mf < 4; ++mf)
#pragma unroll
                for (int ks = 0; ks < 2; ++ks)
                    acc[mf][nf] = __builtin_amdgcn_mfma_f32_16x16x32_bf16(
                        af[mf][ks], bfr[nf][ks], acc[mf][nf], 0, 0, 0);
        __builtin_amdgcn_s_setprio(0);
        __builtin_amdgcn_s_barrier();
        // phase 3: read A m4-7; stage (t+2).B0
#pragma unroll
        for (int mf = 0; mf < 4; ++mf)
#pragma unroll
            for (int ks = 0; ks < 2; ++ks)
                af[mf][ks] = rd(bt, 0, wr * 128 + 64 + mf * 16 + lr, ks);
        stageHalf(t + 2, 1, 0);
        __builtin_amdgcn_s_barrier();
        asm volatile("s_waitcnt lgkmcnt(0)" ::: "memory");
        __builtin_amdgcn_sched_barrier(0);
        __builtin_amdgcn_s_setprio(1);
#pragma unroll
        for (int nf = 0; nf < 2; ++nf)
#pragma unroll
            for (int mf = 0; mf < 4; ++mf)
#pragma unroll
                for (int ks = 0; ks < 2; ++ks)
                    acc[4 + mf][nf] = __builtin_amdgcn_mfma_f32_16x16x32_bf16(
                        af[mf][ks], bfr[nf][ks], acc[4 + mf][nf], 0, 0, 0);
        __builtin_amdgcn_s_setprio(0);
        __builtin_amdgcn_s_barrier();
        // phase 4: stage (t+2).B1; counted vmcnt; MFMA m4-7 x n2-3
        stageHalf(t + 2, 1, 1);
        if (t + 2 < NT) asm volatile("s_waitcnt vmcnt(4)" ::: "memory");
        else            asm volatile("s_waitcnt vmcnt(0)" ::: "memory");
        __builtin_amdgcn_s_barrier();
        __builtin_amdgcn_sched_barrier(0);
        __builtin_amdgcn_s_setprio(1);
#pragma unroll
        for (int nf = 2; nf < 4; ++nf)
#pragma unroll
            for (int mf = 0; mf < 4; ++mf)
#pragma unroll
                for (int ks = 0; ks < 2; ++ks)
                    acc[4 + mf][nf] = __builtin_amdgcn_mfma_f32_16x16x32_bf16(
                        af[mf][ks], bfr[nf][ks], acc[4 + mf][nf], 0, 0, 0);
        __builtin_amdgcn_s_setprio(0);
        __builtin_amdgcn_s_barrier();
    }

    // ---------------- epilogue (runtime mode) ----------------
    if (p.mode == 0) {
        unsigned short* C = (unsigned short*)p.Cout;
#pragma unroll
        for (int nf = 0; nf < 4; ++nf) {
            const int col = col0 + wc * 64 + nf * 16 + lr;
            const float bc = p.bias ? p.bias[col] : 0.f;
#pragma unroll
            for (int mf = 0; mf < 8; ++mf) {
#pragma unroll
                for (int rr = 0; rr < 4; ++rr) {
                    const long row = row0 + wr * 128 + mf * 16 + lq * 4 + rr;
                    float v = acc[mf][nf][rr] + bc;
                    if (p.addend) v += bf2f(p.addend[row * p.cStride + col]);
                    v *= p.scale;
                    if (p.relu) v = fmaxf(v, 0.f);
                    const long srow = p.rmap ? (long)p.rmap[row] : row;
                    C[srow * p.cStride + col] = f2bf(v);
                }
            }
        }
    } else if (p.mode == 1) {
        unsigned short* C = (unsigned short*)p.Cout;   // fp16 scratch [m][L] compacted
        float btv[4];
#pragma unroll
        for (int nf = 0; nf < 4; ++nf)
            btv[nf] = p.bterm[b * L_ + col0 + wc * 64 + nf * 16 + lr];
#pragma unroll
        for (int mf = 0; mf < 8; ++mf) {
#pragma unroll
            for (int rr = 0; rr < 4; ++rr) {
                const long mg = row0 + wr * 128 + mf * 16 + lq * 4 + rr;
#pragma unroll
                for (int nf = 0; nf < 4; ++nf) {
                    const int col = col0 + wc * 64 + nf * 16 + lr;
                    C[mg * L_ + col] = f2h(acc[mf][nf][rr] + btv[nf]);
                }
            }
        }
    } else {   // mode 2: qrel fp32 (col < NREL)
        float* qout = p.qout;
#pragma unroll
        for (int nf = 0; nf < 3; ++nf) {
            const int col = wc * 64 + nf * 16 + lr;
            if (col < NREL) {
                const float bc = p.bias[col];
#pragma unroll
                for (int mf = 0; mf < 8; ++mf)
#pragma unroll
                    for (int rr = 0; rr < 4; ++rr) {
                        const long mg = row0 + wr * 128 + mf * 16 + lq * 4 + rr;
                        qout[mg * NREL + col] = (acc[mf][nf][rr] + bc) * p.scale;
                    }
            }
        }
    }
}

// ===========================================================================
// 2-phase 128x128 kernel (prep-only: GtT / Wqrel, small M)
__global__ __launch_bounds__(256) void k_mfma_prep(
    PSet4 ps, long aS0, long bS0, int K0)
{
    PSet p = ps.s[blockIdx.z];
    const long row0 = (long)blockIdx.y * 128;
    if (row0 >= p.mValid) return;
    const int col0 = blockIdx.x * 128;

    __shared__ unsigned short As[2][128 * 32];
    __shared__ unsigned short Bs[2][128 * 32];
    const int tid  = threadIdx.x;
    const int lane = tid & 63;
    const int wave = tid >> 6;
    const int wr = wave >> 1, wc = wave & 1;
    const int lq = lane >> 4, lr = lane & 15;
    const int sr = lane >> 2;
    const int sc = (lane & 3) * 8;

    f32x4 acc[4][4];
#pragma unroll
    for (int m = 0; m < 4; ++m)
#pragma unroll
        for (int n = 0; n < 4; ++n) acc[m][n] = (f32x4)0.f;

    const int NT = K0 / 32;
    auto stage = [&](int t, int buf) {
        const int k0 = t * 32;
#pragma unroll
        for (int j = 0; j < 2; ++j) {
            const int c = wave + j * 4;
            const unsigned short* ga = p.A0 + (row0 + c * 16 + sr) * aS0 + k0 + sc;
            const unsigned short* gb = p.B0 + (long)(col0 + c * 16 + sr) * bS0 + k0 + sc;
            __builtin_amdgcn_global_load_lds((gv_t*)ga, (sv_t*)&As[buf][c * 512], 16, 0, 0);
            __builtin_amdgcn_global_load_lds((gv_t*)gb, (sv_t*)&Bs[buf][c * 512], 16, 0, 0);
        }
    };
    stage(0, 0);
    asm volatile("s_waitcnt vmcnt(0)" ::: "memory");
    __builtin_amdgcn_s_barrier();
    int cur = 0;
    for (int t = 0; t < NT; ++t) {
        if (t + 1 < NT) stage(t + 1, cur ^ 1);
        bf16x8 a4[4], b4[4];
#pragma unroll
        for (int m = 0; m < 4; ++m)
            a4[m] = *(const bf16x8*)&As[cur][(wr * 64 + m * 16 + lr) * 32 + lq * 8];
#pragma unroll
        for (int n = 0; n < 4; ++n)
            b4[n] = *(const bf16x8*)&Bs[cur][(wc * 64 + n * 16 + lr) * 32 + lq * 8];
#pragma unroll
        for (int m = 0; m < 4; ++m)
#pragma unroll
            for (int n = 0; n < 4; ++n)
                acc[m][n] = __builtin_amdgcn_mfma_f32_16x16x32_bf16(a4[m], b4[n], acc[m][n], 0, 0, 0);
        asm volatile("s_waitcnt vmcnt(0)" ::: "memory");
        __builtin_amdgcn_s_barrier();
        cur ^= 1;
    }
    unsigned short* C = (unsigned short*)p.Cout;
#pragma unroll
    for (int n = 0; n < 4; ++n) {
        const int col = col0 + wc * 64 + n * 16 + lr;
#pragma unroll
        for (int m = 0; m < 4; ++m)
#pragma unroll
            for (int r = 0; r < 4; ++r) {
                const long row = row0 + wr * 64 + m * 16 + lq * 4 + r;
                C[row * p.cStride + col] = f2bf(acc[m][n][r]);
            }
    }
}

// ---------------------------------------------------------------------------
struct Zero8 { float4* p[8]; long n4[8]; };
__global__ __launch_bounds__(256) void k_zero8(Zero8 z)
{
    long g = (long)blockIdx.x * 256 + threadIdx.x;
#pragma unroll
    for (int s = 0; s < 8; ++s) {
        if (g < z.n4[s]) {
            float4 v; v.x = v.y = v.z = v.w = 0.f;
            z.p[s][g] = v;
            return;
        }
        g -= z.n4[s];
    }
}

struct Cvt8 { const float* src[8]; unsigned short* dst[8]; long n4[8]; };
__global__ __launch_bounds__(256) void k_cvt8(Cvt8 c)
{
    long g = (long)blockIdx.x * 256 + threadIdx.x;
#pragma unroll
    for (int s = 0; s < 8; ++s) {
        if (g < c.n4[s]) {
            const float4 v = ((const float4*)c.src[s])[g];
            ushort4 o; o.x = f2bf(v.x); o.y = f2bf(v.y); o.z = f2bf(v.z); o.w = f2bf(v.w);
            ((ushort4*)c.dst[s])[g] = o;
            return;
        }
        g -= c.n4[s];
    }
}

__global__ __launch_bounds__(256) void k_transpose(
    const float* __restrict__ in, unsigned short* __restrict__ out, int rows, int cols)
{
    __shared__ float t[32][33];
    const long zo = (long)blockIdx.z * rows * cols;
    const int c0 = blockIdx.x * 32, r0 = blockIdx.y * 32;
    const int tx = threadIdx.x & 31, ty = threadIdx.x >> 5;
#pragma unroll
    for (int i = 0; i < 32; i += 8)
        t[ty + i][tx] = in[zo + (long)(r0 + ty + i) * cols + c0 + tx];
    __syncthreads();
#pragma unroll
    for (int i = 0; i < 32; i += 8)
        out[zo + (long)(c0 + ty + i) * rows + r0 + tx] = f2bf(t[tx][ty + i]);
}

// bf16 [rows][cols] -> bf16 [cols][rows], batched over z (separate strides)
__global__ __launch_bounds__(256) void k_transpose_bf(
    const unsigned short* __restrict__ in, long inBatch,
    unsigned short* __restrict__ out, long outBatch, int rows, int cols)
{
    __shared__ unsigned short t[32][33];
    const int z = blockIdx.z;
    const unsigned short* I = in + (long)z * inBatch;
    unsigned short* O = out + (long)z * outBatch;
    const int c0 = blockIdx.x * 32, r0 = blockIdx.y * 32;
    const int tx = threadIdx.x & 31, ty = threadIdx.x >> 5;
#pragma unroll
    for (int i = 0; i < 32; i += 8)
        t[ty + i][tx] = I[(long)(r0 + ty + i) * cols + c0 + tx];
    __syncthreads();
#pragma unroll
    for (int i = 0; i < 32; i += 8)
        O[(long)(c0 + ty + i) * rows + r0 + tx] = t[tx][ty + i];
}

// ---------------------------------------------------------------------------
// biasQ[896]: [0..767] = bq.Wk[i,:]; [768+r] = bq.rel[r,:]; wave per output
__global__ __launch_bounds__(256) void k_biasq(
    const float* __restrict__ bq0, const float* __restrict__ bq1,
    const float* __restrict__ wk0, const float* __restrict__ wk1,
    const float* __restrict__ rel0, const float* __restrict__ rel1,
    float* __restrict__ out0, float* __restrict__ out1)
{
    const int z = blockIdx.y;
    const float* bq  = z ? bq1  : bq0;
    const float* wk  = z ? wk1  : wk0;
    const float* rel = z ? rel1 : rel0;
    float* out       = z ? out1 : out0;
    const int i = blockIdx.x * 4 + (threadIdx.x >> 6);
    const int lane = threadIdx.x & 63;
    const float* w = nullptr;
    if (i < D_) w = wk + (long)i * D_;
    else if (i - D_ < NREL) w = rel + (long)(i - D_) * D_;
    float a = 0.f;
    if (w)
        for (int e = lane * 4; e < D_; e += 256) {
            const float4 w4 = *(const float4*)&w[e];
            const float4 b4 = *(const float4*)&bq[e];
            a += w4.x * b4.x + w4.y * b4.y + w4.z * b4.z + w4.w * b4.w;
        }
#pragma unroll
    for (int o = 32; o > 0; o >>= 1) a += __shfl_xor(a, o, 64);
    if (lane == 0) out[i] = a;
}

// ---------------------------------------------------------------------------
// per-batch key compaction via block prefix scan (no atomics, deterministic)
__global__ __launch_bounds__(256) void k_scan(
    const int* __restrict__ attm, int* __restrict__ keyidx,
    int* __restrict__ rmap, int* __restrict__ cnt)
{
    const int b = blockIdx.x;
    const int t = threadIdx.x;
    __shared__ int sc[256];
    const int base = b * 1024 + t * 4;
    int pred[4]; int c = 0;
#pragma unroll
    for (int j = 0; j < 4; ++j) { pred[j] = (attm[base + j] != 0) ? 1 : 0; c += pred[j]; }
    sc[t] = c;
    __syncthreads();
    for (int ofs = 1; ofs < 256; ofs <<= 1) {
        const int v = (t >= ofs) ? sc[t - ofs] : 0;
        __syncthreads();
        sc[t] += v;
        __syncthreads();
    }
    int pos = sc[t] - c;                    // exclusive prefix
#pragma unroll
    for (int j = 0; j < 4; ++j) {
        if (pred[j]) {
            keyidx[base + j] = pos;
            rmap[base + j]   = b * 1024 + pos;
            ++pos;
        } else {
            keyidx[base + j] = -1;
            rmap[base + j]   = TRASH;
        }
    }
    if (t == 0) cnt[b] = sc[255];
}

// bterm compacted: btermC[b][keyidx[m]] = invs * biasQ . hid[m]
__global__ __launch_bounds__(256) void k_bterm(
    const unsigned short* __restrict__ hid_bf,
    const float* __restrict__ biasQ0, const float* __restrict__ biasQ1,
    float* __restrict__ out0, float* __restrict__ out1,
    const int* __restrict__ keyidx, float invs)
{
    const float* biasQ = blockIdx.y ? biasQ1 : biasQ0;
    float* out = blockIdx.y ? out1 : out0;
    const long row = (long)blockIdx.x * 4 + (threadIdx.x >> 6);
    const int lane = threadIdx.x & 63;
    const unsigned short* h = hid_bf + row * D_;
    float a = 0.f;
    for (int d = lane * 4; d < D_; d += 256) {
        const ushort4 u = *(const ushort4*)&h[d];
        const float4 bq4 = *(const float4*)&biasQ[d];
        a += bf2f(u.x) * bq4.x + bf2f(u.y) * bq4.y + bf2f(u.z) * bq4.z + bf2f(u.w) * bq4.w;
    }
#pragma unroll
    for (int o = 32; o > 0; o >>= 1) a += __shfl_xor(a, o, 64);
    if (lane == 0) {
        const int ji = keyidx[row];
        if (ji >= 0) out[(row & ~(long)(L_ - 1)) + ji] = a * invs;
    }
}

// ---------------------------------------------------------------------------
// softmax: masked rows -> uniform 1/L; active rows read COMPACTED fp16
// scratch via keyidx gather, add qrel, write fp32 d_out (0 at masked cols)
// and compacted bf16 attn.
__global__ __launch_bounds__(256) void k_softmax(
    const unsigned short* __restrict__ sSt, const unsigned short* __restrict__ sEd,
    float* __restrict__ oSt, float* __restrict__ oEd,
    unsigned short* __restrict__ aSt, unsigned short* __restrict__ aEd,
    const float* __restrict__ qrSt, const float* __restrict__ qrEd,
    const int* __restrict__ spw, const int* __restrict__ srcm,
    const int* __restrict__ keyidx, const int* __restrict__ cnt, int it)
{
    const long m = blockIdx.x;
    const int b = (int)(m >> 10);
    float* o = (blockIdx.y ? oEd : oSt) + (m * NSP + it) * L_;
    const int t = threadIdx.x;
    if (spw[m] <= it || srcm[m] == 0 || cnt[b] == 0) {   // fully masked row
        float4 u; u.x = u.y = u.z = u.w = 0.0009765625f;
        *(float4*)&o[4 * t] = u;
        return;
    }
    const unsigned short* s = (blockIdx.y ? sEd : sSt) + m * L_;
    unsigned short* a = (blockIdx.y ? aEd : aSt) + m * L_;
    const float* qrow = (blockIdx.y ? qrEd : qrSt) + m * NREL;
    const int q = (int)(m & (L_ - 1));
    int ji[4]; float vv[4];
#pragma unroll
    for (int j = 0; j < 4; ++j) {
        const int c = 4 * t + j;
        ji[j] = keyidx[b * L_ + c];
        if (ji[j] >= 0) {
            int dr = c - q;
            dr = dr < -R_ ? -R_ : (dr > R_ ? R_ : dr);
            vv[j] = h2f(s[ji[j]]) + qrow[dr + R_];
        } else {
            vv[j] = -1e18f;
        }
    }
    float mx = fmaxf(fmaxf(vv[0], vv[1]), fmaxf(vv[2], vv[3]));
#pragma unroll
    for (int ofs = 32; ofs > 0; ofs >>= 1) mx = fmaxf(mx, __shfl_xor(mx, ofs, 64));
    __shared__ float redm[4];
    __shared__ float reds[4];
    const int wave = t >> 6;
    if ((t & 63) == 0) redm[wave] = mx;
    __syncthreads();
    mx = fmaxf(fmaxf(redm[0], redm[1]), fmaxf(redm[2], redm[3]));
    float sum = 0.f;
#pragma unroll
    for (int j = 0; j < 4; ++j) { vv[j] = expf(vv[j] - mx); sum += vv[j]; }
#pragma unroll
    for (int ofs = 32; ofs > 0; ofs >>= 1) sum += __shfl_xor(sum, ofs, 64);
    if ((t & 63) == 0) reds[wave] = sum;
    __syncthreads();
    sum = reds[0] + reds[1] + reds[2] + reds[3];
    const float inv = 1.0f / sum;
    float4 v; v.x = vv[0] * inv; v.y = vv[1] * inv; v.z = vv[2] * inv; v.w = vv[3] * inv;
    *(float4*)&o[4 * t] = v;
    const float* vp = (const float*)&v;
#pragma unroll
    for (int j = 0; j < 4; ++j)
        if (ji[j] >= 0) a[ji[j]] = f2bf(vp[j]);
}

// ---------------------------------------------------------------------------
__global__ __launch_bounds__(256) void k_batchsum(
    const float* __restrict__ hid, const int* __restrict__ attm, float* __restrict__ pooled)
{
    const int b = blockIdx.x;
    const int d = blockIdx.y * 256 + threadIdx.x;
    const int k0 = blockIdx.z * 128;
    const float* hb = hid + (long)b * L_ * D_;
    float acc = 0.f;
    for (int k = k0; k < k0 + 128; ++k)
        acc += attm[b * L_ + k] ? hb[(long)k * D_ + d] : 0.f;
    atomicAdd(&pooled[b * D_ + d], acc);
}

__global__ __launch_bounds__(256) void k_pw2(
    const float* __restrict__ pooled, const float* __restrict__ W_sp, float* __restrict__ pw2)
{
    const int b = blockIdx.x;
    const int n = blockIdx.y * 256 + threadIdx.x;
    const int d0 = blockIdx.z * 96;
    float acc = 0.f;
    for (int d = d0; d < d0 + 96; ++d)
        acc += pooled[b * D_ + d] * W_sp[(long)(D_ + d) * D_ + n];
    atomicAdd(&pw2[b * D_ + n], acc);
}

__global__ __launch_bounds__(256) void k_addend0m(
    const float* __restrict__ pw2, const int* __restrict__ cnt,
    const int* __restrict__ srcm, const int* __restrict__ spw,
    unsigned short* __restrict__ out, float* __restrict__ outM)
{
    const long idx = (long)blockIdx.x * 256 + threadIdx.x;
    const int d = (int)(idx % D_);
    const long m = idx / D_;
    const int b = (int)(m >> 10);
    const float inv = 1.0f / fmaxf((float)cnt[b], 1.0f);
    out[idx] = f2bf(srcm[m] ? pw2[b * D_ + d] * inv : 0.0f);
    if (idx < (long)B_ * L_ * NSP)
        outM[idx] = ((int)(idx & 3) < spw[idx >> 2]) ? 1.0f : 0.0f;
}

// ---------------------------------------------------------------------------
extern "C" void kernel_launch(void* const* d_in, const int* in_sizes, int n_in,
                              void* d_out, int out_size, void* d_ws, size_t ws_size,
                              hipStream_t stream)
{
    (void)in_sizes; (void)n_in; (void)out_size; (void)ws_size;
    const float* hid     = (const float*)d_in[0];
    const float* src_hid = (const float*)d_in[1];
    const int*   spw     = (const int*)d_in[2];
    const int*   attm    = (const int*)d_in[3];
    const int*   srcm    = (const int*)d_in[4];
    const float* Wq_st = (const float*)d_in[6];
    const float* bq_st = (const float*)d_in[7];
    const float* Wk_st = (const float*)d_in[8];
    const float* rel_st= (const float*)d_in[10];
    const float* Wq_ed = (const float*)d_in[11];
    const float* bq_ed = (const float*)d_in[12];
    const float* Wk_ed = (const float*)d_in[13];
    const float* rel_ed= (const float*)d_in[15];
    const float* W_sp  = (const float*)d_in[16];
    const float* b_sp  = (const float*)d_in[17];

    float* out      = (float*)d_out;
    float* outSts   = out;
    float* outEds   = out + (long)B_ * L_ * NSP * L_;
    float* outMasks = outEds + (long)B_ * L_ * NSP * L_;

    const long S = (long)B_ * L_ * D_;
    const long DD = (long)D_ * D_;
    const long ML = (long)B_ * L_;
    const long SX = (ML + 256) * (long)D_;   // scatter targets (+trash rows)
    char* wsB = (char*)d_ws;
    auto take = [&](size_t bytes) -> char* {
        char* p = wsB; wsB += (bytes + 255) & ~(size_t)255; return p;
    };
    unsigned short* hid_bf  = (unsigned short*)take(S * 2);
    unsigned short* src_bf  = (unsigned short*)take(S * 2);
    unsigned short* h1a     = (unsigned short*)take(S * 2);
    unsigned short* h1b     = (unsigned short*)take(S * 2);
    unsigned short* h2a     = (unsigned short*)take(S * 2);
    unsigned short* h2b     = (unsigned short*)take(S * 2);
    unsigned short* tmpPC   = (unsigned short*)take(SX * 2);  // hid@W2, key-compacted
    unsigned short* hidW2TC = (unsigned short*)take(S * 2);   // [B][D][L] compacted keys
    unsigned short* add0    = (unsigned short*)take(S * 2);
    unsigned short* hidGCst = (unsigned short*)take(SX * 2);  // key-compacted
    unsigned short* hidGCed = (unsigned short*)take(SX * 2);
    unsigned short* GtTst   = (unsigned short*)take(DD * 2);
    unsigned short* GtTed   = (unsigned short*)take(DD * 2);
    unsigned short* W1T     = (unsigned short*)take(DD * 2);  // contiguous with W2T
    unsigned short* W2T     = (unsigned short*)take(DD * 2);
    unsigned short* WqBfSt  = (unsigned short*)take(DD * 2);
    unsigned short* WqBfEd  = (unsigned short*)take(DD * 2);
    unsigned short* WkBfSt  = (unsigned short*)take(DD * 2);
    unsigned short* WkBfEd  = (unsigned short*)take(DD * 2);
    unsigned short* relbst  = (unsigned short*)take((long)128 * D_ * 2);
    unsigned short* relbed  = (unsigned short*)take((long)128 * D_ * 2);
    unsigned short* WqrelSt = (unsigned short*)take((long)256 * D_ * 2);
    unsigned short* WqrelEd = (unsigned short*)take((long)256 * D_ * 2);
    unsigned short* attn_st = (unsigned short*)take(ML * L_ * 2);   // compacted bf16 attn
    unsigned short* attn_ed = (unsigned short*)take(ML * L_ * 2);
    unsigned short* scrSt   = (unsigned short*)take(ML * L_ * 2);   // fp16 scores (compacted cols)
    unsigned short* scrEd   = (unsigned short*)take(ML * L_ * 2);
    float* qrelbSt = (float*)take(ML * NREL * 4);
    float* qrelbEd = (float*)take(ML * NREL * 4);
    float* biasQst = (float*)take(896 * 4);
    float* biasQed = (float*)take(896 * 4);
    float* btermCst= (float*)take(ML * 4);
    float* btermCed= (float*)take(ML * 4);
    float* pooled  = (float*)take((long)B_ * D_ * 4);
    float* pw2     = (float*)take((long)B_ * D_ * 4);
    int*   keyidx  = (int*)take(ML * 4);
    int*   rmap    = (int*)take(ML * 4);
    int*   cnt     = (int*)take(256);

    const float invs = 1.0f / sqrtf((float)D_);
    const long BB   = (long)L_ * D_;
    const int  NOB  = 1 << 30;

    PSet4 ps;
    auto clr = [&](int i) {
        ps.s[i] = PSet{nullptr,nullptr,nullptr,nullptr,nullptr,nullptr,nullptr,
                       nullptr,nullptr,nullptr,0,0,1L<<40,1.f,0,0,1<<30,0,0};
    };

    // ---- prep ----
    {
        Zero8 z;
        z.p[0] = (float4*)(relbst + (long)NREL * D_);  z.n4[0] = (long)(128 - NREL) * D_ * 2 / 16;
        z.p[1] = (float4*)(relbed + (long)NREL * D_);  z.n4[1] = (long)(128 - NREL) * D_ * 2 / 16;
        z.p[2] = (float4*)(WqrelSt + (long)128 * D_);  z.n4[2] = (long)128 * D_ * 2 / 16;
        z.p[3] = (float4*)(WqrelEd + (long)128 * D_);  z.n4[3] = (long)128 * D_ * 2 / 16;
        z.p[4] = (float4*)pooled;                      z.n4[4] = (long)B_ * D_ / 4;
        z.p[5] = (float4*)pw2;                         z.n4[5] = (long)B_ * D_ / 4;
        z.p[6] = (float4*)attn_st;                     z.n4[6] = ML * L_ * 2 / 16;
        z.p[7] = (float4*)attn_ed;                     z.n4[7] = ML * L_ * 2 / 16;
        long tot = 0; for (int i = 0; i < 8; ++i) tot += z.n4[i];
        k_zero8<<<(int)((tot + 255) / 256), 256, 0, stream>>>(z);
    }
    {
        Cvt8 c;
        c.src[0] = hid;     c.dst[0] = hid_bf;  c.n4[0] = S / 4;
        c.src[1] = src_hid; c.dst[1] = src_bf;  c.n4[1] = S / 4;
        c.src[2] = Wq_st;   c.dst[2] = WqBfSt;  c.n4[2] = DD / 4;
        c.src[3] = Wq_ed;   c.dst[3] = WqBfEd;  c.n4[3] = DD / 4;
        c.src[4] = Wk_st;   c.dst[4] = WkBfSt;  c.n4[4] = DD / 4;
        c.src[5] = Wk_ed;   c.dst[5] = WkBfEd;  c.n4[5] = DD / 4;
        c.src[6] = rel_st;  c.dst[6] = relbst;  c.n4[6] = (long)NREL * D_ / 4;
        c.src[7] = rel_ed;  c.dst[7] = relbed;  c.n4[7] = (long)NREL * D_ / 4;
        long tot = 0; for (int i = 0; i < 8; ++i) tot += c.n4[i];
        k_cvt8<<<(int)((tot + 255) / 256), 256, 0, stream>>>(c);
    }
    k_transpose<<<dim3(D_ / 32, D_ / 32, 2), 256, 0, stream>>>(W_sp, W1T, D_, D_);
    k_biasq<<<dim3(224, 2), 256, 0, stream>>>(bq_st, bq_ed, Wk_st, Wk_ed,
                                              rel_st, rel_ed, biasQst, biasQed);
    k_scan<<<B_, 256, 0, stream>>>(attm, keyidx, rmap, cnt);
    k_batchsum<<<dim3(B_, D_ / 256, 8), 256, 0, stream>>>(hid, attm, pooled);
    k_pw2<<<dim3(B_, D_ / 256, 8), 256, 0, stream>>>(pooled, W_sp, pw2);
    k_addend0m<<<(int)(S / 256), 256, 0, stream>>>(pw2, cnt, srcm, spw, add0, outMasks);
    k_bterm<<<dim3(B_ * L_ / 4, 2), 256, 0, stream>>>(hid_bf, biasQst, biasQed,
                                                      btermCst, btermCed, keyidx, invs);

    // GtT (Wq.Wk^T) + Wqrel (rel.Wq^T), 2-phase 128^2 kernel, z=4
    for (int i = 0; i < 4; ++i) clr(i);
    ps.s[0].A0 = WqBfSt; ps.s[0].B0 = WkBfSt; ps.s[0].Cout = GtTst;   ps.s[0].cStride = D_; ps.s[0].mValid = D_;
    ps.s[1].A0 = WqBfEd; ps.s[1].B0 = WkBfEd; ps.s[1].Cout = GtTed;   ps.s[1].cStride = D_; ps.s[1].mValid = D_;
    ps.s[2].A0 = relbst; ps.s[2].B0 = WqBfSt; ps.s[2].Cout = WqrelSt; ps.s[2].cStride = D_; ps.s[2].mValid = 128;
    ps.s[3].A0 = relbed; ps.s[3].B0 = WqBfEd; ps.s[3].Cout = WqrelEd; ps.s[3].cStride = D_; ps.s[3].mValid = 128;
    k_mfma_prep<<<dim3(D_ / 128, D_ / 128, 4), 256, 0, stream>>>(ps, D_, D_, D_);

    // concat0 + hid@W2 (scattered) + hidGC st/ed (scattered) : one z=4 dispatch
    for (int i = 0; i < 4; ++i) clr(i);
    ps.s[0].A0 = src_bf; ps.s[0].B0 = W1T;   ps.s[0].bias = b_sp; ps.s[0].addend = add0;
    ps.s[0].Cout = h1a;  ps.s[0].cStride = D_; ps.s[0].relu = 1; ps.s[0].nValid = D_;
    ps.s[1].A0 = hid_bf; ps.s[1].B0 = W2T;   ps.s[1].Cout = tmpPC;   ps.s[1].cStride = D_;
    ps.s[1].nValid = D_; ps.s[1].rmap = rmap;
    ps.s[2].A0 = hid_bf; ps.s[2].B0 = GtTst; ps.s[2].Cout = hidGCst; ps.s[2].cStride = D_;
    ps.s[2].scale = invs; ps.s[2].nValid = D_; ps.s[2].rmap = rmap;
    ps.s[3].A0 = hid_bf; ps.s[3].B0 = GtTed; ps.s[3].Cout = hidGCed; ps.s[3].cStride = D_;
    ps.s[3].scale = invs; ps.s[3].nValid = D_; ps.s[3].rmap = rmap;
    k_mfma8<<<dim3(D_ / 256, (B_ * L_) / 256, 4), 512, 0, stream>>>(
        ps, D_, D_, NOB, D_, D_, D_, 0, cnt);
    k_transpose_bf<<<dim3(D_ / 32, L_ / 32, B_), 256, 0, stream>>>(
        tmpPC, (long)L_ * D_, hidW2TC, (long)D_ * L_, L_, D_);

    unsigned short* h1cur = h1a; unsigned short* h2cur = h1a;
    unsigned short* h1nxt = h1b; unsigned short* h2nxt = h2a;

    for (int it = 0; it < NSP; ++it) {
        if (it > 0) {
            // fused pooling+concat: attnC@hidW2TC (K=round64(cnt[b])) + hcur@W1 (K=768)
            for (int i = 0; i < 4; ++i) clr(i);
            ps.s[0].A0 = attn_st; ps.s[0].B0 = hidW2TC; ps.s[0].A1 = h1cur; ps.s[0].B1 = W1T;
            ps.s[0].bias = b_sp; ps.s[0].Cout = h1nxt; ps.s[0].cStride = D_;
            ps.s[0].relu = 1; ps.s[0].bB0 = (long)D_ * L_; ps.s[0].nValid = D_; ps.s[0].varK0 = 1;
            ps.s[1] = ps.s[0];
            ps.s[1].A0 = attn_ed; ps.s[1].A1 = h2cur; ps.s[1].Cout = h2nxt;
            k_mfma8<<<dim3(D_ / 256, (B_ * L_) / 256, 2), 512, 0, stream>>>(
                ps, L_, L_, L_, 1024, D_, D_, D_, cnt);
            h1cur = h1nxt; h2cur = h2nxt;
            h1nxt = (h1cur == h1a) ? h1b : h1a;
            h2nxt = (h2cur == h2a) ? h2b : h2a;
        }
        // scores over COMPACTED key cols (z0,z1 -> fp16 scratch) + qrel (z2,z3)
        for (int i = 0; i < 4; ++i) clr(i);
        ps.s[0].A0 = h1cur; ps.s[0].B0 = hidGCst; ps.s[0].Cout = scrSt;
        ps.s[0].bterm = btermCst; ps.s[0].bB0 = BB; ps.s[0].mode = 1;
        ps.s[0].cStride = L_; ps.s[0].nValid = L_; ps.s[0].useCnt = 1;
        ps.s[1].A0 = h2cur; ps.s[1].B0 = hidGCed; ps.s[1].Cout = scrEd;
        ps.s[1].bterm = btermCed; ps.s[1].bB0 = BB; ps.s[1].mode = 1;
        ps.s[1].cStride = L_; ps.s[1].nValid = L_; ps.s[1].useCnt = 1;
        ps.s[2].A0 = h1cur; ps.s[2].B0 = WqrelSt; ps.s[2].qout = qrelbSt;
        ps.s[2].bias = biasQst + D_; ps.s[2].scale = invs; ps.s[2].mode = 2; ps.s[2].nValid = 256;
        ps.s[3].A0 = h2cur; ps.s[3].B0 = WqrelEd; ps.s[3].qout = qrelbEd;
        ps.s[3].bias = biasQed + D_; ps.s[3].scale = invs; ps.s[3].mode = 2; ps.s[3].nValid = 256;
        k_mfma8<<<dim3(L_ / 256, (B_ * L_) / 256, 4), 512, 0, stream>>>(
            ps, D_, D_, L_, D_, D_, D_, 0, cnt);
        // softmax: gather compacted scratch, write d_out + compacted attn
        k_softmax<<<dim3(B_ * L_, 2), 256, 0, stream>>>(
            scrSt, scrEd, outSts, outEds, attn_st, attn_ed,
            qrelbSt, qrelbEd, spw, srcm, keyidx, cnt, it);
    }
}

// Round 12
// 700.893 us; speedup vs baseline: 1.5351x; 1.0118x over previous
//
#include <hip/hip_runtime.h>
#include <math.h>

#define B_   8
#define L_   1024
#define D_   768
#define R_   16
#define NSP  4
#define NREL 33
#define TRASH (B_ * L_)   // scatter row for masked keys

typedef __attribute__((ext_vector_type(8))) short bf16x8;
typedef __attribute__((ext_vector_type(4))) float f32x4;
typedef __attribute__((address_space(1))) const void gv_t;
typedef __attribute__((address_space(3))) void sv_t;

__device__ __forceinline__ unsigned short f2bf(float f) {
    unsigned int u = __float_as_uint(f);
    u += 0x7fff + ((u >> 16) & 1);          // RNE
    return (unsigned short)(u >> 16);
}
__device__ __forceinline__ float bf2f(unsigned short s) {
    return __uint_as_float(((unsigned int)s) << 16);
}
__device__ __forceinline__ unsigned short f2h(float f) {
    _Float16 h = (_Float16)f;
    return *(unsigned short*)&h;
}
__device__ __forceinline__ float h2f(unsigned short u) {
    _Float16 h = *(_Float16*)&u;
    return (float)h;
}

struct PSet {
    const unsigned short* A0;
    const unsigned short* B0;
    const unsigned short* A1;   // dual-K phase 2
    const unsigned short* B1;
    const float*          bias;
    const unsigned short* addend;
    void*                 Cout;
    float*                qout;    // mode 2 output (fp32 qrel)
    const float*          bterm;   // mode 1 per-key bias (compacted)
    const int*            rmap;    // mode 0 store-row remap (nullptr = identity)
    long                  bB0;     // per-batch stride of B0 (0 = unbatched)
    long                  cStride;
    long                  mValid;  // prep kernel row guard
    float                 scale;
    int                   mode;    // 0=bf16 C, 1=scores->fp16 scratch, 2=qrel
    int                   relu;
    int                   nValid;  // early-exit when col0 >= nValid
    int                   useCnt;  // also exit when col0 >= cntp[b]
    int                   varK0;   // K0 = round64(cntp[b])
};
struct PSet4 { PSet s[4]; };

// ===========================================================================
// 8-phase 256x256 MFMA GEMM (T2+T3+T4+T5). BK=64, 8 waves (2Mx4N), 512 thr.
// LDS 128 KiB dbuf, st_16x32 XOR-swizzle reads + inverse-swizzled global src,
// linear global_load_lds dest, counted vmcnt(4). Runtime per-z mode/epilogue.
// Per-batch variable K0 (key compaction) and per-batch col bound via cntp.
__global__ __launch_bounds__(512, 2) void k_mfma8(
    PSet4 ps, long aS0, long bS0, int bR0, int K0,
    long aS1, long bS1, int K1, const int* __restrict__ cntp)
{
    PSet p = ps.s[blockIdx.z];
    const int col0 = blockIdx.x * 256;
    if (col0 >= p.nValid) return;
    const long row0 = (long)blockIdx.y * 256;
    const int b = (int)(row0 >> 10);
    const int cb = (p.useCnt | p.varK0) ? cntp[b] : 0;
    if (p.useCnt && col0 >= cb) return;

    __shared__ unsigned short lds[2][2][256 * 64];   // 128 KiB

    const int tid  = threadIdx.x;
    const int lane = tid & 63;
    const int wave = tid >> 6;
    const int wr = wave >> 2;           // 0..1 (M half)
    const int wc = wave & 3;            // 0..3 (N quarter)
    const int lq = lane >> 4, lr = lane & 15;

    const unsigned short* Bb0 = p.B0 + (row0 / bR0) * p.bB0;

    const int K0l = p.varK0 ? ((cb + 63) & ~63) : K0;
    const int NT0 = K0l / 64;
    const int NT  = NT0 + K1 / 64;

    f32x4 acc[8][4];
#pragma unroll
    for (int m = 0; m < 8; ++m)
#pragma unroll
        for (int n = 0; n < 4; ++n) acc[m][n] = (f32x4)0.f;

    auto stageHalf = [&](int tt, int side, int h) {
        if (tt >= NT) return;
        const unsigned short* src; long stride; int k0;
        if (tt < NT0) { src = side ? Bb0  : p.A0; stride = side ? bS0 : aS0; k0 = tt * 64; }
        else          { src = side ? p.B1 : p.A1; stride = side ? bS1 : aS1; k0 = (tt - NT0) * 64; }
        const long base = side ? (long)col0 : row0;
        unsigned short* dst = &lds[tt & 1][side][h * 8192];
#pragma unroll
        for (int j = 0; j < 2; ++j) {
            const int r = j * 64 + wave * 8 + (lane >> 3);
            const int csrc = ((lane & 7) * 8) ^ (((r >> 2) & 1) << 4);
            const unsigned short* g = src + (base + h * 128 + r) * stride + k0 + csrc;
            __builtin_amdgcn_global_load_lds((gv_t*)g,
                (sv_t*)(dst + j * 4096 + wave * 512), 16, 0, 0);
        }
    };
    auto rd = [&](int bt, int side, int r, int ks) -> bf16x8 {
        const int idx = r * 64 + (((ks << 5) | (lq << 3)) ^ (((r >> 2) & 1) << 4));
        return *(const bf16x8*)&lds[bt][side][idx];
    };

    stageHalf(0, 0, 0); stageHalf(0, 0, 1);
    stageHalf(0, 1, 0); stageHalf(0, 1, 1);
    stageHalf(1, 1, 0); stageHalf(1, 1, 1);
    if (1 < NT) asm volatile("s_waitcnt vmcnt(4)" ::: "memory");
    else        asm volatile("s_waitcnt vmcnt(0)" ::: "memory");
    __builtin_amdgcn_s_barrier();

    bf16x8 af[4][2], bfr[4][2];

    for (int t = 0; t < NT; ++t) {
        const int bt = t & 1;
        // phase 1: read A m0-3 + B n0-1; stage (t+1).A0
#pragma unroll
        for (int mf = 0; mf < 4; ++mf)
#pragma unroll
            for (int ks = 0; ks < 2; ++ks)
                af[mf][ks] = rd(bt, 0, wr * 128 + mf * 16 + lr, ks);
#pragma unroll
        for (int nf = 0; nf < 2; ++nf)
#pragma unroll
            for (int ks = 0; ks < 2; ++ks)
                bfr[nf][ks] = rd(bt, 1, wc * 64 + nf * 16 + lr, ks);
        stageHalf(t + 1, 0, 0);
        __builtin_amdgcn_s_barrier();
        asm volatile("s_waitcnt lgkmcnt(0)" ::: "memory");
        __builtin_amdgcn_sched_barrier(0);
        __builtin_amdgcn_s_setprio(1);
#pragma unroll
        for (int nf = 0; nf < 2; ++nf)
#pragma unroll
            for (int mf = 0; mf < 4; ++mf)
#pragma unroll
                for (int ks = 0; ks < 2; ++ks)
                    acc[mf][nf] = __builtin_amdgcn_mfma_f32_16x16x32_bf16(
                        af[mf][ks], bfr[nf][ks], acc[mf][nf], 0, 0, 0);
        __builtin_amdgcn_s_setprio(0);
        __builtin_amdgcn_s_barrier();
        // phase 2: read B n2-3; stage (t+1).A1
#pragma unroll
        for (int nf = 2; nf < 4; ++nf)
#pragma unroll
            for (int ks = 0; ks < 2; ++ks)
                bfr[nf][ks] = rd(bt, 1, wc * 64 + nf * 16 + lr, ks);
        stageHalf(t + 1, 0, 1);
        __builtin_amdgcn_s_barrier();
        asm volatile("s_waitcnt lgkmcnt(0)" ::: "memory");
        __builtin_amdgcn_sched_barrier(0);
        __builtin_amdgcn_s_setprio(1);
#pragma unroll
        for (int nf = 2; nf < 4; ++nf)
#pragma unroll
            for (int mf = 0; mf < 4; ++mf)
#pragma unroll
                for (int ks = 0; ks < 2; ++ks)
                    acc[mf][nf] = __builtin_amdgcn_mfma_f32_16x16x32_bf16(
                        af[mf][ks], bfr[nf][ks], acc[mf][nf], 0, 0, 0);
        __builtin_amdgcn_s_setprio(0);
        __builtin_amdgcn_s_barrier();
        // phase 3: read A m4-7; stage (t+2).B0
#pragma unroll
        for (int mf = 0; mf < 4; ++mf)
#pragma unroll
            for (int ks = 0; ks < 2; ++ks)
                af[mf][ks] = rd(bt, 0, wr * 128 + 64 + mf * 16 + lr, ks);
        stageHalf(t + 2, 1, 0);
        __builtin_amdgcn_s_barrier();
        asm volatile("s_waitcnt lgkmcnt(0)" ::: "memory");
        __builtin_amdgcn_sched_barrier(0);
        __builtin_amdgcn_s_setprio(1);
#pragma unroll
        for (int nf = 0; nf < 2; ++nf)
#pragma unroll
            for (int mf = 0; mf < 4; ++mf)
#pragma unroll
                for (int ks = 0; ks < 2; ++ks)
                    acc[4 + mf][nf] = __builtin_amdgcn_mfma_f32_16x16x32_bf16(
                        af[mf][ks], bfr[nf][ks], acc[4 + mf][nf], 0, 0, 0);
        __builtin_amdgcn_s_setprio(0);
        __builtin_amdgcn_s_barrier();
        // phase 4: stage (t+2).B1; counted vmcnt; MFMA m4-7 x n2-3
        stageHalf(t + 2, 1, 1);
        if (t + 2 < NT) asm volatile("s_waitcnt vmcnt(4)" ::: "memory");
        else            asm volatile("s_waitcnt vmcnt(0)" ::: "memory");
        __builtin_amdgcn_s_barrier();
        __builtin_amdgcn_sched_barrier(0);
        __builtin_amdgcn_s_setprio(1);
#pragma unroll
        for (int nf = 2; nf < 4; ++nf)
#pragma unroll
            for (int mf = 0; mf < 4; ++mf)
#pragma unroll
                for (int ks = 0; ks < 2; ++ks)
                    acc[4 + mf][nf] = __builtin_amdgcn_mfma_f32_16x16x32_bf16(
                        af[mf][ks], bfr[nf][ks], acc[4 + mf][nf], 0, 0, 0);
        __builtin_amdgcn_s_setprio(0);
        __builtin_amdgcn_s_barrier();
    }

    // ---------------- epilogue (runtime mode) ----------------
    if (p.mode == 0) {
        unsigned short* C = (unsigned short*)p.Cout;
#pragma unroll
        for (int nf = 0; nf < 4; ++nf) {
            const int col = col0 + wc * 64 + nf * 16 + lr;
            const float bc = p.bias ? p.bias[col] : 0.f;
#pragma unroll
            for (int mf = 0; mf < 8; ++mf) {
#pragma unroll
                for (int rr = 0; rr < 4; ++rr) {
                    const long row = row0 + wr * 128 + mf * 16 + lq * 4 + rr;
                    float v = acc[mf][nf][rr] + bc;
                    if (p.addend) v += bf2f(p.addend[row * p.cStride + col]);
                    v *= p.scale;
                    if (p.relu) v = fmaxf(v, 0.f);
                    const long srow = p.rmap ? (long)p.rmap[row] : row;
                    C[srow * p.cStride + col] = f2bf(v);
                }
            }
        }
    } else if (p.mode == 1) {
        unsigned short* C = (unsigned short*)p.Cout;   // fp16 scratch [m][L] compacted
        float btv[4];
#pragma unroll
        for (int nf = 0; nf < 4; ++nf)
            btv[nf] = p.bterm[b * L_ + col0 + wc * 64 + nf * 16 + lr];
#pragma unroll
        for (int mf = 0; mf < 8; ++mf) {
#pragma unroll
            for (int rr = 0; rr < 4; ++rr) {
                const long mg = row0 + wr * 128 + mf * 16 + lq * 4 + rr;
#pragma unroll
                for (int nf = 0; nf < 4; ++nf) {
                    const int col = col0 + wc * 64 + nf * 16 + lr;
                    C[mg * L_ + col] = f2h(acc[mf][nf][rr] + btv[nf]);
                }
            }
        }
    } else {   // mode 2: qrel fp32 (col < NREL)
        float* qout = p.qout;
#pragma unroll
        for (int nf = 0; nf < 3; ++nf) {
            const int col = wc * 64 + nf * 16 + lr;
            if (col < NREL) {
                const float bc = p.bias[col];
#pragma unroll
                for (int mf = 0; mf < 8; ++mf)
#pragma unroll
                    for (int rr = 0; rr < 4; ++rr) {
                        const long mg = row0 + wr * 128 + mf * 16 + lq * 4 + rr;
                        qout[mg * NREL + col] = (acc[mf][nf][rr] + bc) * p.scale;
                    }
            }
        }
    }
}

// ===========================================================================
// 2-phase 128x128 kernel (prep-only: GtT / Wqrel, small M)
__global__ __launch_bounds__(256) void k_mfma_prep(
    PSet4 ps, long aS0, long bS0, int K0)
{
    PSet p = ps.s[blockIdx.z];
    const long row0 = (long)blockIdx.y * 128;
    if (row0 >= p.mValid) return;
    const int col0 = blockIdx.x * 128;

    __shared__ unsigned short As[2][128 * 32];
    __shared__ unsigned short Bs[2][128 * 32];
    const int tid  = threadIdx.x;
    const int lane = tid & 63;
    const int wave = tid >> 6;
    const int wr = wave >> 1, wc = wave & 1;
    const int lq = lane >> 4, lr = lane & 15;
    const int sr = lane >> 2;
    const int sc = (lane & 3) * 8;

    f32x4 acc[4][4];
#pragma unroll
    for (int m = 0; m < 4; ++m)
#pragma unroll
        for (int n = 0; n < 4; ++n) acc[m][n] = (f32x4)0.f;

    const int NT = K0 / 32;
    auto stage = [&](int t, int buf) {
        const int k0 = t * 32;
#pragma unroll
        for (int j = 0; j < 2; ++j) {
            const int c = wave + j * 4;
            const unsigned short* ga = p.A0 + (row0 + c * 16 + sr) * aS0 + k0 + sc;
            const unsigned short* gb = p.B0 + (long)(col0 + c * 16 + sr) * bS0 + k0 + sc;
            __builtin_amdgcn_global_load_lds((gv_t*)ga, (sv_t*)&As[buf][c * 512], 16, 0, 0);
            __builtin_amdgcn_global_load_lds((gv_t*)gb, (sv_t*)&Bs[buf][c * 512], 16, 0, 0);
        }
    };
    stage(0, 0);
    asm volatile("s_waitcnt vmcnt(0)" ::: "memory");
    __builtin_amdgcn_s_barrier();
    int cur = 0;
    for (int t = 0; t < NT; ++t) {
        if (t + 1 < NT) stage(t + 1, cur ^ 1);
        bf16x8 a4[4], b4[4];
#pragma unroll
        for (int m = 0; m < 4; ++m)
            a4[m] = *(const bf16x8*)&As[cur][(wr * 64 + m * 16 + lr) * 32 + lq * 8];
#pragma unroll
        for (int n = 0; n < 4; ++n)
            b4[n] = *(const bf16x8*)&Bs[cur][(wc * 64 + n * 16 + lr) * 32 + lq * 8];
#pragma unroll
        for (int m = 0; m < 4; ++m)
#pragma unroll
            for (int n = 0; n < 4; ++n)
                acc[m][n] = __builtin_amdgcn_mfma_f32_16x16x32_bf16(a4[m], b4[n], acc[m][n], 0, 0, 0);
        asm volatile("s_waitcnt vmcnt(0)" ::: "memory");
        __builtin_amdgcn_s_barrier();
        cur ^= 1;
    }
    unsigned short* C = (unsigned short*)p.Cout;
#pragma unroll
    for (int n = 0; n < 4; ++n) {
        const int col = col0 + wc * 64 + n * 16 + lr;
#pragma unroll
        for (int m = 0; m < 4; ++m)
#pragma unroll
            for (int r = 0; r < 4; ++r) {
                const long row = row0 + wr * 64 + m * 16 + lq * 4 + r;
                C[row * p.cStride + col] = f2bf(acc[m][n][r]);
            }
    }
}

// ---------------------------------------------------------------------------
// prep1: zero regions + fp32->bf16 converts, one streaming dispatch
struct Prep1 {
    float4* zp[6];   long zn4[6];
    const float* src[8]; unsigned short* dst[8]; long cn4[8];
};
__global__ __launch_bounds__(256) void k_prep1(Prep1 c)
{
    long g = (long)blockIdx.x * 256 + threadIdx.x;
#pragma unroll
    for (int s = 0; s < 6; ++s) {
        if (g < c.zn4[s]) {
            float4 v; v.x = v.y = v.z = v.w = 0.f;
            c.zp[s][g] = v;
            return;
        }
        g -= c.zn4[s];
    }
#pragma unroll
    for (int s = 0; s < 8; ++s) {
        if (g < c.cn4[s]) {
            const float4 v = ((const float4*)c.src[s])[g];
            ushort4 o; o.x = f2bf(v.x); o.y = f2bf(v.y); o.z = f2bf(v.z); o.w = f2bf(v.w);
            ((ushort4*)c.dst[s])[g] = o;
            return;
        }
        g -= c.cn4[s];
    }
}

// ---------------------------------------------------------------------------
// prep2: scan(8) | biasq(448) | batchsum(192) | W_sp transpose(1152)
__global__ __launch_bounds__(256) void k_prep2(
    const int* __restrict__ attm, int* __restrict__ keyidx,
    int* __restrict__ rmap, int* __restrict__ cnt,
    const float* __restrict__ bq0, const float* __restrict__ bq1,
    const float* __restrict__ wk0, const float* __restrict__ wk1,
    const float* __restrict__ rel0, const float* __restrict__ rel1,
    float* __restrict__ biasQ0, float* __restrict__ biasQ1,
    const float* __restrict__ hid, float* __restrict__ pooled,
    const float* __restrict__ W_sp, unsigned short* __restrict__ W1T)
{
    __shared__ int sci[256];
    __shared__ float tf[32][33];
    const int blk = blockIdx.x;
    const int t = threadIdx.x;

    if (blk < 8) {                       // ---- scan (batch = blk)
        const int b = blk;
        const int base = b * 1024 + t * 4;
        int pred[4]; int c = 0;
#pragma unroll
        for (int j = 0; j < 4; ++j) { pred[j] = (attm[base + j] != 0) ? 1 : 0; c += pred[j]; }
        sci[t] = c;
        __syncthreads();
        for (int ofs = 1; ofs < 256; ofs <<= 1) {
            const int v = (t >= ofs) ? sci[t - ofs] : 0;
            __syncthreads();
            sci[t] += v;
            __syncthreads();
        }
        int pos = sci[t] - c;
#pragma unroll
        for (int j = 0; j < 4; ++j) {
            if (pred[j]) {
                keyidx[base + j] = pos;
                rmap[base + j]   = b * 1024 + pos;
                ++pos;
            } else {
                keyidx[base + j] = -1;
                rmap[base + j]   = TRASH;
            }
        }
        if (t == 0) cnt[b] = sci[255];
    } else if (blk < 456) {              // ---- biasq
        const int i0 = blk - 8;
        const int side = i0 / 224;
        const float* bq  = side ? bq1  : bq0;
        const float* wk  = side ? wk1  : wk0;
        const float* rel = side ? rel1 : rel0;
        float* out       = side ? biasQ1 : biasQ0;
        const int i = (i0 % 224) * 4 + (t >> 6);
        const int lane = t & 63;
        const float* w = nullptr;
        if (i < D_) w = wk + (long)i * D_;
        else if (i - D_ < NREL) w = rel + (long)(i - D_) * D_;
        float a = 0.f;
        if (w)
            for (int e = lane * 4; e < D_; e += 256) {
                const float4 w4 = *(const float4*)&w[e];
                const float4 b4 = *(const float4*)&bq[e];
                a += w4.x * b4.x + w4.y * b4.y + w4.z * b4.z + w4.w * b4.w;
            }
#pragma unroll
        for (int o = 32; o > 0; o >>= 1) a += __shfl_xor(a, o, 64);
        if (lane == 0 && i < 896) out[i] = a;
    } else if (blk < 648) {              // ---- batchsum (split-K atomic)
        const int i = blk - 456;
        const int b = i & 7;
        const int dc = (i >> 3) % 3;
        const int ks = i / 24;
        const int d = dc * 256 + t;
        const int k0 = ks * 128;
        const float* hb = hid + (long)b * L_ * D_;
        float acc = 0.f;
        for (int k = k0; k < k0 + 128; ++k)
            acc += attm[b * L_ + k] ? hb[(long)k * D_ + d] : 0.f;
        atomicAdd(&pooled[b * D_ + d], acc);
    } else {                             // ---- W_sp transpose -> W1T/W2T
        const int i = blk - 648;
        const int z = i / 576;
        const int rem = i % 576;
        const int c0 = (rem % 24) * 32, r0 = (rem / 24) * 32;
        const long zo = (long)z * D_ * D_;
        const int tx = t & 31, ty = t >> 5;
#pragma unroll
        for (int j = 0; j < 32; j += 8)
            tf[ty + j][tx] = W_sp[zo + (long)(r0 + ty + j) * D_ + c0 + tx];
        __syncthreads();
#pragma unroll
        for (int j = 0; j < 32; j += 8)
            W1T[zo + (long)(c0 + ty + j) * D_ + r0 + tx] = f2bf(tf[tx][ty + j]);
    }
}

// ---------------------------------------------------------------------------
// prep3: pw2(192) | bterm(4096) | attn strip-zero(16)
__global__ __launch_bounds__(256) void k_prep3(
    const float* __restrict__ pooled, const float* __restrict__ W_sp,
    float* __restrict__ pw2,
    const unsigned short* __restrict__ hid_bf,
    const float* __restrict__ biasQ0, const float* __restrict__ biasQ1,
    float* __restrict__ btC0, float* __restrict__ btC1,
    const int* __restrict__ keyidx, float invs,
    unsigned short* __restrict__ attn0, unsigned short* __restrict__ attn1,
    const int* __restrict__ cnt)
{
    const int blk = blockIdx.x;
    const int t = threadIdx.x;
    if (blk < 192) {                     // ---- pw2
        const int b = blk & 7;
        const int dc = (blk >> 3) % 3;
        const int d0 = (blk / 24) * 96;
        const int n = dc * 256 + t;
        float acc = 0.f;
        for (int d = d0; d < d0 + 96; ++d)
            acc += pooled[b * D_ + d] * W_sp[(long)(D_ + d) * D_ + n];
        atomicAdd(&pw2[b * D_ + n], acc);
    } else if (blk < 4288) {             // ---- bterm (compacted)
        const int i = blk - 192;
        const int side = i >> 11;
        const float* biasQ = side ? biasQ1 : biasQ0;
        float* out = side ? btC1 : btC0;
        const long row = (long)(i & 2047) * 4 + (t >> 6);
        const int lane = t & 63;
        const unsigned short* h = hid_bf + row * D_;
        float a = 0.f;
        for (int d = lane * 4; d < D_; d += 256) {
            const ushort4 u = *(const ushort4*)&h[d];
            const float4 bq4 = *(const float4*)&biasQ[d];
            a += bf2f(u.x) * bq4.x + bf2f(u.y) * bq4.y + bf2f(u.z) * bq4.z + bf2f(u.w) * bq4.w;
        }
#pragma unroll
        for (int o = 32; o > 0; o >>= 1) a += __shfl_xor(a, o, 64);
        if (lane == 0) {
            const int ji = keyidx[row];
            if (ji >= 0) out[(row & ~(long)(L_ - 1)) + ji] = a * invs;
        }
    } else {                             // ---- attn padding strip-zero
        const int i = blk - 4288;
        unsigned short* a = (i >> 3) ? attn1 : attn0;
        const int b = i & 7;
        const int c0 = cnt[b];
        const int ce = (c0 + 63) & ~63;
        if (ce == c0) return;
        for (int r = t; r < 1024; r += 256) {
            unsigned short* row = a + ((long)b * 1024 + r) * L_;
            for (int c = c0; c < ce; ++c) row[c] = 0;
        }
    }
}

// ---------------------------------------------------------------------------
// bf16 [rows][cols] -> bf16 [cols][rows], batched over z (separate strides)
__global__ __launch_bounds__(256) void k_transpose_bf(
    const unsigned short* __restrict__ in, long inBatch,
    unsigned short* __restrict__ out, long outBatch, int rows, int cols)
{
    __shared__ unsigned short t[32][33];
    const int z = blockIdx.z;
    const unsigned short* I = in + (long)z * inBatch;
    unsigned short* O = out + (long)z * outBatch;
    const int c0 = blockIdx.x * 32, r0 = blockIdx.y * 32;
    const int tx = threadIdx.x & 31, ty = threadIdx.x >> 5;
#pragma unroll
    for (int i = 0; i < 32; i += 8)
        t[ty + i][tx] = I[(long)(r0 + ty + i) * cols + c0 + tx];
    __syncthreads();
#pragma unroll
    for (int i = 0; i < 32; i += 8)
        O[(long)(c0 + ty + i) * rows + r0 + tx] = t[tx][ty + i];
}

// ---------------------------------------------------------------------------
// softmax: masked rows -> uniform 1/L; active rows read COMPACTED fp16
// scratch via keyidx gather, add qrel, write fp32 d_out + compacted bf16 attn
__global__ __launch_bounds__(256) void k_softmax(
    const unsigned short* __restrict__ sSt, const unsigned short* __restrict__ sEd,
    float* __restrict__ oSt, float* __restrict__ oEd,
    unsigned short* __restrict__ aSt, unsigned short* __restrict__ aEd,
    const float* __restrict__ qrSt, const float* __restrict__ qrEd,
    const int* __restrict__ spw, const int* __restrict__ srcm,
    const int* __restrict__ keyidx, const int* __restrict__ cnt, int it)
{
    const long m = blockIdx.x;
    const int b = (int)(m >> 10);
    float* o = (blockIdx.y ? oEd : oSt) + (m * NSP + it) * L_;
    const int t = threadIdx.x;
    if (spw[m] <= it || srcm[m] == 0 || cnt[b] == 0) {   // fully masked row
        float4 u; u.x = u.y = u.z = u.w = 0.0009765625f;
        *(float4*)&o[4 * t] = u;
        return;
    }
    const unsigned short* s = (blockIdx.y ? sEd : sSt) + m * L_;
    unsigned short* a = (blockIdx.y ? aEd : aSt) + m * L_;
    const float* qrow = (blockIdx.y ? qrEd : qrSt) + m * NREL;
    const int q = (int)(m & (L_ - 1));
    int ji[4]; float vv[4];
#pragma unroll
    for (int j = 0; j < 4; ++j) {
        const int c = 4 * t + j;
        ji[j] = keyidx[b * L_ + c];
        if (ji[j] >= 0) {
            int dr = c - q;
            dr = dr < -R_ ? -R_ : (dr > R_ ? R_ : dr);
            vv[j] = h2f(s[ji[j]]) + qrow[dr + R_];
        } else {
            vv[j] = -1e18f;
        }
    }
    float mx = fmaxf(fmaxf(vv[0], vv[1]), fmaxf(vv[2], vv[3]));
#pragma unroll
    for (int ofs = 32; ofs > 0; ofs >>= 1) mx = fmaxf(mx, __shfl_xor(mx, ofs, 64));
    __shared__ float redm[4];
    __shared__ float reds[4];
    const int wave = t >> 6;
    if ((t & 63) == 0) redm[wave] = mx;
    __syncthreads();
    mx = fmaxf(fmaxf(redm[0], redm[1]), fmaxf(redm[2], redm[3]));
    float sum = 0.f;
#pragma unroll
    for (int j = 0; j < 4; ++j) { vv[j] = expf(vv[j] - mx); sum += vv[j]; }
#pragma unroll
    for (int ofs = 32; ofs > 0; ofs >>= 1) sum += __shfl_xor(sum, ofs, 64);
    if ((t & 63) == 0) reds[wave] = sum;
    __syncthreads();
    sum = reds[0] + reds[1] + reds[2] + reds[3];
    const float inv = 1.0f / sum;
    float4 v; v.x = vv[0] * inv; v.y = vv[1] * inv; v.z = vv[2] * inv; v.w = vv[3] * inv;
    *(float4*)&o[4 * t] = v;
    const float* vp = (const float*)&v;
#pragma unroll
    for (int j = 0; j < 4; ++j)
        if (ji[j] >= 0) a[ji[j]] = f2bf(vp[j]);
}

// ---------------------------------------------------------------------------
__global__ __launch_bounds__(256) void k_addend0m(
    const float* __restrict__ pw2, const int* __restrict__ cnt,
    const int* __restrict__ srcm, const int* __restrict__ spw,
    unsigned short* __restrict__ out, float* __restrict__ outM)
{
    const long idx = (long)blockIdx.x * 256 + threadIdx.x;
    const int d = (int)(idx % D_);
    const long m = idx / D_;
    const int b = (int)(m >> 10);
    const float inv = 1.0f / fmaxf((float)cnt[b], 1.0f);
    out[idx] = f2bf(srcm[m] ? pw2[b * D_ + d] * inv : 0.0f);
    if (idx < (long)B_ * L_ * NSP)
        outM[idx] = ((int)(idx & 3) < spw[idx >> 2]) ? 1.0f : 0.0f;
}

// ---------------------------------------------------------------------------
extern "C" void kernel_launch(void* const* d_in, const int* in_sizes, int n_in,
                              void* d_out, int out_size, void* d_ws, size_t ws_size,
                              hipStream_t stream)
{
    (void)in_sizes; (void)n_in; (void)out_size; (void)ws_size;
    const float* hid     = (const float*)d_in[0];
    const float* src_hid = (const float*)d_in[1];
    const int*   spw     = (const int*)d_in[2];
    const int*   attm    = (const int*)d_in[3];
    const int*   srcm    = (const int*)d_in[4];
    const float* Wq_st = (const float*)d_in[6];
    const float* bq_st = (const float*)d_in[7];
    const float* Wk_st = (const float*)d_in[8];
    const float* rel_st= (const float*)d_in[10];
    const float* Wq_ed = (const float*)d_in[11];
    const float* bq_ed = (const float*)d_in[12];
    const float* Wk_ed = (const float*)d_in[13];
    const float* rel_ed= (const float*)d_in[15];
    const float* W_sp  = (const float*)d_in[16];
    const float* b_sp  = (const float*)d_in[17];

    float* out      = (float*)d_out;
    float* outSts   = out;
    float* outEds   = out + (long)B_ * L_ * NSP * L_;
    float* outMasks = outEds + (long)B_ * L_ * NSP * L_;

    const long S = (long)B_ * L_ * D_;
    const long DD = (long)D_ * D_;
    const long ML = (long)B_ * L_;
    const long SX = (ML + 256) * (long)D_;   // scatter targets (+trash rows)
    char* wsB = (char*)d_ws;
    auto take = [&](size_t bytes) -> char* {
        char* p = wsB; wsB += (bytes + 255) & ~(size_t)255; return p;
    };
    unsigned short* hid_bf  = (unsigned short*)take(S * 2);
    unsigned short* src_bf  = (unsigned short*)take(S * 2);
    unsigned short* h1a     = (unsigned short*)take(S * 2);
    unsigned short* h1b     = (unsigned short*)take(S * 2);
    unsigned short* h2a     = (unsigned short*)take(S * 2);
    unsigned short* h2b     = (unsigned short*)take(S * 2);
    unsigned short* tmpPC   = (unsigned short*)take(SX * 2);  // hid@W2, key-compacted
    unsigned short* hidW2TC = (unsigned short*)take(S * 2);   // [B][D][L] compacted keys
    unsigned short* add0    = (unsigned short*)take(S * 2);
    unsigned short* hidGCst = (unsigned short*)take(SX * 2);  // key-compacted
    unsigned short* hidGCed = (unsigned short*)take(SX * 2);
    unsigned short* GtTst   = (unsigned short*)take(DD * 2);
    unsigned short* GtTed   = (unsigned short*)take(DD * 2);
    unsigned short* W1T     = (unsigned short*)take(DD * 2);  // contiguous with W2T
    unsigned short* W2T     = (unsigned short*)take(DD * 2);
    unsigned short* WqBfSt  = (unsigned short*)take(DD * 2);
    unsigned short* WqBfEd  = (unsigned short*)take(DD * 2);
    unsigned short* WkBfSt  = (unsigned short*)take(DD * 2);
    unsigned short* WkBfEd  = (unsigned short*)take(DD * 2);
    unsigned short* relbst  = (unsigned short*)take((long)128 * D_ * 2);
    unsigned short* relbed  = (unsigned short*)take((long)128 * D_ * 2);
    unsigned short* WqrelSt = (unsigned short*)take((long)256 * D_ * 2);
    unsigned short* WqrelEd = (unsigned short*)take((long)256 * D_ * 2);
    unsigned short* attn_st = (unsigned short*)take(ML * L_ * 2);   // compacted bf16 attn
    unsigned short* attn_ed = (unsigned short*)take(ML * L_ * 2);
    unsigned short* scrSt   = (unsigned short*)take(ML * L_ * 2);   // fp16 scores (compacted cols)
    unsigned short* scrEd   = (unsigned short*)take(ML * L_ * 2);
    float* qrelbSt = (float*)take(ML * NREL * 4);
    float* qrelbEd = (float*)take(ML * NREL * 4);
    float* biasQst = (float*)take(896 * 4);
    float* biasQed = (float*)take(896 * 4);
    float* btermCst= (float*)take(ML * 4);
    float* btermCed= (float*)take(ML * 4);
    float* pooled  = (float*)take((long)B_ * D_ * 4);
    float* pw2     = (float*)take((long)B_ * D_ * 4);
    int*   keyidx  = (int*)take(ML * 4);
    int*   rmap    = (int*)take(ML * 4);
    int*   cnt     = (int*)take(256);

    const float invs = 1.0f / sqrtf((float)D_);
    const long BB   = (long)L_ * D_;
    const int  NOB  = 1 << 30;

    PSet4 ps;
    auto clr = [&](int i) {
        ps.s[i] = PSet{nullptr,nullptr,nullptr,nullptr,nullptr,nullptr,nullptr,
                       nullptr,nullptr,nullptr,0,0,1L<<40,1.f,0,0,1<<30,0,0};
    };

    // ---- prep1: zeros + converts (one streaming dispatch) ----
    {
        Prep1 c;
        c.zp[0] = (float4*)(relbst + (long)NREL * D_);  c.zn4[0] = (long)(128 - NREL) * D_ * 2 / 16;
        c.zp[1] = (float4*)(relbed + (long)NREL * D_);  c.zn4[1] = (long)(128 - NREL) * D_ * 2 / 16;
        c.zp[2] = (float4*)(WqrelSt + (long)128 * D_);  c.zn4[2] = (long)128 * D_ * 2 / 16;
        c.zp[3] = (float4*)(WqrelEd + (long)128 * D_);  c.zn4[3] = (long)128 * D_ * 2 / 16;
        c.zp[4] = (float4*)pooled;                      c.zn4[4] = (long)B_ * D_ / 4;
        c.zp[5] = (float4*)pw2;                         c.zn4[5] = (long)B_ * D_ / 4;
        c.src[0] = hid;     c.dst[0] = hid_bf;  c.cn4[0] = S / 4;
        c.src[1] = src_hid; c.dst[1] = src_bf;  c.cn4[1] = S / 4;
        c.src[2] = Wq_st;   c.dst[2] = WqBfSt;  c.cn4[2] = DD / 4;
        c.src[3] = Wq_ed;   c.dst[3] = WqBfEd;  c.cn4[3] = DD / 4;
        c.src[4] = Wk_st;   c.dst[4] = WkBfSt;  c.cn4[4] = DD / 4;
        c.src[5] = Wk_ed;   c.dst[5] = WkBfEd;  c.cn4[5] = DD / 4;
        c.src[6] = rel_st;  c.dst[6] = relbst;  c.cn4[6] = (long)NREL * D_ / 4;
        c.src[7] = rel_ed;  c.dst[7] = relbed;  c.cn4[7] = (long)NREL * D_ / 4;
        long tot = 0;
        for (int i = 0; i < 6; ++i) tot += c.zn4[i];
        for (int i = 0; i < 8; ++i) tot += c.cn4[i];
        k_prep1<<<(int)((tot + 255) / 256), 256, 0, stream>>>(c);
    }
    // ---- prep2: scan | biasq | batchsum | W_sp transpose ----
    k_prep2<<<1800, 256, 0, stream>>>(attm, keyidx, rmap, cnt,
                                      bq_st, bq_ed, Wk_st, Wk_ed, rel_st, rel_ed,
                                      biasQst, biasQed, hid, pooled, W_sp, W1T);
    // ---- prep3: pw2 | bterm | attn strip-zero ----
    k_prep3<<<4304, 256, 0, stream>>>(pooled, W_sp, pw2, hid_bf,
                                      biasQst, biasQed, btermCst, btermCed,
                                      keyidx, invs, attn_st, attn_ed, cnt);
    k_addend0m<<<(int)(S / 256), 256, 0, stream>>>(pw2, cnt, srcm, spw, add0, outMasks);

    // GtT (Wq.Wk^T) + Wqrel (rel.Wq^T), 2-phase 128^2 kernel, z=4
    for (int i = 0; i < 4; ++i) clr(i);
    ps.s[0].A0 = WqBfSt; ps.s[0].B0 = WkBfSt; ps.s[0].Cout = GtTst;   ps.s[0].cStride = D_; ps.s[0].mValid = D_;
    ps.s[1].A0 = WqBfEd; ps.s[1].B0 = WkBfEd; ps.s[1].Cout = GtTed;   ps.s[1].cStride = D_; ps.s[1].mValid = D_;
    ps.s[2].A0 = relbst; ps.s[2].B0 = WqBfSt; ps.s[2].Cout = WqrelSt; ps.s[2].cStride = D_; ps.s[2].mValid = 128;
    ps.s[3].A0 = relbed; ps.s[3].B0 = WqBfEd; ps.s[3].Cout = WqrelEd; ps.s[3].cStride = D_; ps.s[3].mValid = 128;
    k_mfma_prep<<<dim3(D_ / 128, D_ / 128, 4), 256, 0, stream>>>(ps, D_, D_, D_);

    // concat0 + hid@W2 (scattered) + hidGC st/ed (scattered) : one z=4 dispatch
    for (int i = 0; i < 4; ++i) clr(i);
    ps.s[0].A0 = src_bf; ps.s[0].B0 = W1T;   ps.s[0].bias = b_sp; ps.s[0].addend = add0;
    ps.s[0].Cout = h1a;  ps.s[0].cStride = D_; ps.s[0].relu = 1; ps.s[0].nValid = D_;
    ps.s[1].A0 = hid_bf; ps.s[1].B0 = W2T;   ps.s[1].Cout = tmpPC;   ps.s[1].cStride = D_;
    ps.s[1].nValid = D_; ps.s[1].rmap = rmap;
    ps.s[2].A0 = hid_bf; ps.s[2].B0 = GtTst; ps.s[2].Cout = hidGCst; ps.s[2].cStride = D_;
    ps.s[2].scale = invs; ps.s[2].nValid = D_; ps.s[2].rmap = rmap;
    ps.s[3].A0 = hid_bf; ps.s[3].B0 = GtTed; ps.s[3].Cout = hidGCed; ps.s[3].cStride = D_;
    ps.s[3].scale = invs; ps.s[3].nValid = D_; ps.s[3].rmap = rmap;
    k_mfma8<<<dim3(D_ / 256, (B_ * L_) / 256, 4), 512, 0, stream>>>(
        ps, D_, D_, NOB, D_, D_, D_, 0, cnt);
    k_transpose_bf<<<dim3(D_ / 32, L_ / 32, B_), 256, 0, stream>>>(
        tmpPC, (long)L_ * D_, hidW2TC, (long)D_ * L_, L_, D_);

    unsigned short* h1cur = h1a; unsigned short* h2cur = h1a;
    unsigned short* h1nxt = h1b; unsigned short* h2nxt = h2a;

    for (int it = 0; it < NSP; ++it) {
        if (it > 0) {
            // fused pooling+concat: attnC@hidW2TC (K=round64(cnt[b])) + hcur@W1 (K=768)
            for (int i = 0; i < 4; ++i) clr(i);
            ps.s[0].A0 = attn_st; ps.s[0].B0 = hidW2TC; ps.s[0].A1 = h1cur; ps.s[0].B1 = W1T;
            ps.s[0].bias = b_sp; ps.s[0].Cout = h1nxt; ps.s[0].cStride = D_;
            ps.s[0].relu = 1; ps.s[0].bB0 = (long)D_ * L_; ps.s[0].nValid = D_; ps.s[0].varK0 = 1;
            ps.s[1] = ps.s[0];
            ps.s[1].A0 = attn_ed; ps.s[1].A1 = h2cur; ps.s[1].Cout = h2nxt;
            k_mfma8<<<dim3(D_ / 256, (B_ * L_) / 256, 2), 512, 0, stream>>>(
                ps, L_, L_, L_, 1024, D_, D_, D_, cnt);
            h1cur = h1nxt; h2cur = h2nxt;
            h1nxt = (h1cur == h1a) ? h1b : h1a;
            h2nxt = (h2cur == h2a) ? h2b : h2a;
        }
        // scores over COMPACTED key cols (z0,z1 -> fp16 scratch) + qrel (z2,z3)
        for (int i = 0; i < 4; ++i) clr(i);
        ps.s[0].A0 = h1cur; ps.s[0].B0 = hidGCst; ps.s[0].Cout = scrSt;
        ps.s[0].bterm = btermCst; ps.s[0].bB0 = BB; ps.s[0].mode = 1;
        ps.s[0].cStride = L_; ps.s[0].nValid = L_; ps.s[0].useCnt = 1;
        ps.s[1].A0 = h2cur; ps.s[1].B0 = hidGCed; ps.s[1].Cout = scrEd;
        ps.s[1].bterm = btermCed; ps.s[1].bB0 = BB; ps.s[1].mode = 1;
        ps.s[1].cStride = L_; ps.s[1].nValid = L_; ps.s[1].useCnt = 1;
        ps.s[2].A0 = h1cur; ps.s[2].B0 = WqrelSt; ps.s[2].qout = qrelbSt;
        ps.s[2].bias = biasQst + D_; ps.s[2].scale = invs; ps.s[2].mode = 2; ps.s[2].nValid = 256;
        ps.s[3].A0 = h2cur; ps.s[3].B0 = WqrelEd; ps.s[3].qout = qrelbEd;
        ps.s[3].bias = biasQed + D_; ps.s[3].scale = invs; ps.s[3].mode = 2; ps.s[3].nValid = 256;
        k_mfma8<<<dim3(L_ / 256, (B_ * L_) / 256, 4), 512, 0, stream>>>(
            ps, D_, D_, L_, D_, D_, D_, 0, cnt);
        // softmax: gather compacted scratch, write d_out + compacted attn
        k_softmax<<<dim3(B_ * L_, 2), 256, 0, stream>>>(
            scrSt, scrEd, outSts, outEds, attn_st, attn_ed,
            qrelbSt, qrelbEd, spw, srcm, keyidx, cnt, it);
    }
}